// Round 1
// baseline (6858.018 us; speedup 1.0000x reference)
//
#include <hip/hip_runtime.h>
#include <hip/hip_bf16.h>
#include <math.h>

#define Nn 512
#define Ee 768
#define Pp 64
#define PHh 32
#define Hh 8
#define Dd 96
#define NNe 262144      // N*N
#define LNEPS 1e-5f

__device__ __forceinline__ float wave_red_sum(float v) {
#pragma unroll
  for (int off = 32; off > 0; off >>= 1) v += __shfl_xor(v, off);
  return v;
}
__device__ __forceinline__ float wave_red_max(float v) {
#pragma unroll
  for (int off = 32; off > 0; off >>= 1) v = fmaxf(v, __shfl_xor(v, off));
  return v;
}
__device__ __forceinline__ float half_red_sum(float v) {
#pragma unroll
  for (int off = 16; off > 0; off >>= 1) v += __shfl_xor(v, off, 32);
  return v;
}
__device__ __forceinline__ float gelu_exact(float v) {
  return 0.5f * v * (1.f + erff(v * 0.70710678118654752f));
}
__device__ __forceinline__ float sigmoidf_(float v) {
  return 1.f / (1.f + expf(-v));
}

// ---------------- LayerNorm over last dim C (C multiple of blockDim) ----------------
__global__ __launch_bounds__(256) void ln_kernel(const float* __restrict__ in,
                                                 float* __restrict__ out,
                                                 const float* __restrict__ gam,
                                                 const float* __restrict__ bet, int C) {
  int row = blockIdx.x;
  const float* xr = in + (long)row * C;
  float* yr = out + (long)row * C;
  float s = 0.f, ss = 0.f;
  for (int c = threadIdx.x; c < C; c += 256) { float v = xr[c]; s += v; ss += v * v; }
  s = wave_red_sum(s); ss = wave_red_sum(ss);
  __shared__ float sm[4][2];
  int wv = threadIdx.x >> 6, lane = threadIdx.x & 63;
  if (lane == 0) { sm[wv][0] = s; sm[wv][1] = ss; }
  __syncthreads();
  float ts = sm[0][0] + sm[1][0] + sm[2][0] + sm[3][0];
  float tss = sm[0][1] + sm[1][1] + sm[2][1] + sm[3][1];
  float mu = ts / C;
  float var = tss / C - mu * mu;
  float rs = rsqrtf(var + LNEPS);
  for (int c = threadIdx.x; c < C; c += 256) {
    float v = xr[c];
    yr[c] = (v - mu) * rs * gam[c] + bet[c];
  }
}

// ---------------- Generic tiled GEMMs: 64x64 tile, 4x4 microtile ----------------
// NT: C[M,N] = act(alpha * A[M,K] * B[N,K]^T + bias + resid)
#define TS 64
#define KS 16
__global__ __launch_bounds__(256) void gemm_nt(
    const float* __restrict__ A, int lda, long asB, long asH,
    const float* __restrict__ Bm, int ldb, long bsB, long bsH,
    float* __restrict__ C, int ldc, long csB, long csH,
    const float* __restrict__ resid, int ldr, long rsB, long rsH,
    const float* __restrict__ bias,
    int M, int N, int K, float alpha, int act, int Hdim) {
  int bz = blockIdx.z;
  int bb = bz / Hdim, hh = bz % Hdim;
  A += bb * asB + hh * asH;
  Bm += bb * bsB + hh * bsH;
  C += bb * csB + hh * csH;
  if (resid) resid += bb * rsB + hh * rsH;
  __shared__ float As[KS][TS + 1];
  __shared__ float Bs[KS][TS + 1];
  int m0 = blockIdx.y * TS, n0 = blockIdx.x * TS;
  int tid = threadIdx.x;
  int tx = tid & 15, ty = tid >> 4;
  float acc[4][4];
#pragma unroll
  for (int i = 0; i < 4; ++i)
#pragma unroll
    for (int j = 0; j < 4; ++j) acc[i][j] = 0.f;
  for (int k0 = 0; k0 < K; k0 += KS) {
    for (int l = tid; l < TS * KS; l += 256) {
      int r = l / KS, kk = l % KS;
      int gm = m0 + r, gn = n0 + r, gk = k0 + kk;
      As[kk][r] = (gm < M) ? A[(long)gm * lda + gk] : 0.f;
      Bs[kk][r] = (gn < N) ? Bm[(long)gn * ldb + gk] : 0.f;
    }
    __syncthreads();
#pragma unroll
    for (int kk = 0; kk < KS; ++kk) {
      float a[4], b[4];
#pragma unroll
      for (int i = 0; i < 4; ++i) { a[i] = As[kk][ty * 4 + i]; b[i] = Bs[kk][tx * 4 + i]; }
#pragma unroll
      for (int i = 0; i < 4; ++i)
#pragma unroll
        for (int j = 0; j < 4; ++j) acc[i][j] += a[i] * b[j];
    }
    __syncthreads();
  }
#pragma unroll
  for (int i = 0; i < 4; ++i)
#pragma unroll
    for (int j = 0; j < 4; ++j) {
      int gm = m0 + ty * 4 + i, gn = n0 + tx * 4 + j;
      if (gm < M && gn < N) {
        float v = acc[i][j] * alpha;
        if (bias) v += bias[gn];
        if (resid) v += resid[(long)gm * ldr + gn];
        if (act == 1) v = gelu_exact(v);
        C[(long)gm * ldc + gn] = v;
      }
    }
}

// NN: C[M,N] = A[M,K] * B[K,N] (+bias/resid/act)
__global__ __launch_bounds__(256) void gemm_nn(
    const float* __restrict__ A, int lda, long asB, long asH,
    const float* __restrict__ Bm, int ldb, long bsB, long bsH,
    float* __restrict__ C, int ldc, long csB, long csH,
    const float* __restrict__ resid, int ldr, long rsB, long rsH,
    const float* __restrict__ bias,
    int M, int N, int K, float alpha, int act, int Hdim) {
  int bz = blockIdx.z;
  int bb = bz / Hdim, hh = bz % Hdim;
  A += bb * asB + hh * asH;
  Bm += bb * bsB + hh * bsH;
  C += bb * csB + hh * csH;
  if (resid) resid += bb * rsB + hh * rsH;
  __shared__ float As[KS][TS + 1];
  __shared__ float Bs[KS][TS + 1];
  int m0 = blockIdx.y * TS, n0 = blockIdx.x * TS;
  int tid = threadIdx.x;
  int tx = tid & 15, ty = tid >> 4;
  float acc[4][4];
#pragma unroll
  for (int i = 0; i < 4; ++i)
#pragma unroll
    for (int j = 0; j < 4; ++j) acc[i][j] = 0.f;
  for (int k0 = 0; k0 < K; k0 += KS) {
    for (int l = tid; l < TS * KS; l += 256) {
      int r = l / KS, kk = l % KS;
      int gm = m0 + r;
      As[kk][r] = (gm < M) ? A[(long)gm * lda + k0 + kk] : 0.f;
    }
    for (int l = tid; l < TS * KS; l += 256) {
      int n = l % TS, kk = l / TS;
      int gn = n0 + n;
      Bs[kk][n] = (gn < N) ? Bm[(long)(k0 + kk) * ldb + gn] : 0.f;
    }
    __syncthreads();
#pragma unroll
    for (int kk = 0; kk < KS; ++kk) {
      float a[4], b[4];
#pragma unroll
      for (int i = 0; i < 4; ++i) { a[i] = As[kk][ty * 4 + i]; b[i] = Bs[kk][tx * 4 + i]; }
#pragma unroll
      for (int i = 0; i < 4; ++i)
#pragma unroll
        for (int j = 0; j < 4; ++j) acc[i][j] += a[i] * b[j];
    }
    __syncthreads();
  }
#pragma unroll
  for (int i = 0; i < 4; ++i)
#pragma unroll
    for (int j = 0; j < 4; ++j) {
      int gm = m0 + ty * 4 + i, gn = n0 + tx * 4 + j;
      if (gm < M && gn < N) {
        float v = acc[i][j] * alpha;
        if (bias) v += bias[gn];
        if (resid) v += resid[(long)gm * ldr + gn];
        if (act == 1) v = gelu_exact(v);
        C[(long)gm * ldc + gn] = v;
      }
    }
}

// ---------------- pair bias: bias[b,h,i,j] = LN(pair[b,i,j,:]) . wb[h,:] + bb[h] ----------------
__global__ __launch_bounds__(256) void pair_bias_kernel(
    const float* __restrict__ pair, const float* __restrict__ gam,
    const float* __restrict__ bet, const float* __restrict__ wb,
    const float* __restrict__ bbv, float* __restrict__ bias) {
  int wv = threadIdx.x >> 6, lane = threadIdx.x & 63;
  long e0 = ((long)blockIdx.x * 4 + wv) * 8;
  float gl = gam[lane], bl = bet[lane];
  float wrow[8];
#pragma unroll
  for (int h = 0; h < 8; ++h) wrow[h] = wb[h * 64 + lane];
  for (int it = 0; it < 8; ++it) {
    long e = e0 + it;
    float v = pair[e * 64 + lane];
    float s = wave_red_sum(v);
    float ss = wave_red_sum(v * v);
    float mu = s * 0.015625f;
    float var = ss * 0.015625f - mu * mu;
    float zp = (v - mu) * rsqrtf(var + LNEPS) * gl + bl;
    int b = (int)(e >> 18);
    int i = (int)((e >> 9) & 511);
    int j = (int)(e & 511);
#pragma unroll
    for (int h = 0; h < 8; ++h) {
      float pr = wave_red_sum(zp * wrow[h]);
      if (lane == h) bias[(((long)(b * 8 + h) * 512) + i) * 512 + j] = pr + bbv[h];
    }
  }
}

// ---------------- softmax over last dim (512) with attn_mask add ----------------
__global__ __launch_bounds__(256) void softmax_kernel(float* __restrict__ sc,
                                                      const float* __restrict__ mask) {
  long row = blockIdx.x;  // (b*H+h)*N + i
  int g = (int)(row >> 9);
  int i = (int)(row & 511);
  int b = g >> 3;
  float* p = sc + row * 512;
  const float* mk = mask + ((long)b * 512 + i) * 512;
  int t = threadIdx.x;
  float v0 = p[t] + mk[t];
  float v1 = p[t + 256] + mk[t + 256];
  float mx = fmaxf(v0, v1);
  mx = wave_red_max(mx);
  __shared__ float sm[4];
  __shared__ float sm2[4];
  int wv = t >> 6, lane = t & 63;
  if (lane == 0) sm[wv] = mx;
  __syncthreads();
  mx = fmaxf(fmaxf(sm[0], sm[1]), fmaxf(sm[2], sm[3]));
  float e0 = expf(v0 - mx), e1 = expf(v1 - mx);
  float s = wave_red_sum(e0 + e1);
  if (lane == 0) sm2[wv] = s;
  __syncthreads();
  s = sm2[0] + sm2[1] + sm2[2] + sm2[3];
  float inv = 1.f / s;
  p[t] = e0 * inv;
  p[t + 256] = e1 * inv;
}

// ---------------- elementwise: g = sigmoid(g) * o ----------------
__global__ __launch_bounds__(256) void og_kernel(float* __restrict__ gio,
                                                 const float* __restrict__ o, long n) {
  long idx = (long)blockIdx.x * 256 + threadIdx.x;
  if (idx < n) {
    float gv = gio[idx];
    gio[idx] = sigmoidf_(gv) * o[idx];
  }
}

// ---------------- ab *= op_mask[row] ----------------
__global__ __launch_bounds__(256) void opmask_kernel(float* __restrict__ ab,
                                                     const float* __restrict__ mask) {
  int idx = blockIdx.x * 256 + threadIdx.x;
  if (idx < 2048 * 64) ab[idx] *= mask[idx >> 6];
}

// ---------------- T[row,p,e] = sum_d a_o[row,d] * w[p, d*32+e] ----------------
__global__ __launch_bounds__(256) void opm_T_kernel(const float* __restrict__ ab,
                                                    const float* __restrict__ w,
                                                    float* __restrict__ T) {
  int p = blockIdx.y;
  int row = blockIdx.x * 8 + threadIdx.y;
  int e = threadIdx.x;
  const float* a = ab + (long)row * 64;
  const float* wp = w + p * 1024 + e;
  float acc = 0.f;
#pragma unroll
  for (int d = 0; d < 32; ++d) acc += a[d] * wp[d * 32];
  T[((long)row * 64 + p) * 32 + e] = acc;
}

// ---------------- pair1 = pair + (T[b,i] . b_o[b,j]^T + b_out) * norm ----------------
__global__ __launch_bounds__(256) void opm_update_kernel(
    const float* __restrict__ pair_in, const float* __restrict__ T,
    const float* __restrict__ ab, const float* __restrict__ b_out,
    const float* __restrict__ op_norm, float* __restrict__ pair1) {
  int bi = blockIdx.x;  // b*512 + i
  int b = bi >> 9;
  int j0 = blockIdx.y * 64;
  __shared__ float Ts[64][33];
  __shared__ float Bs[64][33];
  int tid = threadIdx.x;
  for (int l = tid; l < 2048; l += 256) Ts[l >> 5][l & 31] = T[(long)bi * 2048 + l];
  for (int l = tid; l < 2048; l += 256) {
    int j = l >> 5, e = l & 31;
    Bs[j][e] = ab[(long)(b * 512 + j0 + j) * 64 + 32 + e];
  }
  __syncthreads();
  int p = tid & 63, jg = tid >> 6;
  float acc[16];
#pragma unroll
  for (int jj = 0; jj < 16; ++jj) acc[jj] = 0.f;
  for (int e = 0; e < 32; ++e) {
    float tv = Ts[p][e];
#pragma unroll
    for (int jj = 0; jj < 16; ++jj) acc[jj] += tv * Bs[jg * 16 + jj][e];
  }
  float bo = b_out[p];
  float nrm = op_norm[0];
  long base = ((long)bi * 512 + j0) * 64;
#pragma unroll
  for (int jj = 0; jj < 16; ++jj) {
    long idx = base + (long)(jg * 16 + jj) * 64 + p;
    pair1[idx] = pair_in[idx] + (acc[jj] + bo) * nrm;
  }
}

// ---------------- triangle: a_t/b_t from LN(pair1) (h-major layout [32][N*N]) ----------------
__global__ __launch_bounds__(256) void tm_ab_kernel(
    const float* __restrict__ pair1, const float* __restrict__ gam,
    const float* __restrict__ bet, const float* __restrict__ w_abp,
    const float* __restrict__ b_abp, const float* __restrict__ w_abg,
    const float* __restrict__ b_abg, float* __restrict__ a_t,
    float* __restrict__ b_t) {
  __shared__ float Wp[64][65];
  __shared__ float Wg[64][65];
  __shared__ float zs[4][64];
  int tid = threadIdx.x;
  for (int l = tid; l < 4096; l += 256) {
    Wp[l >> 6][l & 63] = w_abp[l];
    Wg[l >> 6][l & 63] = w_abg[l];
  }
  __syncthreads();
  int wv = tid >> 6, lane = tid & 63;
  float gl = gam[lane], bl = bet[lane];
  float bp = b_abp[lane], bgv = b_abg[lane];
  long e0 = ((long)blockIdx.x * 4 + wv) * 8;
  for (int it = 0; it < 8; ++it) {
    long e = e0 + it;
    float v = pair1[e * 64 + lane];
    float s = wave_red_sum(v), ss = wave_red_sum(v * v);
    float mu = s * 0.015625f, var = ss * 0.015625f - mu * mu;
    float zp = (v - mu) * rsqrtf(var + LNEPS) * gl + bl;
    zs[wv][lane] = zp;
    __syncthreads();
    float ap = bp, ag = bgv;
#pragma unroll 8
    for (int p = 0; p < 64; ++p) {
      float z = zs[wv][p];
      ap += Wp[lane][p] * z;
      ag += Wg[lane][p] * z;
    }
    float val = ap * sigmoidf_(ag);
    if (lane < 32) a_t[(long)lane * NNe + e] = val;
    else b_t[(long)(lane - 32) * NNe + e] = val;
    __syncthreads();
  }
}

// ---------------- t[h,i,k] = sum_j a[h,i,j]b[h,k,j] + a[h,j,i]b[h,j,k] ----------------
__global__ __launch_bounds__(256) void tm_tri_kernel(const float* __restrict__ a_t,
                                                     const float* __restrict__ b_t,
                                                     float* __restrict__ t_out) {
  int h = blockIdx.z;
  int i0 = blockIdx.y * 64, k0 = blockIdx.x * 64;
  const float* A = a_t + (long)h * NNe;
  const float* Bv = b_t + (long)h * NNe;
  __shared__ float As1[64][33];  // [i][j]
  __shared__ float Bs1[64][33];  // [k][j]
  __shared__ float As2[32][65];  // [j][i]
  __shared__ float Bs2[32][65];  // [j][k]
  int tid = threadIdx.x;
  int tx = tid & 15, ty = tid >> 4;
  float acc[4][4];
#pragma unroll
  for (int r = 0; r < 4; ++r)
#pragma unroll
    for (int c = 0; c < 4; ++c) acc[r][c] = 0.f;
  for (int j0 = 0; j0 < 512; j0 += 32) {
    for (int l = tid; l < 2048; l += 256) {
      int rr = l >> 5, cc = l & 31;
      As1[rr][cc] = A[(long)(i0 + rr) * 512 + j0 + cc];
      Bs1[rr][cc] = Bv[(long)(k0 + rr) * 512 + j0 + cc];
    }
    for (int l = tid; l < 2048; l += 256) {
      int rr = l >> 6, cc = l & 63;
      As2[rr][cc] = A[(long)(j0 + rr) * 512 + i0 + cc];
      Bs2[rr][cc] = Bv[(long)(j0 + rr) * 512 + k0 + cc];
    }
    __syncthreads();
#pragma unroll 4
    for (int jj = 0; jj < 32; ++jj) {
      float a1[4], b1[4], a2[4], b2[4];
#pragma unroll
      for (int r = 0; r < 4; ++r) {
        a1[r] = As1[ty * 4 + r][jj];
        a2[r] = As2[jj][ty * 4 + r];
      }
#pragma unroll
      for (int c = 0; c < 4; ++c) {
        b1[c] = Bs1[tx * 4 + c][jj];
        b2[c] = Bs2[jj][tx * 4 + c];
      }
#pragma unroll
      for (int r = 0; r < 4; ++r)
#pragma unroll
        for (int c = 0; c < 4; ++c) acc[r][c] += a1[r] * b1[c] + a2[r] * b2[c];
    }
    __syncthreads();
  }
  float* tp = t_out + (long)h * NNe;
#pragma unroll
  for (int r = 0; r < 4; ++r)
#pragma unroll
    for (int c = 0; c < 4; ++c)
      tp[(long)(i0 + ty * 4 + r) * 512 + k0 + tx * 4 + c] = acc[r][c];
}

// ---------------- pair = pair1 + gate(LN(pair1)) * (LN32(t) @ w_z^T + b_z) (in place) ----------------
__global__ __launch_bounds__(256) void tm_update_kernel(
    float* __restrict__ pairb, const float* __restrict__ t_in,
    const float* __restrict__ g_tm, const float* __restrict__ b_tm,
    const float* __restrict__ w_g, const float* __restrict__ b_g,
    const float* __restrict__ g_tmo, const float* __restrict__ b_tmo,
    const float* __restrict__ w_z, const float* __restrict__ b_z) {
  __shared__ float Wg[64][65];
  __shared__ float Wz[64][33];
  __shared__ float zsm[4][64];
  __shared__ float tsm[4][32];
  int tid = threadIdx.x;
  for (int l = tid; l < 4096; l += 256) Wg[l >> 6][l & 63] = w_g[l];
  for (int l = tid; l < 2048; l += 256) Wz[l >> 5][l & 31] = w_z[l];
  __syncthreads();
  int wv = tid >> 6, lane = tid & 63;
  float gl = g_tm[lane], bl = b_tm[lane];
  float bgl = b_g[lane], bzl = b_z[lane];
  float gol = (lane < 32) ? g_tmo[lane] : 0.f;
  float bol = (lane < 32) ? b_tmo[lane] : 0.f;
  long e0 = ((long)blockIdx.x * 4 + wv) * 8;
  for (int it = 0; it < 8; ++it) {
    long e = e0 + it;
    float v = pairb[e * 64 + lane];
    float s = wave_red_sum(v), ss = wave_red_sum(v * v);
    float mu = s * 0.015625f, var = ss * 0.015625f - mu * mu;
    float zp = (v - mu) * rsqrtf(var + LNEPS) * gl + bl;
    zsm[wv][lane] = zp;
    float tv = 0.f;
    if (lane < 32) tv = t_in[(long)lane * NNe + e];
    float ts2 = half_red_sum(tv), tss = half_red_sum(tv * tv);
    float tmu = ts2 * 0.03125f, tvar = tss * 0.03125f - tmu * tmu;
    float tln = (tv - tmu) * rsqrtf(tvar + LNEPS) * gol + bol;
    if (lane < 32) tsm[wv][lane] = tln;
    __syncthreads();
    float gacc = bgl, zacc = bzl;
#pragma unroll 8
    for (int p = 0; p < 64; ++p) gacc += Wg[lane][p] * zsm[wv][p];
#pragma unroll 8
    for (int hh = 0; hh < 32; ++hh) zacc += Wz[lane][hh] * tsm[wv][hh];
    pairb[e * 64 + lane] = v + gacc * zacc;
    __syncthreads();
  }
}

// ---------------- pair ffn (in place over full pair) ----------------
__global__ __launch_bounds__(256) void pffn_kernel(
    float* __restrict__ pairp, const float* __restrict__ gam,
    const float* __restrict__ bet, const float* __restrict__ w1,
    const float* __restrict__ b1, const float* __restrict__ w2,
    const float* __restrict__ b2) {
  __shared__ float W1[64][65];
  __shared__ float W2[64][65];
  __shared__ float zsm[4][64];
  __shared__ float msm[4][64];
  int tid = threadIdx.x;
  for (int l = tid; l < 4096; l += 256) {
    W1[l >> 6][l & 63] = w1[l];
    W2[l >> 6][l & 63] = w2[l];
  }
  __syncthreads();
  int wv = tid >> 6, lane = tid & 63;
  float gl = gam[lane], bl = bet[lane];
  float b1l = b1[lane], b2l = b2[lane];
  long e0 = ((long)blockIdx.x * 4 + wv) * 8;
  for (int it = 0; it < 8; ++it) {
    long e = e0 + it;
    float v = pairp[e * 64 + lane];
    float s = wave_red_sum(v), ss = wave_red_sum(v * v);
    float mu = s * 0.015625f, var = ss * 0.015625f - mu * mu;
    float zp = (v - mu) * rsqrtf(var + LNEPS) * gl + bl;
    zsm[wv][lane] = zp;
    __syncthreads();
    float macc = b1l;
#pragma unroll 8
    for (int p = 0; p < 64; ++p) macc += W1[lane][p] * zsm[wv][p];
    float m = gelu_exact(macc);
    msm[wv][lane] = m;
    __syncthreads();
    float oacc = b2l;
#pragma unroll 8
    for (int hh = 0; hh < 64; ++hh) oacc += W2[lane][hh] * msm[wv][hh];
    pairp[e * 64 + lane] = v + oacc;
    __syncthreads();
  }
}

extern "C" void kernel_launch(void* const* d_in, const int* in_sizes, int n_in,
                              void* d_out, int out_size, void* d_ws, size_t ws_size,
                              hipStream_t stream) {
  const float* x = (const float*)d_in[0];
  const float* pair = (const float*)d_in[1];
  const float* attn_mask = (const float*)d_in[2];
  const float* op_mask = (const float*)d_in[3];
  const float* op_norm = (const float*)d_in[4];
  const float* wq = (const float*)d_in[6];
  const float* wk = (const float*)d_in[7];
  const float* wv_ = (const float*)d_in[8];
  const float* wg = (const float*)d_in[9];
  const float* bg = (const float*)d_in[10];
  const float* wo = (const float*)d_in[11];
  const float* bo = (const float*)d_in[12];
  const float* ln_pair_g = (const float*)d_in[13];
  const float* ln_pair_b = (const float*)d_in[14];
  const float* wb = (const float*)d_in[15];
  const float* bb = (const float*)d_in[16];
  const float* ln_attn_g = (const float*)d_in[17];
  const float* ln_attn_b = (const float*)d_in[18];
  const float* ln_ffn_g = (const float*)d_in[19];
  const float* ln_ffn_b = (const float*)d_in[20];
  const float* w_ffn1 = (const float*)d_in[21];
  const float* b_ffn1 = (const float*)d_in[22];
  const float* w_ffn2 = (const float*)d_in[23];
  const float* b_ffn2 = (const float*)d_in[24];
  const float* ln_opm_g = (const float*)d_in[25];
  const float* ln_opm_b = (const float*)d_in[26];
  const float* w_opm_in = (const float*)d_in[27];
  const float* b_opm_in = (const float*)d_in[28];
  const float* w_opm_out = (const float*)d_in[29];
  const float* b_opm_out = (const float*)d_in[30];
  const float* ln_tm_g = (const float*)d_in[31];
  const float* ln_tm_b = (const float*)d_in[32];
  const float* w_tm_abp = (const float*)d_in[33];
  const float* b_tm_abp = (const float*)d_in[34];
  const float* w_tm_abg = (const float*)d_in[35];
  const float* b_tm_abg = (const float*)d_in[36];
  const float* w_tm_g = (const float*)d_in[37];
  const float* b_tm_g = (const float*)d_in[38];
  const float* w_tm_z = (const float*)d_in[39];
  const float* b_tm_z = (const float*)d_in[40];
  const float* ln_tmo_g = (const float*)d_in[41];
  const float* ln_tmo_b = (const float*)d_in[42];
  const float* ln_pffn_g = (const float*)d_in[43];
  const float* ln_pffn_b = (const float*)d_in[44];
  const float* w_pffn1 = (const float*)d_in[45];
  const float* b_pffn1 = (const float*)d_in[46];
  const float* w_pffn2 = (const float*)d_in[47];
  const float* b_pffn2 = (const float*)d_in[48];

  float* ws = (float*)d_ws;
  float* hb = ws;                    // 1572864
  float* qb = ws + 1572864;          // 1572864
  float* kb = ws + 3145728;          // 1572864
  float* vb = ws + 4718592;          // 1572864
  float* gb = ws + 6291456;          // 1572864
  float* biasb = ws + 7864320;       // 8388608
  float* ob = ws + 16252928;         // 1572864
  float* x1b = ws + 17825792;        // 1572864
  float* mffn = ws + 19398656;       // 6291456
  float* abb = ws + 25690112;        // 131072
  float* Tb = ws + 25821184;         // 4194304   (total 30,015,488 floats = 114.5 MB)
  // triangle-stage reuse (attention-stage buffers are dead by then):
  float* a_t = ws;                   // 8388608
  float* b_tt = ws + 8388608;        // 8388608
  float* t_b = ws + 16777216;        // 8388608

  float* xo = (float*)d_out;
  float* pair1 = xo + 1572864;

  const float qscale = 0.1020620726159658f;  // 96^-0.5

  // --- attention ---
  ln_kernel<<<2048, 256, 0, stream>>>(x, hb, ln_attn_g, ln_attn_b, 768);
  gemm_nt<<<dim3(12, 32, 1), 256, 0, stream>>>(hb, 768, 0, 0, wq, 768, 0, 0, qb, 768, 0, 0,
                                               nullptr, 0, 0, 0, nullptr, 2048, 768, 768,
                                               qscale, 0, 1);
  gemm_nt<<<dim3(12, 32, 1), 256, 0, stream>>>(hb, 768, 0, 0, wk, 768, 0, 0, kb, 768, 0, 0,
                                               nullptr, 0, 0, 0, nullptr, 2048, 768, 768,
                                               1.f, 0, 1);
  gemm_nt<<<dim3(12, 32, 1), 256, 0, stream>>>(hb, 768, 0, 0, wv_, 768, 0, 0, vb, 768, 0, 0,
                                               nullptr, 0, 0, 0, nullptr, 2048, 768, 768,
                                               1.f, 0, 1);
  gemm_nt<<<dim3(12, 32, 1), 256, 0, stream>>>(hb, 768, 0, 0, wg, 768, 0, 0, gb, 768, 0, 0,
                                               nullptr, 0, 0, 0, bg, 2048, 768, 768,
                                               1.f, 0, 1);
  pair_bias_kernel<<<32768, 256, 0, stream>>>(pair, ln_pair_g, ln_pair_b, wb, bb, biasb);
  // scores: biasb += q.k^T (in place), per (b,h)
  gemm_nt<<<dim3(8, 8, 32), 256, 0, stream>>>(qb, 768, 393216, 96, kb, 768, 393216, 96,
                                              biasb, 512, 2097152, 262144,
                                              biasb, 512, 2097152, 262144, nullptr,
                                              512, 512, 96, 1.f, 0, 8);
  softmax_kernel<<<16384, 256, 0, stream>>>(biasb, attn_mask);
  gemm_nn<<<dim3(2, 8, 32), 256, 0, stream>>>(biasb, 512, 2097152, 262144, vb, 768, 393216, 96,
                                              ob, 768, 393216, 96, nullptr, 0, 0, 0, nullptr,
                                              512, 96, 512, 1.f, 0, 8);
  og_kernel<<<6144, 256, 0, stream>>>(gb, ob, 1572864);
  gemm_nt<<<dim3(12, 32, 1), 256, 0, stream>>>(gb, 768, 0, 0, wo, 768, 0, 0, x1b, 768, 0, 0,
                                               x, 768, 0, 0, bo, 2048, 768, 768, 1.f, 0, 1);
  // --- FFN ---
  ln_kernel<<<2048, 256, 0, stream>>>(x1b, hb, ln_ffn_g, ln_ffn_b, 768);
  gemm_nt<<<dim3(48, 32, 1), 256, 0, stream>>>(hb, 768, 0, 0, w_ffn1, 768, 0, 0, mffn, 3072,
                                               0, 0, nullptr, 0, 0, 0, b_ffn1, 2048, 3072,
                                               768, 1.f, 1, 1);
  gemm_nt<<<dim3(12, 32, 1), 256, 0, stream>>>(mffn, 3072, 0, 0, w_ffn2, 3072, 0, 0, xo, 768,
                                               0, 0, x1b, 768, 0, 0, b_ffn2, 2048, 768, 3072,
                                               1.f, 0, 1);
  // --- outer product mean ---
  ln_kernel<<<2048, 256, 0, stream>>>(xo, hb, ln_opm_g, ln_opm_b, 768);
  gemm_nt<<<dim3(1, 32, 1), 256, 0, stream>>>(hb, 768, 0, 0, w_opm_in, 768, 0, 0, abb, 64,
                                              0, 0, nullptr, 0, 0, 0, b_opm_in, 2048, 64,
                                              768, 1.f, 0, 1);
  opmask_kernel<<<512, 256, 0, stream>>>(abb, op_mask);
  opm_T_kernel<<<dim3(256, 64, 1), dim3(32, 8, 1), 0, stream>>>(abb, w_opm_out, Tb);
  opm_update_kernel<<<dim3(2048, 8, 1), 256, 0, stream>>>(pair, Tb, abb, b_opm_out, op_norm,
                                                          pair1);
  // --- triangle multiplication (per batch, reusing arena) ---
  for (int b = 0; b < 4; ++b) {
    float* pb = pair1 + (long)b * NNe * 64;
    tm_ab_kernel<<<8192, 256, 0, stream>>>(pb, ln_tm_g, ln_tm_b, w_tm_abp, b_tm_abp,
                                           w_tm_abg, b_tm_abg, a_t, b_tt);
    tm_tri_kernel<<<dim3(8, 8, 32), 256, 0, stream>>>(a_t, b_tt, t_b);
    tm_update_kernel<<<8192, 256, 0, stream>>>(pb, t_b, ln_tm_g, ln_tm_b, w_tm_g, b_tm_g,
                                               ln_tmo_g, ln_tmo_b, w_tm_z, b_tm_z);
  }
  // --- pair transition ---
  pffn_kernel<<<32768, 256, 0, stream>>>(pair1, ln_pffn_g, ln_pffn_b, w_pffn1, b_pffn1,
                                         w_pffn2, b_pffn2);
}

// Round 2
// 3215.742 us; speedup vs baseline: 2.1326x; 2.1326x over previous
//
#include <hip/hip_runtime.h>
#include <hip/hip_bf16.h>
#include <math.h>

#define Nn 512
#define Ee 768
#define Pp 64
#define PHh 32
#define Hh 8
#define Dd 96
#define NNe 262144      // N*N
#define LNEPS 1e-5f

typedef __attribute__((ext_vector_type(8))) short bf8;
typedef __attribute__((ext_vector_type(4))) short bf4;
typedef __attribute__((ext_vector_type(4))) float f32x4;
#define MFMA(a,b,c) __builtin_amdgcn_mfma_f32_16x16x32_bf16(a,b,c,0,0,0)

__device__ __forceinline__ short f2bf(float f) {
  unsigned u = __builtin_bit_cast(unsigned, f);
  unsigned r = (u + 0x7fffu + ((u >> 16) & 1u)) >> 16;
  return (short)r;
}

__device__ __forceinline__ float wave_red_sum(float v) {
#pragma unroll
  for (int off = 32; off > 0; off >>= 1) v += __shfl_xor(v, off);
  return v;
}
__device__ __forceinline__ float wave_red_max(float v) {
#pragma unroll
  for (int off = 32; off > 0; off >>= 1) v = fmaxf(v, __shfl_xor(v, off));
  return v;
}
__device__ __forceinline__ float half_red_sum(float v) {
#pragma unroll
  for (int off = 16; off > 0; off >>= 1) v += __shfl_xor(v, off, 32);
  return v;
}
__device__ __forceinline__ float gelu_exact(float v) {
  return 0.5f * v * (1.f + erff(v * 0.70710678118654752f));
}
__device__ __forceinline__ float sigmoidf_(float v) {
  return 1.f / (1.f + expf(-v));
}

// ---------------- LayerNorm over last dim C ----------------
__global__ __launch_bounds__(256) void ln_kernel(const float* __restrict__ in,
                                                 float* __restrict__ out,
                                                 const float* __restrict__ gam,
                                                 const float* __restrict__ bet, int C) {
  int row = blockIdx.x;
  const float* xr = in + (long)row * C;
  float* yr = out + (long)row * C;
  float s = 0.f, ss = 0.f;
  for (int c = threadIdx.x; c < C; c += 256) { float v = xr[c]; s += v; ss += v * v; }
  s = wave_red_sum(s); ss = wave_red_sum(ss);
  __shared__ float sm[4][2];
  int wv = threadIdx.x >> 6, lane = threadIdx.x & 63;
  if (lane == 0) { sm[wv][0] = s; sm[wv][1] = ss; }
  __syncthreads();
  float ts = sm[0][0] + sm[1][0] + sm[2][0] + sm[3][0];
  float tss = sm[0][1] + sm[1][1] + sm[2][1] + sm[3][1];
  float mu = ts / C;
  float var = tss / C - mu * mu;
  float rs = rsqrtf(var + LNEPS);
  for (int c = threadIdx.x; c < C; c += 256) {
    float v = xr[c];
    yr[c] = (v - mu) * rs * gam[c] + bet[c];
  }
}

// ---------------- Generic fp32 tiled GEMMs (x-side) ----------------
#define TS 64
#define KS 16
__global__ __launch_bounds__(256) void gemm_nt(
    const float* __restrict__ A, int lda, long asB, long asH,
    const float* __restrict__ Bm, int ldb, long bsB, long bsH,
    float* __restrict__ C, int ldc, long csB, long csH,
    const float* __restrict__ resid, int ldr, long rsB, long rsH,
    const float* __restrict__ bias,
    int M, int N, int K, float alpha, int act, int Hdim) {
  int bz = blockIdx.z;
  int bb = bz / Hdim, hh = bz % Hdim;
  A += bb * asB + hh * asH;
  Bm += bb * bsB + hh * bsH;
  C += bb * csB + hh * csH;
  if (resid) resid += bb * rsB + hh * rsH;
  __shared__ float As[KS][TS + 1];
  __shared__ float Bs[KS][TS + 1];
  int m0 = blockIdx.y * TS, n0 = blockIdx.x * TS;
  int tid = threadIdx.x;
  int tx = tid & 15, ty = tid >> 4;
  float acc[4][4];
#pragma unroll
  for (int i = 0; i < 4; ++i)
#pragma unroll
    for (int j = 0; j < 4; ++j) acc[i][j] = 0.f;
  for (int k0 = 0; k0 < K; k0 += KS) {
    for (int l = tid; l < TS * KS; l += 256) {
      int r = l / KS, kk = l % KS;
      int gm = m0 + r, gn = n0 + r, gk = k0 + kk;
      As[kk][r] = (gm < M) ? A[(long)gm * lda + gk] : 0.f;
      Bs[kk][r] = (gn < N) ? Bm[(long)gn * ldb + gk] : 0.f;
    }
    __syncthreads();
#pragma unroll
    for (int kk = 0; kk < KS; ++kk) {
      float a[4], b[4];
#pragma unroll
      for (int i = 0; i < 4; ++i) { a[i] = As[kk][ty * 4 + i]; b[i] = Bs[kk][tx * 4 + i]; }
#pragma unroll
      for (int i = 0; i < 4; ++i)
#pragma unroll
        for (int j = 0; j < 4; ++j) acc[i][j] += a[i] * b[j];
    }
    __syncthreads();
  }
#pragma unroll
  for (int i = 0; i < 4; ++i)
#pragma unroll
    for (int j = 0; j < 4; ++j) {
      int gm = m0 + ty * 4 + i, gn = n0 + tx * 4 + j;
      if (gm < M && gn < N) {
        float v = acc[i][j] * alpha;
        if (bias) v += bias[gn];
        if (resid) v += resid[(long)gm * ldr + gn];
        if (act == 1) v = gelu_exact(v);
        C[(long)gm * ldc + gn] = v;
      }
    }
}

__global__ __launch_bounds__(256) void gemm_nn(
    const float* __restrict__ A, int lda, long asB, long asH,
    const float* __restrict__ Bm, int ldb, long bsB, long bsH,
    float* __restrict__ C, int ldc, long csB, long csH,
    const float* __restrict__ resid, int ldr, long rsB, long rsH,
    const float* __restrict__ bias,
    int M, int N, int K, float alpha, int act, int Hdim) {
  int bz = blockIdx.z;
  int bb = bz / Hdim, hh = bz % Hdim;
  A += bb * asB + hh * asH;
  Bm += bb * bsB + hh * bsH;
  C += bb * csB + hh * csH;
  if (resid) resid += bb * rsB + hh * rsH;
  __shared__ float As[KS][TS + 1];
  __shared__ float Bs[KS][TS + 1];
  int m0 = blockIdx.y * TS, n0 = blockIdx.x * TS;
  int tid = threadIdx.x;
  int tx = tid & 15, ty = tid >> 4;
  float acc[4][4];
#pragma unroll
  for (int i = 0; i < 4; ++i)
#pragma unroll
    for (int j = 0; j < 4; ++j) acc[i][j] = 0.f;
  for (int k0 = 0; k0 < K; k0 += KS) {
    for (int l = tid; l < TS * KS; l += 256) {
      int r = l / KS, kk = l % KS;
      int gm = m0 + r;
      As[kk][r] = (gm < M) ? A[(long)gm * lda + k0 + kk] : 0.f;
    }
    for (int l = tid; l < TS * KS; l += 256) {
      int n = l % TS, kk = l / TS;
      int gn = n0 + n;
      Bs[kk][n] = (gn < N) ? Bm[(long)(k0 + kk) * ldb + gn] : 0.f;
    }
    __syncthreads();
#pragma unroll
    for (int kk = 0; kk < KS; ++kk) {
      float a[4], b[4];
#pragma unroll
      for (int i = 0; i < 4; ++i) { a[i] = As[kk][ty * 4 + i]; b[i] = Bs[kk][tx * 4 + i]; }
#pragma unroll
      for (int i = 0; i < 4; ++i)
#pragma unroll
        for (int j = 0; j < 4; ++j) acc[i][j] += a[i] * b[j];
    }
    __syncthreads();
  }
#pragma unroll
  for (int i = 0; i < 4; ++i)
#pragma unroll
    for (int j = 0; j < 4; ++j) {
      int gm = m0 + ty * 4 + i, gn = n0 + tx * 4 + j;
      if (gm < M && gn < N) {
        float v = acc[i][j] * alpha;
        if (bias) v += bias[gn];
        if (resid) v += resid[(long)gm * ldr + gn];
        if (act == 1) v = gelu_exact(v);
        C[(long)gm * ldc + gn] = v;
      }
    }
}

// ---------------- softmax over last dim (512) with attn_mask add ----------------
__global__ __launch_bounds__(256) void softmax_kernel(float* __restrict__ sc,
                                                      const float* __restrict__ mask) {
  long row = blockIdx.x;
  int g = (int)(row >> 9);
  int i = (int)(row & 511);
  int b = g >> 3;
  float* p = sc + row * 512;
  const float* mk = mask + ((long)b * 512 + i) * 512;
  int t = threadIdx.x;
  float v0 = p[t] + mk[t];
  float v1 = p[t + 256] + mk[t + 256];
  float mx = fmaxf(v0, v1);
  mx = wave_red_max(mx);
  __shared__ float sm[4];
  __shared__ float sm2[4];
  int wv = t >> 6, lane = t & 63;
  if (lane == 0) sm[wv] = mx;
  __syncthreads();
  mx = fmaxf(fmaxf(sm[0], sm[1]), fmaxf(sm[2], sm[3]));
  float e0 = expf(v0 - mx), e1 = expf(v1 - mx);
  float s = wave_red_sum(e0 + e1);
  if (lane == 0) sm2[wv] = s;
  __syncthreads();
  s = sm2[0] + sm2[1] + sm2[2] + sm2[3];
  float inv = 1.f / s;
  p[t] = e0 * inv;
  p[t + 256] = e1 * inv;
}

__global__ __launch_bounds__(256) void og_kernel(float* __restrict__ gio,
                                                 const float* __restrict__ o, long n) {
  long idx = (long)blockIdx.x * 256 + threadIdx.x;
  if (idx < n) {
    float gv = gio[idx];
    gio[idx] = sigmoidf_(gv) * o[idx];
  }
}

__global__ __launch_bounds__(256) void opmask_kernel(float* __restrict__ ab,
                                                     const float* __restrict__ mask) {
  int idx = blockIdx.x * 256 + threadIdx.x;
  if (idx < 2048 * 64) ab[idx] *= mask[idx >> 6];
}

__global__ __launch_bounds__(256) void opm_T_kernel(const float* __restrict__ ab,
                                                    const float* __restrict__ w,
                                                    float* __restrict__ T) {
  int p = blockIdx.y;
  int row = blockIdx.x * 8 + threadIdx.y;
  int e = threadIdx.x;
  const float* a = ab + (long)row * 64;
  const float* wp = w + p * 1024 + e;
  float acc = 0.f;
#pragma unroll
  for (int d = 0; d < 32; ++d) acc += a[d] * wp[d * 32];
  T[((long)row * 64 + p) * 32 + e] = acc;
}

__global__ __launch_bounds__(256) void opm_update_kernel(
    const float* __restrict__ pair_in, const float* __restrict__ T,
    const float* __restrict__ ab, const float* __restrict__ b_out,
    const float* __restrict__ op_norm, float* __restrict__ pair1) {
  int bi = blockIdx.x;
  int b = bi >> 9;
  int j0 = blockIdx.y * 64;
  __shared__ float Ts[64][33];
  __shared__ float Bs[64][33];
  int tid = threadIdx.x;
  for (int l = tid; l < 2048; l += 256) Ts[l >> 5][l & 31] = T[(long)bi * 2048 + l];
  for (int l = tid; l < 2048; l += 256) {
    int j = l >> 5, e = l & 31;
    Bs[j][e] = ab[(long)(b * 512 + j0 + j) * 64 + 32 + e];
  }
  __syncthreads();
  int p = tid & 63, jg = tid >> 6;
  float acc[16];
#pragma unroll
  for (int jj = 0; jj < 16; ++jj) acc[jj] = 0.f;
  for (int e = 0; e < 32; ++e) {
    float tv = Ts[p][e];
#pragma unroll
    for (int jj = 0; jj < 16; ++jj) acc[jj] += tv * Bs[jg * 16 + jj][e];
  }
  float bo = b_out[p];
  float nrm = op_norm[0];
  long base = ((long)bi * 512 + j0) * 64;
#pragma unroll
  for (int jj = 0; jj < 16; ++jj) {
    long idx = base + (long)(jg * 16 + jj) * 64 + p;
    pair1[idx] = pair_in[idx] + (acc[jj] + bo) * nrm;
  }
}

// ================= MFMA pair-side kernels =================

// pair bias: bias[(b*8+h)*NNe + e] = LN(pair[e]) . wb[h] + bb[h]
__global__ __launch_bounds__(256) void pair_bias_mfma(
    const float* __restrict__ pair, const float* __restrict__ gam,
    const float* __restrict__ bet, const float* __restrict__ wb,
    const float* __restrict__ bbv, float* __restrict__ bias) {
  __shared__ __align__(16) float Xs[64 * 68];
  __shared__ __align__(16) short Zb[64 * 72];
  __shared__ __align__(16) short Wb[16 * 72];
  int tid = threadIdx.x;
  long e0 = (long)blockIdx.x * 64;
  int b = (int)(e0 >> 18);
  long ein = e0 & (NNe - 1);
  const float* base = pair + e0 * 64;
  for (int l = tid; l < 1024; l += 256) {
    int h = l >> 6, c = l & 63;
    Wb[h * 72 + c] = (h < 8) ? f2bf(wb[h * 64 + c]) : (short)0;
  }
#pragma unroll
  for (int i = 0; i < 4; ++i) {
    int idx = tid + i * 256;
    f32x4 v = *(const f32x4*)(base + idx * 4);
    *(f32x4*)&Xs[(idx >> 4) * 68 + (idx & 15) * 4] = v;
  }
  __syncthreads();
  int wv = tid >> 6, lane = tid & 63;
  float gl = gam[lane], bl = bet[lane];
  for (int e = wv * 16; e < wv * 16 + 16; ++e) {
    float v = Xs[e * 68 + lane];
    float s = wave_red_sum(v), ss = wave_red_sum(v * v);
    float mu = s * 0.015625f, var = ss * 0.015625f - mu * mu;
    Zb[e * 72 + lane] = f2bf((v - mu) * rsqrtf(var + LNEPS) * gl + bl);
  }
  __syncthreads();
  int lhi = lane >> 4, llo = lane & 15;
  int n0 = wv * 16;
  f32x4 acc = {0.f, 0.f, 0.f, 0.f};
#pragma unroll
  for (int ks = 0; ks < 2; ++ks) {
    bf8 a = *(const bf8*)&Wb[llo * 72 + ks * 32 + lhi * 8];
    bf8 bz = *(const bf8*)&Zb[(n0 + llo) * 72 + ks * 32 + lhi * 8];
    acc = MFMA(a, bz, acc);
  }
  int elem = n0 + llo;
#pragma unroll
  for (int r = 0; r < 4; ++r) {
    int h = lhi * 4 + r;
    if (h < 8) bias[(long)(b * 8 + h) * NNe + ein + elem] = acc[r] + bbv[h];
  }
}

// pffn: pair = pair + W2.(gelu(W1.LN(pair)+b1))+b2   (in place, 64 elems/block)
__global__ __launch_bounds__(256) void pffn_mfma(
    float* __restrict__ pairp, const float* __restrict__ gam,
    const float* __restrict__ bet, const float* __restrict__ w1,
    const float* __restrict__ b1, const float* __restrict__ w2,
    const float* __restrict__ b2) {
  __shared__ __align__(16) float Xs[64 * 68];
  __shared__ __align__(16) short Zb[64 * 72];
  __shared__ __align__(16) short W1b[64 * 72];
  __shared__ __align__(16) short W2b[64 * 72];
  int tid = threadIdx.x;
  long e0 = (long)blockIdx.x * 64;
  float* base = pairp + e0 * 64;
  for (int l = tid; l < 4096; l += 256) {
    W1b[(l >> 6) * 72 + (l & 63)] = f2bf(w1[l]);
    W2b[(l >> 6) * 72 + (l & 63)] = f2bf(w2[l]);
  }
#pragma unroll
  for (int i = 0; i < 4; ++i) {
    int idx = tid + i * 256;
    f32x4 v = *(const f32x4*)(base + idx * 4);
    *(f32x4*)&Xs[(idx >> 4) * 68 + (idx & 15) * 4] = v;
  }
  __syncthreads();
  int wv = tid >> 6, lane = tid & 63;
  float gl = gam[lane], bl = bet[lane];
  for (int e = wv * 16; e < wv * 16 + 16; ++e) {
    float v = Xs[e * 68 + lane];
    float s = wave_red_sum(v), ss = wave_red_sum(v * v);
    float mu = s * 0.015625f, var = ss * 0.015625f - mu * mu;
    Zb[e * 72 + lane] = f2bf((v - mu) * rsqrtf(var + LNEPS) * gl + bl);
  }
  __syncthreads();
  int wr = wv >> 1, wc = wv & 1;
  int lhi = lane >> 4, llo = lane & 15;
  f32x4 acc[2][2] = {};
#pragma unroll
  for (int ks = 0; ks < 2; ++ks) {
    bf8 a0 = *(const bf8*)&W1b[(wr * 32 + llo) * 72 + ks * 32 + lhi * 8];
    bf8 a1 = *(const bf8*)&W1b[(wr * 32 + 16 + llo) * 72 + ks * 32 + lhi * 8];
    bf8 z0 = *(const bf8*)&Zb[(wc * 32 + llo) * 72 + ks * 32 + lhi * 8];
    bf8 z1 = *(const bf8*)&Zb[(wc * 32 + 16 + llo) * 72 + ks * 32 + lhi * 8];
    acc[0][0] = MFMA(a0, z0, acc[0][0]);
    acc[0][1] = MFMA(a0, z1, acc[0][1]);
    acc[1][0] = MFMA(a1, z0, acc[1][0]);
    acc[1][1] = MFMA(a1, z1, acc[1][1]);
  }
  __syncthreads();  // all Zb reads done before overwrite as G
#pragma unroll
  for (int mi = 0; mi < 2; ++mi) {
    int chb = wr * 32 + mi * 16 + lhi * 4;
    f32x4 bv = *(const f32x4*)(b1 + chb);
#pragma unroll
    for (int ni = 0; ni < 2; ++ni) {
      int elem = wc * 32 + ni * 16 + llo;
      bf4 pack;
#pragma unroll
      for (int r = 0; r < 4; ++r)
        pack[r] = f2bf(gelu_exact(acc[mi][ni][r] + bv[r]));
      *(bf4*)&Zb[elem * 72 + chb] = pack;
    }
  }
  __syncthreads();
  f32x4 acc2[2][2] = {};
#pragma unroll
  for (int ks = 0; ks < 2; ++ks) {
    bf8 a0 = *(const bf8*)&W2b[(wr * 32 + llo) * 72 + ks * 32 + lhi * 8];
    bf8 a1 = *(const bf8*)&W2b[(wr * 32 + 16 + llo) * 72 + ks * 32 + lhi * 8];
    bf8 z0 = *(const bf8*)&Zb[(wc * 32 + llo) * 72 + ks * 32 + lhi * 8];
    bf8 z1 = *(const bf8*)&Zb[(wc * 32 + 16 + llo) * 72 + ks * 32 + lhi * 8];
    acc2[0][0] = MFMA(a0, z0, acc2[0][0]);
    acc2[0][1] = MFMA(a0, z1, acc2[0][1]);
    acc2[1][0] = MFMA(a1, z0, acc2[1][0]);
    acc2[1][1] = MFMA(a1, z1, acc2[1][1]);
  }
#pragma unroll
  for (int mi = 0; mi < 2; ++mi) {
    int chb = wr * 32 + mi * 16 + lhi * 4;
    f32x4 bv = *(const f32x4*)(b2 + chb);
#pragma unroll
    for (int ni = 0; ni < 2; ++ni) {
      int elem = wc * 32 + ni * 16 + llo;
      f32x4 res = *(const f32x4*)&Xs[elem * 68 + chb];
      f32x4 o;
#pragma unroll
      for (int r = 0; r < 4; ++r) o[r] = res[r] + acc2[mi][ni][r] + bv[r];
      *(f32x4*)(base + (long)elem * 64 + chb) = o;
    }
  }
}

// tm_ab: val = (LN(p).Wp+bp)*sigmoid(LN(p).Wg+bg) -> aN/bN bf16 [32][NNe]
__global__ __launch_bounds__(256) void tm_ab_mfma(
    const float* __restrict__ pb, const float* __restrict__ gam,
    const float* __restrict__ bet, const float* __restrict__ w_abp,
    const float* __restrict__ b_abp, const float* __restrict__ w_abg,
    const float* __restrict__ b_abg, short* __restrict__ aN,
    short* __restrict__ bN) {
  __shared__ __align__(16) float Xs[64 * 68];
  __shared__ __align__(16) short Zb[64 * 72];
  __shared__ __align__(16) short Wp[64 * 72];
  __shared__ __align__(16) short Wg[64 * 72];
  int tid = threadIdx.x;
  long e0 = (long)blockIdx.x * 64;
  const float* base = pb + e0 * 64;
  for (int l = tid; l < 4096; l += 256) {
    Wp[(l >> 6) * 72 + (l & 63)] = f2bf(w_abp[l]);
    Wg[(l >> 6) * 72 + (l & 63)] = f2bf(w_abg[l]);
  }
#pragma unroll
  for (int i = 0; i < 4; ++i) {
    int idx = tid + i * 256;
    f32x4 v = *(const f32x4*)(base + idx * 4);
    *(f32x4*)&Xs[(idx >> 4) * 68 + (idx & 15) * 4] = v;
  }
  __syncthreads();
  int wv = tid >> 6, lane = tid & 63;
  float gl = gam[lane], bl = bet[lane];
  for (int e = wv * 16; e < wv * 16 + 16; ++e) {
    float v = Xs[e * 68 + lane];
    float s = wave_red_sum(v), ss = wave_red_sum(v * v);
    float mu = s * 0.015625f, var = ss * 0.015625f - mu * mu;
    Zb[e * 72 + lane] = f2bf((v - mu) * rsqrtf(var + LNEPS) * gl + bl);
  }
  __syncthreads();
  int wr = wv >> 1, wc = wv & 1;
  int lhi = lane >> 4, llo = lane & 15;
  f32x4 ap[2][2] = {};
  f32x4 ag[2][2] = {};
#pragma unroll
  for (int ks = 0; ks < 2; ++ks) {
    bf8 z0 = *(const bf8*)&Zb[(wr * 32 + llo) * 72 + ks * 32 + lhi * 8];
    bf8 z1 = *(const bf8*)&Zb[(wr * 32 + 16 + llo) * 72 + ks * 32 + lhi * 8];
    bf8 p0 = *(const bf8*)&Wp[(wc * 32 + llo) * 72 + ks * 32 + lhi * 8];
    bf8 p1 = *(const bf8*)&Wp[(wc * 32 + 16 + llo) * 72 + ks * 32 + lhi * 8];
    bf8 g0 = *(const bf8*)&Wg[(wc * 32 + llo) * 72 + ks * 32 + lhi * 8];
    bf8 g1 = *(const bf8*)&Wg[(wc * 32 + 16 + llo) * 72 + ks * 32 + lhi * 8];
    ap[0][0] = MFMA(z0, p0, ap[0][0]);
    ap[0][1] = MFMA(z0, p1, ap[0][1]);
    ap[1][0] = MFMA(z1, p0, ap[1][0]);
    ap[1][1] = MFMA(z1, p1, ap[1][1]);
    ag[0][0] = MFMA(z0, g0, ag[0][0]);
    ag[0][1] = MFMA(z0, g1, ag[0][1]);
    ag[1][0] = MFMA(z1, g0, ag[1][0]);
    ag[1][1] = MFMA(z1, g1, ag[1][1]);
  }
#pragma unroll
  for (int mi = 0; mi < 2; ++mi) {
    int elemb = wr * 32 + mi * 16 + lhi * 4;
#pragma unroll
    for (int ni = 0; ni < 2; ++ni) {
      int ch = wc * 32 + ni * 16 + llo;
      float bp = b_abp[ch], bg = b_abg[ch];
      bf4 pack;
#pragma unroll
      for (int r = 0; r < 4; ++r)
        pack[r] = f2bf((ap[mi][ni][r] + bp) * sigmoidf_(ag[mi][ni][r] + bg));
      short* dst = (ch < 32) ? (aN + (long)ch * NNe) : (bN + (long)(ch - 32) * NNe);
      *(bf4*)(dst + e0 + elemb) = pack;
    }
  }
}

// triangle einsum: t[h,i,k] = sum_j aN[h,i,j]bN[h,k,j] + aN[h,j,i]bN[h,j,k]
__global__ __launch_bounds__(256) void tm_tri_mfma(const short* __restrict__ aN,
                                                   const short* __restrict__ bN,
                                                   float* __restrict__ t_out) {
  int h = blockIdx.z;
  int i0 = blockIdx.y * 64, k0 = blockIdx.x * 64;
  const short* A = aN + (long)h * NNe;
  const short* B = bN + (long)h * NNe;
  __shared__ __align__(16) short A1[64 * 40];
  __shared__ __align__(16) short B1[64 * 40];
  __shared__ __align__(16) short A2[64 * 40];
  __shared__ __align__(16) short B2[64 * 40];
  int tid = threadIdx.x;
  int wv = tid >> 6, lane = tid & 63;
  int wr = wv >> 1, wc = wv & 1;
  int lhi = lane >> 4, llo = lane & 15;
  int r1 = tid >> 2, cp = (tid & 3) * 8;
  int rr = tid >> 3, ip = (tid & 7) * 8;
  f32x4 acc[2][2] = {};
  for (int j0 = 0; j0 < 512; j0 += 32) {
    *(bf8*)&A1[r1 * 40 + cp] = *(const bf8*)(A + (long)(i0 + r1) * 512 + j0 + cp);
    *(bf8*)&B1[r1 * 40 + cp] = *(const bf8*)(B + (long)(k0 + r1) * 512 + j0 + cp);
    bf8 va = *(const bf8*)(A + (long)(j0 + rr) * 512 + i0 + ip);
    bf8 vb = *(const bf8*)(B + (long)(j0 + rr) * 512 + k0 + ip);
#pragma unroll
    for (int q = 0; q < 8; ++q) {
      A2[(ip + q) * 40 + rr] = va[q];
      B2[(ip + q) * 40 + rr] = vb[q];
    }
    __syncthreads();
    bf8 a0 = *(const bf8*)&A1[(wr * 32 + llo) * 40 + lhi * 8];
    bf8 a1 = *(const bf8*)&A1[(wr * 32 + 16 + llo) * 40 + lhi * 8];
    bf8 b0 = *(const bf8*)&B1[(wc * 32 + llo) * 40 + lhi * 8];
    bf8 b1 = *(const bf8*)&B1[(wc * 32 + 16 + llo) * 40 + lhi * 8];
    acc[0][0] = MFMA(a0, b0, acc[0][0]);
    acc[0][1] = MFMA(a0, b1, acc[0][1]);
    acc[1][0] = MFMA(a1, b0, acc[1][0]);
    acc[1][1] = MFMA(a1, b1, acc[1][1]);
    bf8 c0 = *(const bf8*)&A2[(wr * 32 + llo) * 40 + lhi * 8];
    bf8 c1 = *(const bf8*)&A2[(wr * 32 + 16 + llo) * 40 + lhi * 8];
    bf8 d0 = *(const bf8*)&B2[(wc * 32 + llo) * 40 + lhi * 8];
    bf8 d1 = *(const bf8*)&B2[(wc * 32 + 16 + llo) * 40 + lhi * 8];
    acc[0][0] = MFMA(c0, d0, acc[0][0]);
    acc[0][1] = MFMA(c0, d1, acc[0][1]);
    acc[1][0] = MFMA(c1, d0, acc[1][0]);
    acc[1][1] = MFMA(c1, d1, acc[1][1]);
    __syncthreads();
  }
  float* tp = t_out + (long)h * NNe;
#pragma unroll
  for (int mi = 0; mi < 2; ++mi)
#pragma unroll
    for (int ni = 0; ni < 2; ++ni) {
      int row = i0 + wr * 32 + mi * 16 + lhi * 4;
      int col = k0 + wc * 32 + ni * 16 + llo;
#pragma unroll
      for (int r = 0; r < 4; ++r) tp[(long)(row + r) * 512 + col] = acc[mi][ni][r];
    }
}

// tm_update: pair = pair + (LN(pair).Wgate+bg) * (LN32(t).Wz + bz)   (in place)
__global__ __launch_bounds__(256) void tm_update_mfma(
    float* __restrict__ pb, const float* __restrict__ t_in,
    const float* __restrict__ gam, const float* __restrict__ bet,
    const float* __restrict__ w_g, const float* __restrict__ b_g,
    const float* __restrict__ g_tmo, const float* __restrict__ b_tmo,
    const float* __restrict__ w_z, const float* __restrict__ b_z) {
  __shared__ __align__(16) float Xs[64 * 68];
  __shared__ __align__(16) float Ts[64 * 36];
  __shared__ __align__(16) short Zb[64 * 72];
  __shared__ __align__(16) short Tlb[64 * 40];
  __shared__ __align__(16) short Wgb[64 * 72];
  __shared__ __align__(16) short Wzb[64 * 40];
  int tid = threadIdx.x;
  long e0 = (long)blockIdx.x * 64;
  float* base = pb + e0 * 64;
  for (int l = tid; l < 4096; l += 256) Wgb[(l >> 6) * 72 + (l & 63)] = f2bf(w_g[l]);
  for (int l = tid; l < 2048; l += 256) Wzb[(l >> 5) * 40 + (l & 31)] = f2bf(w_z[l]);
#pragma unroll
  for (int i = 0; i < 4; ++i) {
    int idx = tid + i * 256;
    f32x4 v = *(const f32x4*)(base + idx * 4);
    *(f32x4*)&Xs[(idx >> 4) * 68 + (idx & 15) * 4] = v;
  }
  for (int l = tid; l < 2048; l += 256) {
    int hh = l >> 6, e = l & 63;
    Ts[e * 36 + hh] = t_in[(long)hh * NNe + e0 + e];
  }
  __syncthreads();
  int wv = tid >> 6, lane = tid & 63;
  float gl = gam[lane], bl = bet[lane];
  for (int e = wv * 16; e < wv * 16 + 16; ++e) {
    float v = Xs[e * 68 + lane];
    float s = wave_red_sum(v), ss = wave_red_sum(v * v);
    float mu = s * 0.015625f, var = ss * 0.015625f - mu * mu;
    Zb[e * 72 + lane] = f2bf((v - mu) * rsqrtf(var + LNEPS) * gl + bl);
  }
  {
    int ch = lane & 31;
    int sel = lane >> 5;
    float go = g_tmo[ch], bo = b_tmo[ch];
    for (int it = 0; it < 8; ++it) {
      int e = wv * 16 + it * 2 + sel;
      float v = Ts[e * 36 + ch];
      float s = half_red_sum(v), ss = half_red_sum(v * v);
      float mu = s * 0.03125f, var = ss * 0.03125f - mu * mu;
      Tlb[e * 40 + ch] = f2bf((v - mu) * rsqrtf(var + LNEPS) * go + bo);
    }
  }
  __syncthreads();
  int wr = wv >> 1, wc = wv & 1;
  int lhi = lane >> 4, llo = lane & 15;
  f32x4 accg[2][2] = {};
  f32x4 accz[2][2] = {};
#pragma unroll
  for (int ks = 0; ks < 2; ++ks) {
    bf8 a0 = *(const bf8*)&Wgb[(wr * 32 + llo) * 72 + ks * 32 + lhi * 8];
    bf8 a1 = *(const bf8*)&Wgb[(wr * 32 + 16 + llo) * 72 + ks * 32 + lhi * 8];
    bf8 z0 = *(const bf8*)&Zb[(wc * 32 + llo) * 72 + ks * 32 + lhi * 8];
    bf8 z1 = *(const bf8*)&Zb[(wc * 32 + 16 + llo) * 72 + ks * 32 + lhi * 8];
    accg[0][0] = MFMA(a0, z0, accg[0][0]);
    accg[0][1] = MFMA(a0, z1, accg[0][1]);
    accg[1][0] = MFMA(a1, z0, accg[1][0]);
    accg[1][1] = MFMA(a1, z1, accg[1][1]);
  }
  {
    bf8 a0 = *(const bf8*)&Wzb[(wr * 32 + llo) * 40 + lhi * 8];
    bf8 a1 = *(const bf8*)&Wzb[(wr * 32 + 16 + llo) * 40 + lhi * 8];
    bf8 t0 = *(const bf8*)&Tlb[(wc * 32 + llo) * 40 + lhi * 8];
    bf8 t1 = *(const bf8*)&Tlb[(wc * 32 + 16 + llo) * 40 + lhi * 8];
    accz[0][0] = MFMA(a0, t0, accz[0][0]);
    accz[0][1] = MFMA(a0, t1, accz[0][1]);
    accz[1][0] = MFMA(a1, t0, accz[1][0]);
    accz[1][1] = MFMA(a1, t1, accz[1][1]);
  }
#pragma unroll
  for (int mi = 0; mi < 2; ++mi) {
    int chb = wr * 32 + mi * 16 + lhi * 4;
    f32x4 bgv = *(const f32x4*)(b_g + chb);
    f32x4 bzv = *(const f32x4*)(b_z + chb);
#pragma unroll
    for (int ni = 0; ni < 2; ++ni) {
      int elem = wc * 32 + ni * 16 + llo;
      f32x4 res = *(const f32x4*)&Xs[elem * 68 + chb];
      f32x4 o;
#pragma unroll
      for (int r = 0; r < 4; ++r)
        o[r] = res[r] + (accg[mi][ni][r] + bgv[r]) * (accz[mi][ni][r] + bzv[r]);
      *(f32x4*)(base + (long)elem * 64 + chb) = o;
    }
  }
}

extern "C" void kernel_launch(void* const* d_in, const int* in_sizes, int n_in,
                              void* d_out, int out_size, void* d_ws, size_t ws_size,
                              hipStream_t stream) {
  const float* x = (const float*)d_in[0];
  const float* pair = (const float*)d_in[1];
  const float* attn_mask = (const float*)d_in[2];
  const float* op_mask = (const float*)d_in[3];
  const float* op_norm = (const float*)d_in[4];
  const float* wq = (const float*)d_in[6];
  const float* wk = (const float*)d_in[7];
  const float* wv_ = (const float*)d_in[8];
  const float* wg = (const float*)d_in[9];
  const float* bg = (const float*)d_in[10];
  const float* wo = (const float*)d_in[11];
  const float* bo = (const float*)d_in[12];
  const float* ln_pair_g = (const float*)d_in[13];
  const float* ln_pair_b = (const float*)d_in[14];
  const float* wb = (const float*)d_in[15];
  const float* bb = (const float*)d_in[16];
  const float* ln_attn_g = (const float*)d_in[17];
  const float* ln_attn_b = (const float*)d_in[18];
  const float* ln_ffn_g = (const float*)d_in[19];
  const float* ln_ffn_b = (const float*)d_in[20];
  const float* w_ffn1 = (const float*)d_in[21];
  const float* b_ffn1 = (const float*)d_in[22];
  const float* w_ffn2 = (const float*)d_in[23];
  const float* b_ffn2 = (const float*)d_in[24];
  const float* ln_opm_g = (const float*)d_in[25];
  const float* ln_opm_b = (const float*)d_in[26];
  const float* w_opm_in = (const float*)d_in[27];
  const float* b_opm_in = (const float*)d_in[28];
  const float* w_opm_out = (const float*)d_in[29];
  const float* b_opm_out = (const float*)d_in[30];
  const float* ln_tm_g = (const float*)d_in[31];
  const float* ln_tm_b = (const float*)d_in[32];
  const float* w_tm_abp = (const float*)d_in[33];
  const float* b_tm_abp = (const float*)d_in[34];
  const float* w_tm_abg = (const float*)d_in[35];
  const float* b_tm_abg = (const float*)d_in[36];
  const float* w_tm_g = (const float*)d_in[37];
  const float* b_tm_g = (const float*)d_in[38];
  const float* w_tm_z = (const float*)d_in[39];
  const float* b_tm_z = (const float*)d_in[40];
  const float* ln_tmo_g = (const float*)d_in[41];
  const float* ln_tmo_b = (const float*)d_in[42];
  const float* ln_pffn_g = (const float*)d_in[43];
  const float* ln_pffn_b = (const float*)d_in[44];
  const float* w_pffn1 = (const float*)d_in[45];
  const float* b_pffn1 = (const float*)d_in[46];
  const float* w_pffn2 = (const float*)d_in[47];
  const float* b_pffn2 = (const float*)d_in[48];

  float* ws = (float*)d_ws;
  float* hb = ws;                    // 1572864
  float* qb = ws + 1572864;
  float* kb = ws + 3145728;
  float* vb = ws + 4718592;
  float* gb = ws + 6291456;
  float* biasb = ws + 7864320;       // 8388608
  float* ob = ws + 16252928;
  float* x1b = ws + 17825792;
  float* mffn = ws + 19398656;       // 6291456
  float* abb = ws + 25690112;        // 131072
  float* Tb = ws + 25821184;         // 4194304
  // triangle-stage reuse:
  short* aNb = (short*)ws;                    // 8388608 shorts = 4194304 floats
  short* bNb = (short*)(ws + 4194304);        // same size
  float* t_b = ws + 8388608;                  // 8388608 floats

  float* xo = (float*)d_out;
  float* pair1 = xo + 1572864;

  const float qscale = 0.1020620726159658f;  // 96^-0.5

  // --- attention ---
  ln_kernel<<<2048, 256, 0, stream>>>(x, hb, ln_attn_g, ln_attn_b, 768);
  gemm_nt<<<dim3(12, 32, 1), 256, 0, stream>>>(hb, 768, 0, 0, wq, 768, 0, 0, qb, 768, 0, 0,
                                               nullptr, 0, 0, 0, nullptr, 2048, 768, 768,
                                               qscale, 0, 1);
  gemm_nt<<<dim3(12, 32, 1), 256, 0, stream>>>(hb, 768, 0, 0, wk, 768, 0, 0, kb, 768, 0, 0,
                                               nullptr, 0, 0, 0, nullptr, 2048, 768, 768,
                                               1.f, 0, 1);
  gemm_nt<<<dim3(12, 32, 1), 256, 0, stream>>>(hb, 768, 0, 0, wv_, 768, 0, 0, vb, 768, 0, 0,
                                               nullptr, 0, 0, 0, nullptr, 2048, 768, 768,
                                               1.f, 0, 1);
  gemm_nt<<<dim3(12, 32, 1), 256, 0, stream>>>(hb, 768, 0, 0, wg, 768, 0, 0, gb, 768, 0, 0,
                                               nullptr, 0, 0, 0, bg, 2048, 768, 768,
                                               1.f, 0, 1);
  pair_bias_mfma<<<16384, 256, 0, stream>>>(pair, ln_pair_g, ln_pair_b, wb, bb, biasb);
  gemm_nt<<<dim3(8, 8, 32), 256, 0, stream>>>(qb, 768, 393216, 96, kb, 768, 393216, 96,
                                              biasb, 512, 2097152, 262144,
                                              biasb, 512, 2097152, 262144, nullptr,
                                              512, 512, 96, 1.f, 0, 8);
  softmax_kernel<<<16384, 256, 0, stream>>>(biasb, attn_mask);
  gemm_nn<<<dim3(2, 8, 32), 256, 0, stream>>>(biasb, 512, 2097152, 262144, vb, 768, 393216, 96,
                                              ob, 768, 393216, 96, nullptr, 0, 0, 0, nullptr,
                                              512, 96, 512, 1.f, 0, 8);
  og_kernel<<<6144, 256, 0, stream>>>(gb, ob, 1572864);
  gemm_nt<<<dim3(12, 32, 1), 256, 0, stream>>>(gb, 768, 0, 0, wo, 768, 0, 0, x1b, 768, 0, 0,
                                               x, 768, 0, 0, bo, 2048, 768, 768, 1.f, 0, 1);
  // --- FFN ---
  ln_kernel<<<2048, 256, 0, stream>>>(x1b, hb, ln_ffn_g, ln_ffn_b, 768);
  gemm_nt<<<dim3(48, 32, 1), 256, 0, stream>>>(hb, 768, 0, 0, w_ffn1, 768, 0, 0, mffn, 3072,
                                               0, 0, nullptr, 0, 0, 0, b_ffn1, 2048, 3072,
                                               768, 1.f, 1, 1);
  gemm_nt<<<dim3(12, 32, 1), 256, 0, stream>>>(mffn, 3072, 0, 0, w_ffn2, 3072, 0, 0, xo, 768,
                                               0, 0, x1b, 768, 0, 0, b_ffn2, 2048, 768, 3072,
                                               1.f, 0, 1);
  // --- outer product mean ---
  ln_kernel<<<2048, 256, 0, stream>>>(xo, hb, ln_opm_g, ln_opm_b, 768);
  gemm_nt<<<dim3(1, 32, 1), 256, 0, stream>>>(hb, 768, 0, 0, w_opm_in, 768, 0, 0, abb, 64,
                                              0, 0, nullptr, 0, 0, 0, b_opm_in, 2048, 64,
                                              768, 1.f, 0, 1);
  opmask_kernel<<<512, 256, 0, stream>>>(abb, op_mask);
  opm_T_kernel<<<dim3(256, 64, 1), dim3(32, 8, 1), 0, stream>>>(abb, w_opm_out, Tb);
  opm_update_kernel<<<dim3(2048, 8, 1), 256, 0, stream>>>(pair, Tb, abb, b_opm_out, op_norm,
                                                          pair1);
  // --- triangle multiplication (per batch, reusing arena) ---
  for (int b = 0; b < 4; ++b) {
    float* pbb = pair1 + (long)b * NNe * 64;
    tm_ab_mfma<<<4096, 256, 0, stream>>>(pbb, ln_tm_g, ln_tm_b, w_tm_abp, b_tm_abp,
                                         w_tm_abg, b_tm_abg, aNb, bNb);
    tm_tri_mfma<<<dim3(8, 8, 32), 256, 0, stream>>>(aNb, bNb, t_b);
    tm_update_mfma<<<4096, 256, 0, stream>>>(pbb, t_b, ln_tm_g, ln_tm_b, w_tm_g, b_tm_g,
                                             ln_tmo_g, ln_tmo_b, w_tm_z, b_tm_z);
  }
  // --- pair transition ---
  pffn_mfma<<<16384, 256, 0, stream>>>(pair1, ln_pffn_g, ln_pffn_b, w_pffn1, b_pffn1,
                                       w_pffn2, b_pffn2);
}

// Round 3
// 1745.311 us; speedup vs baseline: 3.9294x; 1.8425x over previous
//
#include <hip/hip_runtime.h>
#include <hip/hip_bf16.h>
#include <math.h>

#define Nn 512
#define Ee 768
#define Pp 64
#define PHh 32
#define Hh 8
#define Dd 96
#define NNe 262144      // N*N
#define LNEPS 1e-5f

typedef __attribute__((ext_vector_type(8))) short bf8;
typedef __attribute__((ext_vector_type(4))) short bf4;
typedef __attribute__((ext_vector_type(4))) float f32x4;
#define MFMA(a,b,c) __builtin_amdgcn_mfma_f32_16x16x32_bf16(a,b,c,0,0,0)

__device__ __forceinline__ short f2bf(float f) {
  unsigned u = __builtin_bit_cast(unsigned, f);
  unsigned r = (u + 0x7fffu + ((u >> 16) & 1u)) >> 16;
  return (short)r;
}

__device__ __forceinline__ float wave_red_sum(float v) {
#pragma unroll
  for (int off = 32; off > 0; off >>= 1) v += __shfl_xor(v, off);
  return v;
}
__device__ __forceinline__ float wave_red_max(float v) {
#pragma unroll
  for (int off = 32; off > 0; off >>= 1) v = fmaxf(v, __shfl_xor(v, off));
  return v;
}
__device__ __forceinline__ float half_red_sum(float v) {
#pragma unroll
  for (int off = 16; off > 0; off >>= 1) v += __shfl_xor(v, off, 32);
  return v;
}
__device__ __forceinline__ float gelu_exact(float v) {
  return 0.5f * v * (1.f + erff(v * 0.70710678118654752f));
}
__device__ __forceinline__ float sigmoidf_(float v) {
  return 1.f / (1.f + expf(-v));
}

// ---------------- weight cast to bf16 arena ----------------
__global__ __launch_bounds__(256) void castw_kernel(
    const float* __restrict__ wq, const float* __restrict__ wk,
    const float* __restrict__ wv, const float* __restrict__ wg,
    const float* __restrict__ wo, const float* __restrict__ f1,
    const float* __restrict__ f2, const float* __restrict__ wop,
    short* __restrict__ dst, float qs) {
  long i = (long)blockIdx.x * 256 + threadIdx.x;
  float v;
  if (i < 589824) v = wq[i] * qs;
  else if (i < 1179648) v = wk[i - 589824];
  else if (i < 1769472) v = wv[i - 1179648];
  else if (i < 2359296) v = wg[i - 1769472];
  else if (i < 2949120) v = wo[i - 2359296];
  else if (i < 5308416) v = f1[i - 2949120];
  else if (i < 7667712) v = f2[i - 5308416];
  else if (i < 7716864) v = wop[i - 7667712];
  else return;
  dst[i] = f2bf(v);
}

// ---------------- LayerNorm over last dim C -> bf16 out ----------------
__global__ __launch_bounds__(256) void ln_bf_kernel(const float* __restrict__ in,
                                                    short* __restrict__ out,
                                                    const float* __restrict__ gam,
                                                    const float* __restrict__ bet, int C) {
  int row = blockIdx.x;
  const float* xr = in + (long)row * C;
  short* yr = out + (long)row * C;
  float s = 0.f, ss = 0.f;
  for (int c = threadIdx.x; c < C; c += 256) { float v = xr[c]; s += v; ss += v * v; }
  s = wave_red_sum(s); ss = wave_red_sum(ss);
  __shared__ float sm[4][2];
  int wv = threadIdx.x >> 6, lane = threadIdx.x & 63;
  if (lane == 0) { sm[wv][0] = s; sm[wv][1] = ss; }
  __syncthreads();
  float ts = sm[0][0] + sm[1][0] + sm[2][0] + sm[3][0];
  float tss = sm[0][1] + sm[1][1] + sm[2][1] + sm[3][1];
  float mu = ts / C;
  float var = tss / C - mu * mu;
  float rs = rsqrtf(var + LNEPS);
  for (int c = threadIdx.x; c < C; c += 256) {
    float v = xr[c];
    yr[c] = f2bf((v - mu) * rs * gam[c] + bet[c]);
  }
}

// ---------------- bf16 MFMA NT GEMM: C[M,N] = act(A[M,K]·B[N,K]^T + bias + resid) ----
// outputs optional fp32 (outF) and/or bf16 (outB); vtrans writes V^T layout for AV.
__global__ __launch_bounds__(256) void gemm_bf(
    const short* __restrict__ A, int lda, long asB, long asH,
    const short* __restrict__ Bm, int ldb, long bsB, long bsH,
    float* __restrict__ outF, int ldf, long fsB, long fsH,
    short* __restrict__ outB, int ldob,
    const float* __restrict__ resid, int ldr, long rsB, long rsH,
    const float* __restrict__ bias,
    int M, int N, int K, int act, int vtrans, int Hdim) {
  int bz = blockIdx.z, bb = bz / Hdim, hh = bz % Hdim;
  A += bb * asB + hh * asH;
  Bm += bb * bsB + hh * bsH;
  if (outF) outF += bb * fsB + hh * fsH;
  if (resid) resid += bb * rsB + hh * rsH;
  __shared__ __align__(16) short As[64 * 40];
  __shared__ __align__(16) short Bs[64 * 40];
  int m0 = blockIdx.y * 64, n0 = blockIdx.x * 64;
  int tid = threadIdx.x;
  int wv = tid >> 6, lane = tid & 63;
  int wr = wv >> 1, wc = wv & 1;
  int lhi = lane >> 4, llo = lane & 15;
  int r4 = tid >> 2, c8 = (tid & 3) * 8;
  f32x4 acc[2][2] = {};
  for (int k0 = 0; k0 < K; k0 += 32) {
    *(bf8*)&As[r4 * 40 + c8] = *(const bf8*)(A + (long)(m0 + r4) * lda + k0 + c8);
    bf8 bv = {};
    if (n0 + r4 < N) bv = *(const bf8*)(Bm + (long)(n0 + r4) * ldb + k0 + c8);
    *(bf8*)&Bs[r4 * 40 + c8] = bv;
    __syncthreads();
    bf8 a0 = *(const bf8*)&As[(wr * 32 + llo) * 40 + lhi * 8];
    bf8 a1 = *(const bf8*)&As[(wr * 32 + 16 + llo) * 40 + lhi * 8];
    bf8 b0 = *(const bf8*)&Bs[(wc * 32 + llo) * 40 + lhi * 8];
    bf8 b1 = *(const bf8*)&Bs[(wc * 32 + 16 + llo) * 40 + lhi * 8];
    acc[0][0] = MFMA(a0, b0, acc[0][0]);
    acc[0][1] = MFMA(a0, b1, acc[0][1]);
    acc[1][0] = MFMA(a1, b0, acc[1][0]);
    acc[1][1] = MFMA(a1, b1, acc[1][1]);
    __syncthreads();
  }
#pragma unroll
  for (int mi = 0; mi < 2; ++mi) {
    int gmb = m0 + wr * 32 + mi * 16 + lhi * 4;
#pragma unroll
    for (int ni = 0; ni < 2; ++ni) {
      int gn = n0 + wc * 32 + ni * 16 + llo;
      if (gn >= N) continue;
      float bv = bias ? bias[gn] : 0.f;
      float vr[4];
#pragma unroll
      for (int r = 0; r < 4; ++r) {
        float v = acc[mi][ni][r] + bv;
        if (resid) v += resid[(long)(gmb + r) * ldr + gn];
        if (act == 1) v = gelu_exact(v);
        vr[r] = v;
      }
      if (outF) {
#pragma unroll
        for (int r = 0; r < 4; ++r) outF[(long)(gmb + r) * ldf + gn] = vr[r];
      }
      if (outB) {
        if (vtrans) {
          bf4 pk;
#pragma unroll
          for (int r = 0; r < 4; ++r) pk[r] = f2bf(vr[r]);
          *(bf4*)(outB + ((long)((gmb >> 9) * 768 + gn) * 512 + (gmb & 511))) = pk;
        } else {
#pragma unroll
          for (int r = 0; r < 4; ++r) outB[(long)(gmb + r) * ldob + gn] = f2bf(vr[r]);
        }
      }
    }
  }
}

// ---------------- softmax over last dim (512) with attn_mask add -> bf16 ----------------
__global__ __launch_bounds__(256) void softmax_bf(const float* __restrict__ sc,
                                                  const float* __restrict__ mask,
                                                  short* __restrict__ out) {
  long row = blockIdx.x;
  int i = (int)(row & 511);
  int b = (int)(row >> 12);
  const float* p = sc + row * 512;
  const float* mk = mask + ((long)b * 512 + i) * 512;
  int t = threadIdx.x;
  float v0 = p[t] + mk[t];
  float v1 = p[t + 256] + mk[t + 256];
  float mx = fmaxf(v0, v1);
  mx = wave_red_max(mx);
  __shared__ float sm[4];
  __shared__ float sm2[4];
  int wv = t >> 6, lane = t & 63;
  if (lane == 0) sm[wv] = mx;
  __syncthreads();
  mx = fmaxf(fmaxf(sm[0], sm[1]), fmaxf(sm[2], sm[3]));
  float e0 = expf(v0 - mx), e1 = expf(v1 - mx);
  float s = wave_red_sum(e0 + e1);
  if (lane == 0) sm2[wv] = s;
  __syncthreads();
  s = sm2[0] + sm2[1] + sm2[2] + sm2[3];
  float inv = 1.f / s;
  out[row * 512 + t] = f2bf(e0 * inv);
  out[row * 512 + t + 256] = f2bf(e1 * inv);
}

// ---------------- elementwise: out_bf = sigmoid(g) * o ----------------
__global__ __launch_bounds__(256) void og_bf(const float* __restrict__ g,
                                             const float* __restrict__ o,
                                             short* __restrict__ out, long n) {
  long idx = (long)blockIdx.x * 256 + threadIdx.x;
  if (idx < n) out[idx] = f2bf(sigmoidf_(g[idx]) * o[idx]);
}

__global__ __launch_bounds__(256) void opmask_kernel(float* __restrict__ ab,
                                                     const float* __restrict__ mask) {
  int idx = blockIdx.x * 256 + threadIdx.x;
  if (idx < 2048 * 64) ab[idx] *= mask[idx >> 6];
}

__global__ __launch_bounds__(256) void opm_T_kernel(const float* __restrict__ ab,
                                                    const float* __restrict__ w,
                                                    float* __restrict__ T) {
  int p = blockIdx.y;
  int row = blockIdx.x * 8 + threadIdx.y;
  int e = threadIdx.x;
  const float* a = ab + (long)row * 64;
  const float* wp = w + p * 1024 + e;
  float acc = 0.f;
#pragma unroll
  for (int d = 0; d < 32; ++d) acc += a[d] * wp[d * 32];
  T[((long)row * 64 + p) * 32 + e] = acc;
}

__global__ __launch_bounds__(256) void opm_update_kernel(
    const float* __restrict__ pair_in, const float* __restrict__ T,
    const float* __restrict__ ab, const float* __restrict__ b_out,
    const float* __restrict__ op_norm, float* __restrict__ pair1) {
  int bi = blockIdx.x;
  int b = bi >> 9;
  int j0 = blockIdx.y * 64;
  __shared__ float Ts[64][33];
  __shared__ float Bs[64][33];
  int tid = threadIdx.x;
  for (int l = tid; l < 2048; l += 256) Ts[l >> 5][l & 31] = T[(long)bi * 2048 + l];
  for (int l = tid; l < 2048; l += 256) {
    int j = l >> 5, e = l & 31;
    Bs[j][e] = ab[(long)(b * 512 + j0 + j) * 64 + 32 + e];
  }
  __syncthreads();
  int p = tid & 63, jg = tid >> 6;
  float acc[16];
#pragma unroll
  for (int jj = 0; jj < 16; ++jj) acc[jj] = 0.f;
  for (int e = 0; e < 32; ++e) {
    float tv = Ts[p][e];
#pragma unroll
    for (int jj = 0; jj < 16; ++jj) acc[jj] += tv * Bs[jg * 16 + jj][e];
  }
  float bo = b_out[p];
  float nrm = op_norm[0];
  long base = ((long)bi * 512 + j0) * 64;
#pragma unroll
  for (int jj = 0; jj < 16; ++jj) {
    long idx = base + (long)(jg * 16 + jj) * 64 + p;
    pair1[idx] = pair_in[idx] + (acc[jj] + bo) * nrm;
  }
}

// ================= MFMA pair-side kernels =================

__global__ __launch_bounds__(256) void pair_bias_mfma(
    const float* __restrict__ pair, const float* __restrict__ gam,
    const float* __restrict__ bet, const float* __restrict__ wb,
    const float* __restrict__ bbv, float* __restrict__ bias) {
  __shared__ __align__(16) float Xs[64 * 68];
  __shared__ __align__(16) short Zb[64 * 72];
  __shared__ __align__(16) short Wb[16 * 72];
  int tid = threadIdx.x;
  long e0 = (long)blockIdx.x * 64;
  int b = (int)(e0 >> 18);
  long ein = e0 & (NNe - 1);
  const float* base = pair + e0 * 64;
  for (int l = tid; l < 1024; l += 256) {
    int h = l >> 6, c = l & 63;
    Wb[h * 72 + c] = (h < 8) ? f2bf(wb[h * 64 + c]) : (short)0;
  }
#pragma unroll
  for (int i = 0; i < 4; ++i) {
    int idx = tid + i * 256;
    f32x4 v = *(const f32x4*)(base + idx * 4);
    *(f32x4*)&Xs[(idx >> 4) * 68 + (idx & 15) * 4] = v;
  }
  __syncthreads();
  int wv = tid >> 6, lane = tid & 63;
  float gl = gam[lane], bl = bet[lane];
  for (int e = wv * 16; e < wv * 16 + 16; ++e) {
    float v = Xs[e * 68 + lane];
    float s = wave_red_sum(v), ss = wave_red_sum(v * v);
    float mu = s * 0.015625f, var = ss * 0.015625f - mu * mu;
    Zb[e * 72 + lane] = f2bf((v - mu) * rsqrtf(var + LNEPS) * gl + bl);
  }
  __syncthreads();
  int lhi = lane >> 4, llo = lane & 15;
  int n0 = wv * 16;
  f32x4 acc = {0.f, 0.f, 0.f, 0.f};
#pragma unroll
  for (int ks = 0; ks < 2; ++ks) {
    bf8 a = *(const bf8*)&Wb[llo * 72 + ks * 32 + lhi * 8];
    bf8 bz = *(const bf8*)&Zb[(n0 + llo) * 72 + ks * 32 + lhi * 8];
    acc = MFMA(a, bz, acc);
  }
  int elem = n0 + llo;
#pragma unroll
  for (int r = 0; r < 4; ++r) {
    int h = lhi * 4 + r;
    if (h < 8) bias[(long)(b * 8 + h) * NNe + ein + elem] = acc[r] + bbv[h];
  }
}

__global__ __launch_bounds__(256) void pffn_mfma(
    float* __restrict__ pairp, const float* __restrict__ gam,
    const float* __restrict__ bet, const float* __restrict__ w1,
    const float* __restrict__ b1, const float* __restrict__ w2,
    const float* __restrict__ b2) {
  __shared__ __align__(16) float Xs[64 * 68];
  __shared__ __align__(16) short Zb[64 * 72];
  __shared__ __align__(16) short W1b[64 * 72];
  __shared__ __align__(16) short W2b[64 * 72];
  int tid = threadIdx.x;
  long e0 = (long)blockIdx.x * 64;
  float* base = pairp + e0 * 64;
  for (int l = tid; l < 4096; l += 256) {
    W1b[(l >> 6) * 72 + (l & 63)] = f2bf(w1[l]);
    W2b[(l >> 6) * 72 + (l & 63)] = f2bf(w2[l]);
  }
#pragma unroll
  for (int i = 0; i < 4; ++i) {
    int idx = tid + i * 256;
    f32x4 v = *(const f32x4*)(base + idx * 4);
    *(f32x4*)&Xs[(idx >> 4) * 68 + (idx & 15) * 4] = v;
  }
  __syncthreads();
  int wv = tid >> 6, lane = tid & 63;
  float gl = gam[lane], bl = bet[lane];
  for (int e = wv * 16; e < wv * 16 + 16; ++e) {
    float v = Xs[e * 68 + lane];
    float s = wave_red_sum(v), ss = wave_red_sum(v * v);
    float mu = s * 0.015625f, var = ss * 0.015625f - mu * mu;
    Zb[e * 72 + lane] = f2bf((v - mu) * rsqrtf(var + LNEPS) * gl + bl);
  }
  __syncthreads();
  int wr = wv >> 1, wc = wv & 1;
  int lhi = lane >> 4, llo = lane & 15;
  f32x4 acc[2][2] = {};
#pragma unroll
  for (int ks = 0; ks < 2; ++ks) {
    bf8 a0 = *(const bf8*)&W1b[(wr * 32 + llo) * 72 + ks * 32 + lhi * 8];
    bf8 a1 = *(const bf8*)&W1b[(wr * 32 + 16 + llo) * 72 + ks * 32 + lhi * 8];
    bf8 z0 = *(const bf8*)&Zb[(wc * 32 + llo) * 72 + ks * 32 + lhi * 8];
    bf8 z1 = *(const bf8*)&Zb[(wc * 32 + 16 + llo) * 72 + ks * 32 + lhi * 8];
    acc[0][0] = MFMA(a0, z0, acc[0][0]);
    acc[0][1] = MFMA(a0, z1, acc[0][1]);
    acc[1][0] = MFMA(a1, z0, acc[1][0]);
    acc[1][1] = MFMA(a1, z1, acc[1][1]);
  }
  __syncthreads();
#pragma unroll
  for (int mi = 0; mi < 2; ++mi) {
    int chb = wr * 32 + mi * 16 + lhi * 4;
    f32x4 bv = *(const f32x4*)(b1 + chb);
#pragma unroll
    for (int ni = 0; ni < 2; ++ni) {
      int elem = wc * 32 + ni * 16 + llo;
      bf4 pack;
#pragma unroll
      for (int r = 0; r < 4; ++r)
        pack[r] = f2bf(gelu_exact(acc[mi][ni][r] + bv[r]));
      *(bf4*)&Zb[elem * 72 + chb] = pack;
    }
  }
  __syncthreads();
  f32x4 acc2[2][2] = {};
#pragma unroll
  for (int ks = 0; ks < 2; ++ks) {
    bf8 a0 = *(const bf8*)&W2b[(wr * 32 + llo) * 72 + ks * 32 + lhi * 8];
    bf8 a1 = *(const bf8*)&W2b[(wr * 32 + 16 + llo) * 72 + ks * 32 + lhi * 8];
    bf8 z0 = *(const bf8*)&Zb[(wc * 32 + llo) * 72 + ks * 32 + lhi * 8];
    bf8 z1 = *(const bf8*)&Zb[(wc * 32 + 16 + llo) * 72 + ks * 32 + lhi * 8];
    acc2[0][0] = MFMA(a0, z0, acc2[0][0]);
    acc2[0][1] = MFMA(a0, z1, acc2[0][1]);
    acc2[1][0] = MFMA(a1, z0, acc2[1][0]);
    acc2[1][1] = MFMA(a1, z1, acc2[1][1]);
  }
#pragma unroll
  for (int mi = 0; mi < 2; ++mi) {
    int chb = wr * 32 + mi * 16 + lhi * 4;
    f32x4 bv = *(const f32x4*)(b2 + chb);
#pragma unroll
    for (int ni = 0; ni < 2; ++ni) {
      int elem = wc * 32 + ni * 16 + llo;
      f32x4 res = *(const f32x4*)&Xs[elem * 68 + chb];
      f32x4 o;
#pragma unroll
      for (int r = 0; r < 4; ++r) o[r] = res[r] + acc2[mi][ni][r] + bv[r];
      *(f32x4*)(base + (long)elem * 64 + chb) = o;
    }
  }
}

__global__ __launch_bounds__(256) void tm_ab_mfma(
    const float* __restrict__ pb, const float* __restrict__ gam,
    const float* __restrict__ bet, const float* __restrict__ w_abp,
    const float* __restrict__ b_abp, const float* __restrict__ w_abg,
    const float* __restrict__ b_abg, short* __restrict__ aN,
    short* __restrict__ bN) {
  __shared__ __align__(16) float Xs[64 * 68];
  __shared__ __align__(16) short Zb[64 * 72];
  __shared__ __align__(16) short Wp[64 * 72];
  __shared__ __align__(16) short Wg[64 * 72];
  int tid = threadIdx.x;
  long e0 = (long)blockIdx.x * 64;
  const float* base = pb + e0 * 64;
  for (int l = tid; l < 4096; l += 256) {
    Wp[(l >> 6) * 72 + (l & 63)] = f2bf(w_abp[l]);
    Wg[(l >> 6) * 72 + (l & 63)] = f2bf(w_abg[l]);
  }
#pragma unroll
  for (int i = 0; i < 4; ++i) {
    int idx = tid + i * 256;
    f32x4 v = *(const f32x4*)(base + idx * 4);
    *(f32x4*)&Xs[(idx >> 4) * 68 + (idx & 15) * 4] = v;
  }
  __syncthreads();
  int wv = tid >> 6, lane = tid & 63;
  float gl = gam[lane], bl = bet[lane];
  for (int e = wv * 16; e < wv * 16 + 16; ++e) {
    float v = Xs[e * 68 + lane];
    float s = wave_red_sum(v), ss = wave_red_sum(v * v);
    float mu = s * 0.015625f, var = ss * 0.015625f - mu * mu;
    Zb[e * 72 + lane] = f2bf((v - mu) * rsqrtf(var + LNEPS) * gl + bl);
  }
  __syncthreads();
  int wr = wv >> 1, wc = wv & 1;
  int lhi = lane >> 4, llo = lane & 15;
  f32x4 ap[2][2] = {};
  f32x4 ag[2][2] = {};
#pragma unroll
  for (int ks = 0; ks < 2; ++ks) {
    bf8 z0 = *(const bf8*)&Zb[(wr * 32 + llo) * 72 + ks * 32 + lhi * 8];
    bf8 z1 = *(const bf8*)&Zb[(wr * 32 + 16 + llo) * 72 + ks * 32 + lhi * 8];
    bf8 p0 = *(const bf8*)&Wp[(wc * 32 + llo) * 72 + ks * 32 + lhi * 8];
    bf8 p1 = *(const bf8*)&Wp[(wc * 32 + 16 + llo) * 72 + ks * 32 + lhi * 8];
    bf8 g0 = *(const bf8*)&Wg[(wc * 32 + llo) * 72 + ks * 32 + lhi * 8];
    bf8 g1 = *(const bf8*)&Wg[(wc * 32 + 16 + llo) * 72 + ks * 32 + lhi * 8];
    ap[0][0] = MFMA(z0, p0, ap[0][0]);
    ap[0][1] = MFMA(z0, p1, ap[0][1]);
    ap[1][0] = MFMA(z1, p0, ap[1][0]);
    ap[1][1] = MFMA(z1, p1, ap[1][1]);
    ag[0][0] = MFMA(z0, g0, ag[0][0]);
    ag[0][1] = MFMA(z0, g1, ag[0][1]);
    ag[1][0] = MFMA(z1, g0, ag[1][0]);
    ag[1][1] = MFMA(z1, g1, ag[1][1]);
  }
#pragma unroll
  for (int mi = 0; mi < 2; ++mi) {
    int elemb = wr * 32 + mi * 16 + lhi * 4;
#pragma unroll
    for (int ni = 0; ni < 2; ++ni) {
      int ch = wc * 32 + ni * 16 + llo;
      float bp = b_abp[ch], bg = b_abg[ch];
      bf4 pack;
#pragma unroll
      for (int r = 0; r < 4; ++r)
        pack[r] = f2bf((ap[mi][ni][r] + bp) * sigmoidf_(ag[mi][ni][r] + bg));
      short* dst = (ch < 32) ? (aN + (long)ch * NNe) : (bN + (long)(ch - 32) * NNe);
      *(bf4*)(dst + e0 + elemb) = pack;
    }
  }
}

__global__ __launch_bounds__(256) void tm_tri_mfma(const short* __restrict__ aN,
                                                   const short* __restrict__ bN,
                                                   float* __restrict__ t_out) {
  int h = blockIdx.z;
  int i0 = blockIdx.y * 64, k0 = blockIdx.x * 64;
  const short* A = aN + (long)h * NNe;
  const short* B = bN + (long)h * NNe;
  __shared__ __align__(16) short A1[64 * 40];
  __shared__ __align__(16) short B1[64 * 40];
  __shared__ __align__(16) short A2[64 * 40];
  __shared__ __align__(16) short B2[64 * 40];
  int tid = threadIdx.x;
  int wv = tid >> 6, lane = tid & 63;
  int wr = wv >> 1, wc = wv & 1;
  int lhi = lane >> 4, llo = lane & 15;
  int r1 = tid >> 2, cp = (tid & 3) * 8;
  int rr = tid >> 3, ip = (tid & 7) * 8;
  f32x4 acc[2][2] = {};
  for (int j0 = 0; j0 < 512; j0 += 32) {
    *(bf8*)&A1[r1 * 40 + cp] = *(const bf8*)(A + (long)(i0 + r1) * 512 + j0 + cp);
    *(bf8*)&B1[r1 * 40 + cp] = *(const bf8*)(B + (long)(k0 + r1) * 512 + j0 + cp);
    bf8 va = *(const bf8*)(A + (long)(j0 + rr) * 512 + i0 + ip);
    bf8 vb = *(const bf8*)(B + (long)(j0 + rr) * 512 + k0 + ip);
#pragma unroll
    for (int q = 0; q < 8; ++q) {
      A2[(ip + q) * 40 + rr] = va[q];
      B2[(ip + q) * 40 + rr] = vb[q];
    }
    __syncthreads();
    bf8 a0 = *(const bf8*)&A1[(wr * 32 + llo) * 40 + lhi * 8];
    bf8 a1 = *(const bf8*)&A1[(wr * 32 + 16 + llo) * 40 + lhi * 8];
    bf8 b0 = *(const bf8*)&B1[(wc * 32 + llo) * 40 + lhi * 8];
    bf8 b1 = *(const bf8*)&B1[(wc * 32 + 16 + llo) * 40 + lhi * 8];
    acc[0][0] = MFMA(a0, b0, acc[0][0]);
    acc[0][1] = MFMA(a0, b1, acc[0][1]);
    acc[1][0] = MFMA(a1, b0, acc[1][0]);
    acc[1][1] = MFMA(a1, b1, acc[1][1]);
    bf8 c0 = *(const bf8*)&A2[(wr * 32 + llo) * 40 + lhi * 8];
    bf8 c1 = *(const bf8*)&A2[(wr * 32 + 16 + llo) * 40 + lhi * 8];
    bf8 d0 = *(const bf8*)&B2[(wc * 32 + llo) * 40 + lhi * 8];
    bf8 d1 = *(const bf8*)&B2[(wc * 32 + 16 + llo) * 40 + lhi * 8];
    acc[0][0] = MFMA(c0, d0, acc[0][0]);
    acc[0][1] = MFMA(c0, d1, acc[0][1]);
    acc[1][0] = MFMA(c1, d0, acc[1][0]);
    acc[1][1] = MFMA(c1, d1, acc[1][1]);
    __syncthreads();
  }
  float* tp = t_out + (long)h * NNe;
#pragma unroll
  for (int mi = 0; mi < 2; ++mi)
#pragma unroll
    for (int ni = 0; ni < 2; ++ni) {
      int row = i0 + wr * 32 + mi * 16 + lhi * 4;
      int col = k0 + wc * 32 + ni * 16 + llo;
#pragma unroll
      for (int r = 0; r < 4; ++r) tp[(long)(row + r) * 512 + col] = acc[mi][ni][r];
    }
}

__global__ __launch_bounds__(256) void tm_update_mfma(
    float* __restrict__ pb, const float* __restrict__ t_in,
    const float* __restrict__ gam, const float* __restrict__ bet,
    const float* __restrict__ w_g, const float* __restrict__ b_g,
    const float* __restrict__ g_tmo, const float* __restrict__ b_tmo,
    const float* __restrict__ w_z, const float* __restrict__ b_z) {
  __shared__ __align__(16) float Xs[64 * 68];
  __shared__ __align__(16) float Ts[64 * 36];
  __shared__ __align__(16) short Zb[64 * 72];
  __shared__ __align__(16) short Tlb[64 * 40];
  __shared__ __align__(16) short Wgb[64 * 72];
  __shared__ __align__(16) short Wzb[64 * 40];
  int tid = threadIdx.x;
  long e0 = (long)blockIdx.x * 64;
  float* base = pb + e0 * 64;
  for (int l = tid; l < 4096; l += 256) Wgb[(l >> 6) * 72 + (l & 63)] = f2bf(w_g[l]);
  for (int l = tid; l < 2048; l += 256) Wzb[(l >> 5) * 40 + (l & 31)] = f2bf(w_z[l]);
#pragma unroll
  for (int i = 0; i < 4; ++i) {
    int idx = tid + i * 256;
    f32x4 v = *(const f32x4*)(base + idx * 4);
    *(f32x4*)&Xs[(idx >> 4) * 68 + (idx & 15) * 4] = v;
  }
  for (int l = tid; l < 2048; l += 256) {
    int hh = l >> 6, e = l & 63;
    Ts[e * 36 + hh] = t_in[(long)hh * NNe + e0 + e];
  }
  __syncthreads();
  int wv = tid >> 6, lane = tid & 63;
  float gl = gam[lane], bl = bet[lane];
  for (int e = wv * 16; e < wv * 16 + 16; ++e) {
    float v = Xs[e * 68 + lane];
    float s = wave_red_sum(v), ss = wave_red_sum(v * v);
    float mu = s * 0.015625f, var = ss * 0.015625f - mu * mu;
    Zb[e * 72 + lane] = f2bf((v - mu) * rsqrtf(var + LNEPS) * gl + bl);
  }
  {
    int ch = lane & 31;
    int sel = lane >> 5;
    float go = g_tmo[ch], bo = b_tmo[ch];
    for (int it = 0; it < 8; ++it) {
      int e = wv * 16 + it * 2 + sel;
      float v = Ts[e * 36 + ch];
      float s = half_red_sum(v), ss = half_red_sum(v * v);
      float mu = s * 0.03125f, var = ss * 0.03125f - mu * mu;
      Tlb[e * 40 + ch] = f2bf((v - mu) * rsqrtf(var + LNEPS) * go + bo);
    }
  }
  __syncthreads();
  int wr = wv >> 1, wc = wv & 1;
  int lhi = lane >> 4, llo = lane & 15;
  f32x4 accg[2][2] = {};
  f32x4 accz[2][2] = {};
#pragma unroll
  for (int ks = 0; ks < 2; ++ks) {
    bf8 a0 = *(const bf8*)&Wgb[(wr * 32 + llo) * 72 + ks * 32 + lhi * 8];
    bf8 a1 = *(const bf8*)&Wgb[(wr * 32 + 16 + llo) * 72 + ks * 32 + lhi * 8];
    bf8 z0 = *(const bf8*)&Zb[(wc * 32 + llo) * 72 + ks * 32 + lhi * 8];
    bf8 z1 = *(const bf8*)&Zb[(wc * 32 + 16 + llo) * 72 + ks * 32 + lhi * 8];
    accg[0][0] = MFMA(a0, z0, accg[0][0]);
    accg[0][1] = MFMA(a0, z1, accg[0][1]);
    accg[1][0] = MFMA(a1, z0, accg[1][0]);
    accg[1][1] = MFMA(a1, z1, accg[1][1]);
  }
  {
    bf8 a0 = *(const bf8*)&Wzb[(wr * 32 + llo) * 40 + lhi * 8];
    bf8 a1 = *(const bf8*)&Wzb[(wr * 32 + 16 + llo) * 40 + lhi * 8];
    bf8 t0 = *(const bf8*)&Tlb[(wc * 32 + llo) * 40 + lhi * 8];
    bf8 t1 = *(const bf8*)&Tlb[(wc * 32 + 16 + llo) * 40 + lhi * 8];
    accz[0][0] = MFMA(a0, t0, accz[0][0]);
    accz[0][1] = MFMA(a0, t1, accz[0][1]);
    accz[1][0] = MFMA(a1, t0, accz[1][0]);
    accz[1][1] = MFMA(a1, t1, accz[1][1]);
  }
#pragma unroll
  for (int mi = 0; mi < 2; ++mi) {
    int chb = wr * 32 + mi * 16 + lhi * 4;
    f32x4 bgv = *(const f32x4*)(b_g + chb);
    f32x4 bzv = *(const f32x4*)(b_z + chb);
#pragma unroll
    for (int ni = 0; ni < 2; ++ni) {
      int elem = wc * 32 + ni * 16 + llo;
      f32x4 res = *(const f32x4*)&Xs[elem * 68 + chb];
      f32x4 o;
#pragma unroll
      for (int r = 0; r < 4; ++r)
        o[r] = res[r] + (accg[mi][ni][r] + bgv[r]) * (accz[mi][ni][r] + bzv[r]);
      *(f32x4*)(base + (long)elem * 64 + chb) = o;
    }
  }
}

extern "C" void kernel_launch(void* const* d_in, const int* in_sizes, int n_in,
                              void* d_out, int out_size, void* d_ws, size_t ws_size,
                              hipStream_t stream) {
  const float* x = (const float*)d_in[0];
  const float* pair = (const float*)d_in[1];
  const float* attn_mask = (const float*)d_in[2];
  const float* op_mask = (const float*)d_in[3];
  const float* op_norm = (const float*)d_in[4];
  const float* wq = (const float*)d_in[6];
  const float* wk = (const float*)d_in[7];
  const float* wv_ = (const float*)d_in[8];
  const float* wg = (const float*)d_in[9];
  const float* bg = (const float*)d_in[10];
  const float* wo = (const float*)d_in[11];
  const float* bo = (const float*)d_in[12];
  const float* ln_pair_g = (const float*)d_in[13];
  const float* ln_pair_b = (const float*)d_in[14];
  const float* wb = (const float*)d_in[15];
  const float* bb = (const float*)d_in[16];
  const float* ln_attn_g = (const float*)d_in[17];
  const float* ln_attn_b = (const float*)d_in[18];
  const float* ln_ffn_g = (const float*)d_in[19];
  const float* ln_ffn_b = (const float*)d_in[20];
  const float* w_ffn1 = (const float*)d_in[21];
  const float* b_ffn1 = (const float*)d_in[22];
  const float* w_ffn2 = (const float*)d_in[23];
  const float* b_ffn2 = (const float*)d_in[24];
  const float* ln_opm_g = (const float*)d_in[25];
  const float* ln_opm_b = (const float*)d_in[26];
  const float* w_opm_in = (const float*)d_in[27];
  const float* b_opm_in = (const float*)d_in[28];
  const float* w_opm_out = (const float*)d_in[29];
  const float* b_opm_out = (const float*)d_in[30];
  const float* ln_tm_g = (const float*)d_in[31];
  const float* ln_tm_b = (const float*)d_in[32];
  const float* w_tm_abp = (const float*)d_in[33];
  const float* b_tm_abp = (const float*)d_in[34];
  const float* w_tm_abg = (const float*)d_in[35];
  const float* b_tm_abg = (const float*)d_in[36];
  const float* w_tm_g = (const float*)d_in[37];
  const float* b_tm_g = (const float*)d_in[38];
  const float* w_tm_z = (const float*)d_in[39];
  const float* b_tm_z = (const float*)d_in[40];
  const float* ln_tmo_g = (const float*)d_in[41];
  const float* ln_tmo_b = (const float*)d_in[42];
  const float* ln_pffn_g = (const float*)d_in[43];
  const float* ln_pffn_b = (const float*)d_in[44];
  const float* w_pffn1 = (const float*)d_in[45];
  const float* b_pffn1 = (const float*)d_in[46];
  const float* w_pffn2 = (const float*)d_in[47];
  const float* b_pffn2 = (const float*)d_in[48];

  float* ws = (float*)d_ws;
  // bf16 weight arena (offsets in bf16 elements)
  short* wbf = (short*)ws;                    // 7,716,864 bf16 = 3,858,432 floats
  short* wq_bf = wbf + 0;
  short* wk_bf = wbf + 589824;
  short* wv_bf = wbf + 1179648;
  short* wg_bf = wbf + 1769472;
  short* wo_bf = wbf + 2359296;
  short* wf1_bf = wbf + 2949120;
  short* wf2_bf = wbf + 5308416;
  short* wop_bf = wbf + 7667712;
  short* h_bf   = (short*)(ws + 3858432);     // 1,572,864 bf16
  short* q_bf   = (short*)(ws + 4644864);
  short* k_bf   = (short*)(ws + 5431296);
  short* vT_bf  = (short*)(ws + 6217728);
  float* gb     = ws + 7004160;               // fp32 gate pre-act
  float* ob     = ws + 8577024;               // fp32 attn out
  short* gb_bf  = (short*)(ws + 10149888);
  float* x1b    = ws + 10936320;
  float* biasb  = ws + 12509184;              // 8,388,608 fp32 scores
  short* attn_bf = (short*)(ws + 20897792);   // 4,194,304 floats worth
  short* mffn_bf = (short*)(ws + 12509184);   // reuse biasb region (ffn stage)
  float* abb    = ws + 20897792;              // reuse attn region (opm stage)
  float* Tb     = ws + 21028864;
  // triangle-stage reuse (everything above except d_out is dead by then):
  short* aNb = (short*)ws;                    // [0, 4,194,304) floats
  short* bNb = (short*)(ws + 4194304);
  float* t_b = ws + 8388608;                  // 8,388,608 floats

  float* xo = (float*)d_out;
  float* pair1 = xo + 1572864;

  const float qscale = 0.1020620726159658f;  // 96^-0.5

  // --- weight cast ---
  castw_kernel<<<30144, 256, 0, stream>>>(wq, wk, wv_, wg, wo, w_ffn1, w_ffn2, w_opm_in,
                                          wbf, qscale);
  // --- attention ---
  ln_bf_kernel<<<2048, 256, 0, stream>>>(x, h_bf, ln_attn_g, ln_attn_b, 768);
  gemm_bf<<<dim3(12, 32, 1), 256, 0, stream>>>(h_bf, 768, 0, 0, wq_bf, 768, 0, 0,
                                               nullptr, 0, 0, 0, q_bf, 768,
                                               nullptr, 0, 0, 0, nullptr,
                                               2048, 768, 768, 0, 0, 1);
  gemm_bf<<<dim3(12, 32, 1), 256, 0, stream>>>(h_bf, 768, 0, 0, wk_bf, 768, 0, 0,
                                               nullptr, 0, 0, 0, k_bf, 768,
                                               nullptr, 0, 0, 0, nullptr,
                                               2048, 768, 768, 0, 0, 1);
  gemm_bf<<<dim3(12, 32, 1), 256, 0, stream>>>(h_bf, 768, 0, 0, wv_bf, 768, 0, 0,
                                               nullptr, 0, 0, 0, vT_bf, 0,
                                               nullptr, 0, 0, 0, nullptr,
                                               2048, 768, 768, 0, 1, 1);
  gemm_bf<<<dim3(12, 32, 1), 256, 0, stream>>>(h_bf, 768, 0, 0, wg_bf, 768, 0, 0,
                                               gb, 768, 0, 0, nullptr, 0,
                                               nullptr, 0, 0, 0, bg,
                                               2048, 768, 768, 0, 0, 1);
  pair_bias_mfma<<<16384, 256, 0, stream>>>(pair, ln_pair_g, ln_pair_b, wb, bb, biasb);
  gemm_bf<<<dim3(8, 8, 32), 256, 0, stream>>>(q_bf, 768, 393216, 96, k_bf, 768, 393216, 96,
                                              biasb, 512, 2097152, 262144, nullptr, 0,
                                              biasb, 512, 2097152, 262144, nullptr,
                                              512, 512, 96, 0, 0, 8);
  softmax_bf<<<16384, 256, 0, stream>>>(biasb, attn_mask, attn_bf);
  gemm_bf<<<dim3(2, 8, 32), 256, 0, stream>>>(attn_bf, 512, 2097152, 262144,
                                              vT_bf, 512, 393216, 49152,
                                              ob, 768, 393216, 96, nullptr, 0,
                                              nullptr, 0, 0, 0, nullptr,
                                              512, 96, 512, 0, 0, 8);
  og_bf<<<6144, 256, 0, stream>>>(gb, ob, gb_bf, 1572864);
  gemm_bf<<<dim3(12, 32, 1), 256, 0, stream>>>(gb_bf, 768, 0, 0, wo_bf, 768, 0, 0,
                                               x1b, 768, 0, 0, nullptr, 0,
                                               x, 768, 0, 0, bo,
                                               2048, 768, 768, 0, 0, 1);
  // --- FFN ---
  ln_bf_kernel<<<2048, 256, 0, stream>>>(x1b, h_bf, ln_ffn_g, ln_ffn_b, 768);
  gemm_bf<<<dim3(48, 32, 1), 256, 0, stream>>>(h_bf, 768, 0, 0, wf1_bf, 768, 0, 0,
                                               nullptr, 0, 0, 0, mffn_bf, 3072,
                                               nullptr, 0, 0, 0, b_ffn1,
                                               2048, 3072, 768, 1, 0, 1);
  gemm_bf<<<dim3(12, 32, 1), 256, 0, stream>>>(mffn_bf, 3072, 0, 0, wf2_bf, 3072, 0, 0,
                                               xo, 768, 0, 0, nullptr, 0,
                                               x1b, 768, 0, 0, b_ffn2,
                                               2048, 768, 3072, 0, 0, 1);
  // --- outer product mean ---
  ln_bf_kernel<<<2048, 256, 0, stream>>>(xo, h_bf, ln_opm_g, ln_opm_b, 768);
  gemm_bf<<<dim3(1, 32, 1), 256, 0, stream>>>(h_bf, 768, 0, 0, wop_bf, 768, 0, 0,
                                              abb, 64, 0, 0, nullptr, 0,
                                              nullptr, 0, 0, 0, b_opm_in,
                                              2048, 64, 768, 0, 0, 1);
  opmask_kernel<<<512, 256, 0, stream>>>(abb, op_mask);
  opm_T_kernel<<<dim3(256, 64, 1), dim3(32, 8, 1), 0, stream>>>(abb, w_opm_out, Tb);
  opm_update_kernel<<<dim3(2048, 8, 1), 256, 0, stream>>>(pair, Tb, abb, b_opm_out, op_norm,
                                                          pair1);
  // --- triangle multiplication (per batch, reusing arena) ---
  for (int b = 0; b < 4; ++b) {
    float* pbb = pair1 + (long)b * NNe * 64;
    tm_ab_mfma<<<4096, 256, 0, stream>>>(pbb, ln_tm_g, ln_tm_b, w_tm_abp, b_tm_abp,
                                         w_tm_abg, b_tm_abg, aNb, bNb);
    tm_tri_mfma<<<dim3(8, 8, 32), 256, 0, stream>>>(aNb, bNb, t_b);
    tm_update_mfma<<<4096, 256, 0, stream>>>(pbb, t_b, ln_tm_g, ln_tm_b, w_tm_g, b_tm_g,
                                             ln_tmo_g, ln_tmo_b, w_tm_z, b_tm_z);
  }
  // --- pair transition ---
  pffn_mfma<<<16384, 256, 0, stream>>>(pair1, ln_pffn_g, ln_pffn_b, w_pffn1, b_pffn1,
                                       w_pffn2, b_pffn2);
}

// Round 4
// 1607.829 us; speedup vs baseline: 4.2654x; 1.0855x over previous
//
#include <hip/hip_runtime.h>
#include <hip/hip_bf16.h>
#include <math.h>

#define Nn 512
#define Ee 768
#define Pp 64
#define PHh 32
#define Hh 8
#define Dd 96
#define NNe 262144      // N*N
#define LNEPS 1e-5f

typedef __attribute__((ext_vector_type(8))) short bf8;
typedef __attribute__((ext_vector_type(4))) short bf4;
typedef __attribute__((ext_vector_type(4))) float f32x4;
#define MFMA(a,b,c) __builtin_amdgcn_mfma_f32_16x16x32_bf16(a,b,c,0,0,0)

__device__ __forceinline__ short f2bf(float f) {
  unsigned u = __builtin_bit_cast(unsigned, f);
  unsigned r = (u + 0x7fffu + ((u >> 16) & 1u)) >> 16;
  return (short)r;
}
__device__ __forceinline__ float bf2f(short s) {
  unsigned u = ((unsigned)(unsigned short)s) << 16;
  return __builtin_bit_cast(float, u);
}

__device__ __forceinline__ float wave_red_sum(float v) {
#pragma unroll
  for (int off = 32; off > 0; off >>= 1) v += __shfl_xor(v, off);
  return v;
}
__device__ __forceinline__ float half_red_sum(float v) {
#pragma unroll
  for (int off = 16; off > 0; off >>= 1) v += __shfl_xor(v, off, 32);
  return v;
}
__device__ __forceinline__ float gelu_exact(float v) {
  return 0.5f * v * (1.f + erff(v * 0.70710678118654752f));
}
__device__ __forceinline__ float sigmoidf_(float v) {
  return 1.f / (1.f + expf(-v));
}

// ---------------- weight casts to bf16 arena ----------------
__global__ __launch_bounds__(256) void castw_kernel(
    const float* __restrict__ wq, const float* __restrict__ wk,
    const float* __restrict__ wv, const float* __restrict__ wg,
    const float* __restrict__ wo, const float* __restrict__ f1,
    const float* __restrict__ f2, const float* __restrict__ wop,
    short* __restrict__ dst, float qs) {
  long i = (long)blockIdx.x * 256 + threadIdx.x;
  float v;
  if (i < 589824) v = wq[i] * qs;
  else if (i < 1179648) v = wk[i - 589824];
  else if (i < 1769472) v = wv[i - 1179648];
  else if (i < 2359296) v = wg[i - 1769472];
  else if (i < 2949120) v = wo[i - 2359296];
  else if (i < 5308416) v = f1[i - 2949120];
  else if (i < 7667712) v = f2[i - 5308416];
  else if (i < 7716864) v = wop[i - 7667712];
  else return;
  dst[i] = f2bf(v);
}

__global__ __launch_bounds__(256) void castw2_kernel(
    const float* __restrict__ wb, const float* __restrict__ abp,
    const float* __restrict__ abg, const float* __restrict__ wtg,
    const float* __restrict__ wtz, const float* __restrict__ p1,
    const float* __restrict__ p2, short* __restrict__ dst) {
  int i = blockIdx.x * 256 + threadIdx.x;
  float v;
  if (i < 512) v = wb[i];
  else if (i < 4608) v = abp[i - 512];
  else if (i < 8704) v = abg[i - 4608];
  else if (i < 12800) v = wtg[i - 8704];
  else if (i < 14848) v = wtz[i - 12800];
  else if (i < 18944) v = p1[i - 14848];
  else if (i < 23040) v = p2[i - 18944];
  else return;
  dst[i] = f2bf(v);
}

// ---------------- LayerNorm over last dim C -> bf16 out ----------------
__global__ __launch_bounds__(256) void ln_bf_kernel(const float* __restrict__ in,
                                                    short* __restrict__ out,
                                                    const float* __restrict__ gam,
                                                    const float* __restrict__ bet, int C) {
  int row = blockIdx.x;
  const float* xr = in + (long)row * C;
  short* yr = out + (long)row * C;
  float s = 0.f, ss = 0.f;
  for (int c = threadIdx.x; c < C; c += 256) { float v = xr[c]; s += v; ss += v * v; }
  s = wave_red_sum(s); ss = wave_red_sum(ss);
  __shared__ float sm[4][2];
  int wv = threadIdx.x >> 6, lane = threadIdx.x & 63;
  if (lane == 0) { sm[wv][0] = s; sm[wv][1] = ss; }
  __syncthreads();
  float ts = sm[0][0] + sm[1][0] + sm[2][0] + sm[3][0];
  float tss = sm[0][1] + sm[1][1] + sm[2][1] + sm[3][1];
  float mu = ts / C;
  float var = tss / C - mu * mu;
  float rs = rsqrtf(var + LNEPS);
  for (int c = threadIdx.x; c < C; c += 256) {
    float v = xr[c];
    yr[c] = f2bf((v - mu) * rs * gam[c] + bet[c]);
  }
}

// ---------------- bf16 MFMA NT GEMM ----------------
__global__ __launch_bounds__(256) void gemm_bf(
    const short* __restrict__ A, int lda, long asB, long asH,
    const short* __restrict__ Bm, int ldb, long bsB, long bsH,
    float* __restrict__ outF, int ldf, long fsB, long fsH,
    short* __restrict__ outB, int ldob,
    const float* __restrict__ resid, int ldr, long rsB, long rsH,
    const float* __restrict__ bias,
    int M, int N, int K, int act, int vtrans, int Hdim) {
  int bz = blockIdx.z, bb = bz / Hdim, hh = bz % Hdim;
  A += bb * asB + hh * asH;
  Bm += bb * bsB + hh * bsH;
  if (outF) outF += bb * fsB + hh * fsH;
  if (resid) resid += bb * rsB + hh * rsH;
  __shared__ __align__(16) short As[64 * 40];
  __shared__ __align__(16) short Bs[64 * 40];
  int m0 = blockIdx.y * 64, n0 = blockIdx.x * 64;
  int tid = threadIdx.x;
  int wv = tid >> 6, lane = tid & 63;
  int wr = wv >> 1, wc = wv & 1;
  int lhi = lane >> 4, llo = lane & 15;
  int r4 = tid >> 2, c8 = (tid & 3) * 8;
  f32x4 acc[2][2] = {};
  for (int k0 = 0; k0 < K; k0 += 32) {
    *(bf8*)&As[r4 * 40 + c8] = *(const bf8*)(A + (long)(m0 + r4) * lda + k0 + c8);
    bf8 bv = {};
    if (n0 + r4 < N) bv = *(const bf8*)(Bm + (long)(n0 + r4) * ldb + k0 + c8);
    *(bf8*)&Bs[r4 * 40 + c8] = bv;
    __syncthreads();
    bf8 a0 = *(const bf8*)&As[(wr * 32 + llo) * 40 + lhi * 8];
    bf8 a1 = *(const bf8*)&As[(wr * 32 + 16 + llo) * 40 + lhi * 8];
    bf8 b0 = *(const bf8*)&Bs[(wc * 32 + llo) * 40 + lhi * 8];
    bf8 b1 = *(const bf8*)&Bs[(wc * 32 + 16 + llo) * 40 + lhi * 8];
    acc[0][0] = MFMA(a0, b0, acc[0][0]);
    acc[0][1] = MFMA(a0, b1, acc[0][1]);
    acc[1][0] = MFMA(a1, b0, acc[1][0]);
    acc[1][1] = MFMA(a1, b1, acc[1][1]);
    __syncthreads();
  }
#pragma unroll
  for (int mi = 0; mi < 2; ++mi) {
    int gmb = m0 + wr * 32 + mi * 16 + lhi * 4;
#pragma unroll
    for (int ni = 0; ni < 2; ++ni) {
      int gn = n0 + wc * 32 + ni * 16 + llo;
      if (gn >= N) continue;
      float bv = bias ? bias[gn] : 0.f;
      float vr[4];
#pragma unroll
      for (int r = 0; r < 4; ++r) {
        float v = acc[mi][ni][r] + bv;
        if (resid) v += resid[(long)(gmb + r) * ldr + gn];
        if (act == 1) v = gelu_exact(v);
        vr[r] = v;
      }
      if (outF) {
#pragma unroll
        for (int r = 0; r < 4; ++r) outF[(long)(gmb + r) * ldf + gn] = vr[r];
      }
      if (outB) {
        if (vtrans) {
          bf4 pk;
#pragma unroll
          for (int r = 0; r < 4; ++r) pk[r] = f2bf(vr[r]);
          *(bf4*)(outB + ((long)((gmb >> 9) * 768 + gn) * 512 + (gmb & 511))) = pk;
        } else {
#pragma unroll
          for (int r = 0; r < 4; ++r) outB[(long)(gmb + r) * ldob + gn] = f2bf(vr[r]);
        }
      }
    }
  }
}

// ---------------- fused scores + softmax (flash-row, 16 rows/block) ----------------
__global__ __launch_bounds__(256) void attn_fused(
    const short* __restrict__ q_bf, const short* __restrict__ k_bf,
    const short* __restrict__ bias_bf, const float* __restrict__ mask,
    short* __restrict__ out_bf) {
  int it = blockIdx.x, h = blockIdx.y, b = blockIdx.z;
  int tid = threadIdx.x;
  int wv = tid >> 6, lane = tid & 63;
  int lhi = lane >> 4, llo = lane & 15;
  int i0 = it * 16;
  long qoff = ((long)(b * 512 + i0)) * 768 + h * 96;
  bf8 qf[3];
#pragma unroll
  for (int ks = 0; ks < 3; ++ks)
    qf[ks] = *(const bf8*)(q_bf + qoff + (long)llo * 768 + ks * 32 + lhi * 8);
  long koff = ((long)b * 512) * 768 + h * 96;
  long bioff = (long)(b * 8 + h) * NNe + (long)i0 * 512;
  long moff = (long)b * NNe + (long)i0 * 512;
  float sv[8][4];
  int jb0 = wv * 128;
#pragma unroll
  for (int jf = 0; jf < 8; ++jf) {
    int jb = jb0 + jf * 16;
    f32x4 acc = {0.f, 0.f, 0.f, 0.f};
#pragma unroll
    for (int ks = 0; ks < 3; ++ks) {
      bf8 kf = *(const bf8*)(k_bf + koff + (long)(jb + llo) * 768 + ks * 32 + lhi * 8);
      acc = MFMA(qf[ks], kf, acc);
    }
#pragma unroll
    for (int r = 0; r < 4; ++r) {
      int irow = lhi * 4 + r;
      int j = jb + llo;
      float bia = bf2f(bias_bf[bioff + (long)irow * 512 + j]);
      float mk = mask[moff + (long)irow * 512 + j];
      sv[jf][r] = acc[r] + bia + mk;
    }
  }
  __shared__ float redA[4][20];
  __shared__ float redB[4][20];
  float rmax[4];
#pragma unroll
  for (int r = 0; r < 4; ++r) {
    float m = sv[0][r];
#pragma unroll
    for (int jf = 1; jf < 8; ++jf) m = fmaxf(m, sv[jf][r]);
#pragma unroll
    for (int off = 1; off < 16; off <<= 1) m = fmaxf(m, __shfl_xor(m, off, 16));
    if (llo == 0) redA[wv][lhi * 4 + r] = m;
  }
  __syncthreads();
#pragma unroll
  for (int r = 0; r < 4; ++r) {
    int row = lhi * 4 + r;
    rmax[r] = fmaxf(fmaxf(redA[0][row], redA[1][row]),
                    fmaxf(redA[2][row], redA[3][row]));
  }
  float rsum[4] = {0.f, 0.f, 0.f, 0.f};
#pragma unroll
  for (int jf = 0; jf < 8; ++jf)
#pragma unroll
    for (int r = 0; r < 4; ++r) {
      float e = __expf(sv[jf][r] - rmax[r]);
      sv[jf][r] = e;
      rsum[r] += e;
    }
#pragma unroll
  for (int r = 0; r < 4; ++r) {
#pragma unroll
    for (int off = 1; off < 16; off <<= 1) rsum[r] += __shfl_xor(rsum[r], off, 16);
    if (llo == 0) redB[wv][lhi * 4 + r] = rsum[r];
  }
  __syncthreads();
#pragma unroll
  for (int r = 0; r < 4; ++r) {
    int row = lhi * 4 + r;
    float s = redB[0][row] + redB[1][row] + redB[2][row] + redB[3][row];
    float inv = 1.f / s;
#pragma unroll
    for (int jf = 0; jf < 8; ++jf) {
      int j = jb0 + jf * 16 + llo;
      out_bf[bioff + (long)row * 512 + j] = f2bf(sv[jf][r] * inv);
    }
  }
}

// ---------------- elementwise: out_bf = sigmoid(g) * o ----------------
__global__ __launch_bounds__(256) void og_bf(const float* __restrict__ g,
                                             const float* __restrict__ o,
                                             short* __restrict__ out, long n) {
  long idx = (long)blockIdx.x * 256 + threadIdx.x;
  if (idx < n) out[idx] = f2bf(sigmoidf_(g[idx]) * o[idx]);
}

// ---------------- ab *= op_mask ; emit b-half bf16 ----------------
__global__ __launch_bounds__(256) void opmask_kernel(float* __restrict__ ab,
                                                     const float* __restrict__ mask,
                                                     short* __restrict__ bo_bf) {
  int idx = blockIdx.x * 256 + threadIdx.x;
  if (idx < 131072) {
    float v = ab[idx] * mask[idx >> 6];
    ab[idx] = v;
    int ch = idx & 63;
    if (ch >= 32) bo_bf[(idx >> 6) * 32 + ch - 32] = f2bf(v);
  }
}

// ---------------- T[row,p,e] (bf16) = sum_d a_o[row,d] * w[p, d*32+e] ----------------
__global__ __launch_bounds__(256) void opm_T_kernel(const float* __restrict__ ab,
                                                    const float* __restrict__ w,
                                                    short* __restrict__ T) {
  int p = blockIdx.y;
  int row = blockIdx.x * 8 + threadIdx.y;
  int e = threadIdx.x;
  const float* a = ab + (long)row * 64;
  const float* wp = w + p * 1024 + e;
  float acc = 0.f;
#pragma unroll
  for (int d = 0; d < 32; ++d) acc += a[d] * wp[d * 32];
  T[((long)row * 64 + p) * 32 + e] = f2bf(acc);
}

// ---------------- pair bias: bf16 out ----------------
__global__ __launch_bounds__(256) void pair_bias_mfma(
    const float* __restrict__ pair, const float* __restrict__ gam,
    const float* __restrict__ bet, const short* __restrict__ wb_a,
    const float* __restrict__ bbv, short* __restrict__ bias) {
  __shared__ __align__(16) float Xs[64 * 68];
  __shared__ __align__(16) short Zb[64 * 72];
  __shared__ __align__(16) short Wb[16 * 72];
  int tid = threadIdx.x;
  long e0 = (long)blockIdx.x * 64;
  int b = (int)(e0 >> 18);
  long ein = e0 & (NNe - 1);
  const float* base = pair + e0 * 64;
  for (int l = tid; l < 1024; l += 256) {
    int h = l >> 6, c = l & 63;
    Wb[h * 72 + c] = (h < 8) ? wb_a[h * 64 + c] : (short)0;
  }
#pragma unroll
  for (int i = 0; i < 4; ++i) {
    int idx = tid + i * 256;
    f32x4 v = *(const f32x4*)(base + idx * 4);
    *(f32x4*)&Xs[(idx >> 4) * 68 + (idx & 15) * 4] = v;
  }
  __syncthreads();
  int wv = tid >> 6, lane = tid & 63;
  float gl = gam[lane], bl = bet[lane];
  for (int e = wv * 16; e < wv * 16 + 16; ++e) {
    float v = Xs[e * 68 + lane];
    float s = wave_red_sum(v), ss = wave_red_sum(v * v);
    float mu = s * 0.015625f, var = ss * 0.015625f - mu * mu;
    Zb[e * 72 + lane] = f2bf((v - mu) * rsqrtf(var + LNEPS) * gl + bl);
  }
  __syncthreads();
  int lhi = lane >> 4, llo = lane & 15;
  int n0 = wv * 16;
  f32x4 acc = {0.f, 0.f, 0.f, 0.f};
#pragma unroll
  for (int ks = 0; ks < 2; ++ks) {
    bf8 a = *(const bf8*)&Wb[llo * 72 + ks * 32 + lhi * 8];
    bf8 bz = *(const bf8*)&Zb[(n0 + llo) * 72 + ks * 32 + lhi * 8];
    acc = MFMA(a, bz, acc);
  }
  int elem = n0 + llo;
#pragma unroll
  for (int r = 0; r < 4; ++r) {
    int h = lhi * 4 + r;
    if (h < 8) bias[(long)(b * 8 + h) * NNe + ein + elem] = f2bf(acc[r] + bbv[h]);
  }
}

// ---------------- fused opm update + triangle ab (per batch) ----------------
__global__ __launch_bounds__(256) void opm_ab_fused(
    const float* __restrict__ pair_in, const short* __restrict__ Tb,
    const short* __restrict__ bo_bf, const float* __restrict__ b_out,
    const float* __restrict__ op_norm, const float* __restrict__ gam,
    const float* __restrict__ bet, const short* __restrict__ wp_a,
    const float* __restrict__ b_abp, const short* __restrict__ wg_a,
    const float* __restrict__ b_abg, float* __restrict__ pair1,
    short* __restrict__ aN, short* __restrict__ bN) {
  int jt = blockIdx.x;   // 0..7
  int i = blockIdx.y;    // 0..511
  int tid = threadIdx.x;
  __shared__ __align__(16) short Tsb[64 * 40];
  __shared__ __align__(16) short Bob[64 * 40];
  __shared__ __align__(16) float Xs[64 * 68];
  __shared__ __align__(16) short Zb[64 * 72];
  __shared__ __align__(16) short Wp[64 * 72];
  __shared__ __align__(16) short Wg[64 * 72];
  {
    int p = tid >> 2, e8 = (tid & 3) * 8;
    *(bf8*)&Tsb[p * 40 + e8] = *(const bf8*)(Tb + (long)i * 2048 + p * 32 + e8);
    *(bf8*)&Bob[p * 40 + e8] = *(const bf8*)(bo_bf + (long)(jt * 64 + p) * 32 + e8);
  }
  for (int l = tid; l < 512; l += 256) {
    int r = l >> 3, c8 = (l & 7) * 8;
    *(bf8*)&Wp[r * 72 + c8] = *(const bf8*)(wp_a + r * 64 + c8);
    *(bf8*)&Wg[r * 72 + c8] = *(const bf8*)(wg_a + r * 64 + c8);
  }
  __syncthreads();
  int wv = tid >> 6, lane = tid & 63;
  int wr = wv >> 1, wc = wv & 1;
  int lhi = lane >> 4, llo = lane & 15;
  // opm: D[j][p] = sum_e Bo[j][e] * T[p][e]
  f32x4 acc[2][2] = {};
  {
    bf8 a0 = *(const bf8*)&Bob[(wr * 32 + llo) * 40 + lhi * 8];
    bf8 a1 = *(const bf8*)&Bob[(wr * 32 + 16 + llo) * 40 + lhi * 8];
    bf8 b0 = *(const bf8*)&Tsb[(wc * 32 + llo) * 40 + lhi * 8];
    bf8 b1 = *(const bf8*)&Tsb[(wc * 32 + 16 + llo) * 40 + lhi * 8];
    acc[0][0] = MFMA(a0, b0, acc[0][0]);
    acc[0][1] = MFMA(a0, b1, acc[0][1]);
    acc[1][0] = MFMA(a1, b0, acc[1][0]);
    acc[1][1] = MFMA(a1, b1, acc[1][1]);
  }
  float nrm = op_norm[0];
  long ebase = (long)i * 512 + jt * 64;
#pragma unroll
  for (int mi = 0; mi < 2; ++mi) {
    int jrow = wr * 32 + mi * 16 + lhi * 4;
#pragma unroll
    for (int ni = 0; ni < 2; ++ni) {
      int p = wc * 32 + ni * 16 + llo;
      float bo = b_out[p];
#pragma unroll
      for (int r = 0; r < 4; ++r) {
        int jl = jrow + r;
        long gidx = (ebase + jl) * 64 + p;
        float v = pair_in[gidx] + (acc[mi][ni][r] + bo) * nrm;
        pair1[gidx] = v;
        Xs[jl * 68 + p] = v;
      }
    }
  }
  __syncthreads();
  float gl = gam[lane], bl = bet[lane];
  for (int e = wv * 16; e < wv * 16 + 16; ++e) {
    float v = Xs[e * 68 + lane];
    float s = wave_red_sum(v), ss = wave_red_sum(v * v);
    float mu = s * 0.015625f, var = ss * 0.015625f - mu * mu;
    Zb[e * 72 + lane] = f2bf((v - mu) * rsqrtf(var + LNEPS) * gl + bl);
  }
  __syncthreads();
  f32x4 ap[2][2] = {};
  f32x4 ag[2][2] = {};
#pragma unroll
  for (int ks = 0; ks < 2; ++ks) {
    bf8 z0 = *(const bf8*)&Zb[(wr * 32 + llo) * 72 + ks * 32 + lhi * 8];
    bf8 z1 = *(const bf8*)&Zb[(wr * 32 + 16 + llo) * 72 + ks * 32 + lhi * 8];
    bf8 p0 = *(const bf8*)&Wp[(wc * 32 + llo) * 72 + ks * 32 + lhi * 8];
    bf8 p1 = *(const bf8*)&Wp[(wc * 32 + 16 + llo) * 72 + ks * 32 + lhi * 8];
    bf8 g0 = *(const bf8*)&Wg[(wc * 32 + llo) * 72 + ks * 32 + lhi * 8];
    bf8 g1 = *(const bf8*)&Wg[(wc * 32 + 16 + llo) * 72 + ks * 32 + lhi * 8];
    ap[0][0] = MFMA(z0, p0, ap[0][0]);
    ap[0][1] = MFMA(z0, p1, ap[0][1]);
    ap[1][0] = MFMA(z1, p0, ap[1][0]);
    ap[1][1] = MFMA(z1, p1, ap[1][1]);
    ag[0][0] = MFMA(z0, g0, ag[0][0]);
    ag[0][1] = MFMA(z0, g1, ag[0][1]);
    ag[1][0] = MFMA(z1, g0, ag[1][0]);
    ag[1][1] = MFMA(z1, g1, ag[1][1]);
  }
#pragma unroll
  for (int mi = 0; mi < 2; ++mi) {
    int elemb = wr * 32 + mi * 16 + lhi * 4;
#pragma unroll
    for (int ni = 0; ni < 2; ++ni) {
      int ch = wc * 32 + ni * 16 + llo;
      float bp = b_abp[ch], bg = b_abg[ch];
      bf4 pack;
#pragma unroll
      for (int r = 0; r < 4; ++r)
        pack[r] = f2bf((ap[mi][ni][r] + bp) * sigmoidf_(ag[mi][ni][r] + bg));
      short* dst = (ch < 32) ? (aN + (long)ch * NNe) : (bN + (long)(ch - 32) * NNe);
      *(bf4*)(dst + ebase + elemb) = pack;
    }
  }
}

// ---------------- triangle einsum -> t bf16 ----------------
__global__ __launch_bounds__(256) void tm_tri_mfma(const short* __restrict__ aN,
                                                   const short* __restrict__ bN,
                                                   short* __restrict__ t_out) {
  int h = blockIdx.z;
  int i0 = blockIdx.y * 64, k0 = blockIdx.x * 64;
  const short* A = aN + (long)h * NNe;
  const short* B = bN + (long)h * NNe;
  __shared__ __align__(16) short A1[64 * 40];
  __shared__ __align__(16) short B1[64 * 40];
  __shared__ __align__(16) short A2[64 * 40];
  __shared__ __align__(16) short B2[64 * 40];
  int tid = threadIdx.x;
  int wv = tid >> 6, lane = tid & 63;
  int wr = wv >> 1, wc = wv & 1;
  int lhi = lane >> 4, llo = lane & 15;
  int r1 = tid >> 2, cp = (tid & 3) * 8;
  int rr = tid >> 3, ip = (tid & 7) * 8;
  f32x4 acc[2][2] = {};
  for (int j0 = 0; j0 < 512; j0 += 32) {
    *(bf8*)&A1[r1 * 40 + cp] = *(const bf8*)(A + (long)(i0 + r1) * 512 + j0 + cp);
    *(bf8*)&B1[r1 * 40 + cp] = *(const bf8*)(B + (long)(k0 + r1) * 512 + j0 + cp);
    bf8 va = *(const bf8*)(A + (long)(j0 + rr) * 512 + i0 + ip);
    bf8 vb = *(const bf8*)(B + (long)(j0 + rr) * 512 + k0 + ip);
#pragma unroll
    for (int q = 0; q < 8; ++q) {
      A2[(ip + q) * 40 + rr] = va[q];
      B2[(ip + q) * 40 + rr] = vb[q];
    }
    __syncthreads();
    bf8 a0 = *(const bf8*)&A1[(wr * 32 + llo) * 40 + lhi * 8];
    bf8 a1 = *(const bf8*)&A1[(wr * 32 + 16 + llo) * 40 + lhi * 8];
    bf8 b0 = *(const bf8*)&B1[(wc * 32 + llo) * 40 + lhi * 8];
    bf8 b1 = *(const bf8*)&B1[(wc * 32 + 16 + llo) * 40 + lhi * 8];
    acc[0][0] = MFMA(a0, b0, acc[0][0]);
    acc[0][1] = MFMA(a0, b1, acc[0][1]);
    acc[1][0] = MFMA(a1, b0, acc[1][0]);
    acc[1][1] = MFMA(a1, b1, acc[1][1]);
    bf8 c0 = *(const bf8*)&A2[(wr * 32 + llo) * 40 + lhi * 8];
    bf8 c1 = *(const bf8*)&A2[(wr * 32 + 16 + llo) * 40 + lhi * 8];
    bf8 d0 = *(const bf8*)&B2[(wc * 32 + llo) * 40 + lhi * 8];
    bf8 d1 = *(const bf8*)&B2[(wc * 32 + 16 + llo) * 40 + lhi * 8];
    acc[0][0] = MFMA(c0, d0, acc[0][0]);
    acc[0][1] = MFMA(c0, d1, acc[0][1]);
    acc[1][0] = MFMA(c1, d0, acc[1][0]);
    acc[1][1] = MFMA(c1, d1, acc[1][1]);
    __syncthreads();
  }
  short* tp = t_out + (long)h * NNe;
#pragma unroll
  for (int mi = 0; mi < 2; ++mi)
#pragma unroll
    for (int ni = 0; ni < 2; ++ni) {
      int row = i0 + wr * 32 + mi * 16 + lhi * 4;
      int col = k0 + wc * 32 + ni * 16 + llo;
#pragma unroll
      for (int r = 0; r < 4; ++r) tp[(long)(row + r) * 512 + col] = f2bf(acc[mi][ni][r]);
    }
}

// ---------------- fused triangle update + pair FFN (per batch, in place) ----------------
__global__ __launch_bounds__(256) void upd_pffn_fused(
    float* __restrict__ pb, const short* __restrict__ t_in,
    const float* __restrict__ g_tm, const float* __restrict__ b_tm,
    const short* __restrict__ wg_a, const float* __restrict__ b_g,
    const short* __restrict__ wz_a, const float* __restrict__ b_z,
    const float* __restrict__ g_tmo, const float* __restrict__ b_tmo,
    const float* __restrict__ g_pf, const float* __restrict__ b_pf,
    const short* __restrict__ w1_a, const float* __restrict__ b1,
    const short* __restrict__ w2_a, const float* __restrict__ b2) {
  __shared__ __align__(16) float Xs[64 * 68];
  __shared__ __align__(16) short Zb[64 * 72];
  __shared__ __align__(16) short Tst[64 * 36];
  __shared__ __align__(16) short Tlb[64 * 40];
  __shared__ __align__(16) short Wgb[64 * 72];
  __shared__ __align__(16) short Wzb[64 * 40];
  __shared__ __align__(16) short W1b[64 * 72];
  __shared__ __align__(16) short W2b[64 * 72];
  int tid = threadIdx.x;
  long e0 = (long)blockIdx.x * 64;
  float* base = pb + e0 * 64;
  for (int l = tid; l < 512; l += 256) {
    int r = l >> 3, c8 = (l & 7) * 8;
    *(bf8*)&Wgb[r * 72 + c8] = *(const bf8*)(wg_a + r * 64 + c8);
    *(bf8*)&W1b[r * 72 + c8] = *(const bf8*)(w1_a + r * 64 + c8);
    *(bf8*)&W2b[r * 72 + c8] = *(const bf8*)(w2_a + r * 64 + c8);
  }
  {
    int r = tid >> 2, c8 = (tid & 3) * 8;
    *(bf8*)&Wzb[r * 40 + c8] = *(const bf8*)(wz_a + r * 32 + c8);
  }
#pragma unroll
  for (int i = 0; i < 4; ++i) {
    int idx = tid + i * 256;
    f32x4 v = *(const f32x4*)(base + idx * 4);
    *(f32x4*)&Xs[(idx >> 4) * 68 + (idx & 15) * 4] = v;
  }
  for (int l = tid; l < 2048; l += 256) {
    int hh = l >> 6, e = l & 63;
    Tst[e * 36 + hh] = t_in[(long)hh * NNe + e0 + e];
  }
  __syncthreads();
  int wv = tid >> 6, lane = tid & 63;
  int wr = wv >> 1, wc = wv & 1;
  int lhi = lane >> 4, llo = lane & 15;
  {
    float gl = g_tm[lane], bl = b_tm[lane];
    for (int e = wv * 16; e < wv * 16 + 16; ++e) {
      float v = Xs[e * 68 + lane];
      float s = wave_red_sum(v), ss = wave_red_sum(v * v);
      float mu = s * 0.015625f, var = ss * 0.015625f - mu * mu;
      Zb[e * 72 + lane] = f2bf((v - mu) * rsqrtf(var + LNEPS) * gl + bl);
    }
  }
  {
    int ch = lane & 31;
    int sel = lane >> 5;
    float go = g_tmo[ch], bo = b_tmo[ch];
    for (int it = 0; it < 8; ++it) {
      int e = wv * 16 + it * 2 + sel;
      float v = bf2f(Tst[e * 36 + ch]);
      float s = half_red_sum(v), ss = half_red_sum(v * v);
      float mu = s * 0.03125f, var = ss * 0.03125f - mu * mu;
      Tlb[e * 40 + ch] = f2bf((v - mu) * rsqrtf(var + LNEPS) * go + bo);
    }
  }
  __syncthreads();
  // gate & z matvecs
  f32x4 accg[2][2] = {};
  f32x4 accz[2][2] = {};
#pragma unroll
  for (int ks = 0; ks < 2; ++ks) {
    bf8 a0 = *(const bf8*)&Wgb[(wr * 32 + llo) * 72 + ks * 32 + lhi * 8];
    bf8 a1 = *(const bf8*)&Wgb[(wr * 32 + 16 + llo) * 72 + ks * 32 + lhi * 8];
    bf8 z0 = *(const bf8*)&Zb[(wc * 32 + llo) * 72 + ks * 32 + lhi * 8];
    bf8 z1 = *(const bf8*)&Zb[(wc * 32 + 16 + llo) * 72 + ks * 32 + lhi * 8];
    accg[0][0] = MFMA(a0, z0, accg[0][0]);
    accg[0][1] = MFMA(a0, z1, accg[0][1]);
    accg[1][0] = MFMA(a1, z0, accg[1][0]);
    accg[1][1] = MFMA(a1, z1, accg[1][1]);
  }
  {
    bf8 a0 = *(const bf8*)&Wzb[(wr * 32 + llo) * 40 + lhi * 8];
    bf8 a1 = *(const bf8*)&Wzb[(wr * 32 + 16 + llo) * 40 + lhi * 8];
    bf8 t0 = *(const bf8*)&Tlb[(wc * 32 + llo) * 40 + lhi * 8];
    bf8 t1 = *(const bf8*)&Tlb[(wc * 32 + 16 + llo) * 40 + lhi * 8];
    accz[0][0] = MFMA(a0, t0, accz[0][0]);
    accz[0][1] = MFMA(a0, t1, accz[0][1]);
    accz[1][0] = MFMA(a1, t0, accz[1][0]);
    accz[1][1] = MFMA(a1, t1, accz[1][1]);
  }
  // p2 = pair1 + gate*z  (lane-local RMW into Xs)
#pragma unroll
  for (int mi = 0; mi < 2; ++mi) {
    int chb = wr * 32 + mi * 16 + lhi * 4;
    f32x4 bgv = *(const f32x4*)(b_g + chb);
    f32x4 bzv = *(const f32x4*)(b_z + chb);
#pragma unroll
    for (int ni = 0; ni < 2; ++ni) {
      int elem = wc * 32 + ni * 16 + llo;
      f32x4 res = *(const f32x4*)&Xs[elem * 68 + chb];
#pragma unroll
      for (int r = 0; r < 4; ++r)
        res[r] = res[r] + (accg[mi][ni][r] + bgv[r]) * (accz[mi][ni][r] + bzv[r]);
      *(f32x4*)&Xs[elem * 68 + chb] = res;
    }
  }
  __syncthreads();
  // pffn LN
  {
    float gl = g_pf[lane], bl = b_pf[lane];
    for (int e = wv * 16; e < wv * 16 + 16; ++e) {
      float v = Xs[e * 68 + lane];
      float s = wave_red_sum(v), ss = wave_red_sum(v * v);
      float mu = s * 0.015625f, var = ss * 0.015625f - mu * mu;
      Zb[e * 72 + lane] = f2bf((v - mu) * rsqrtf(var + LNEPS) * gl + bl);
    }
  }
  __syncthreads();
  f32x4 acc1[2][2] = {};
#pragma unroll
  for (int ks = 0; ks < 2; ++ks) {
    bf8 a0 = *(const bf8*)&W1b[(wr * 32 + llo) * 72 + ks * 32 + lhi * 8];
    bf8 a1 = *(const bf8*)&W1b[(wr * 32 + 16 + llo) * 72 + ks * 32 + lhi * 8];
    bf8 z0 = *(const bf8*)&Zb[(wc * 32 + llo) * 72 + ks * 32 + lhi * 8];
    bf8 z1 = *(const bf8*)&Zb[(wc * 32 + 16 + llo) * 72 + ks * 32 + lhi * 8];
    acc1[0][0] = MFMA(a0, z0, acc1[0][0]);
    acc1[0][1] = MFMA(a0, z1, acc1[0][1]);
    acc1[1][0] = MFMA(a1, z0, acc1[1][0]);
    acc1[1][1] = MFMA(a1, z1, acc1[1][1]);
  }
  __syncthreads();
#pragma unroll
  for (int mi = 0; mi < 2; ++mi) {
    int chb = wr * 32 + mi * 16 + lhi * 4;
    f32x4 bv = *(const f32x4*)(b1 + chb);
#pragma unroll
    for (int ni = 0; ni < 2; ++ni) {
      int elem = wc * 32 + ni * 16 + llo;
      bf4 pack;
#pragma unroll
      for (int r = 0; r < 4; ++r) pack[r] = f2bf(gelu_exact(acc1[mi][ni][r] + bv[r]));
      *(bf4*)&Zb[elem * 72 + chb] = pack;
    }
  }
  __syncthreads();
  f32x4 acc2[2][2] = {};
#pragma unroll
  for (int ks = 0; ks < 2; ++ks) {
    bf8 a0 = *(const bf8*)&W2b[(wr * 32 + llo) * 72 + ks * 32 + lhi * 8];
    bf8 a1 = *(const bf8*)&W2b[(wr * 32 + 16 + llo) * 72 + ks * 32 + lhi * 8];
    bf8 z0 = *(const bf8*)&Zb[(wc * 32 + llo) * 72 + ks * 32 + lhi * 8];
    bf8 z1 = *(const bf8*)&Zb[(wc * 32 + 16 + llo) * 72 + ks * 32 + lhi * 8];
    acc2[0][0] = MFMA(a0, z0, acc2[0][0]);
    acc2[0][1] = MFMA(a0, z1, acc2[0][1]);
    acc2[1][0] = MFMA(a1, z0, acc2[1][0]);
    acc2[1][1] = MFMA(a1, z1, acc2[1][1]);
  }
#pragma unroll
  for (int mi = 0; mi < 2; ++mi) {
    int chb = wr * 32 + mi * 16 + lhi * 4;
    f32x4 bv = *(const f32x4*)(b2 + chb);
#pragma unroll
    for (int ni = 0; ni < 2; ++ni) {
      int elem = wc * 32 + ni * 16 + llo;
      f32x4 res = *(const f32x4*)&Xs[elem * 68 + chb];
      f32x4 o;
#pragma unroll
      for (int r = 0; r < 4; ++r) o[r] = res[r] + acc2[mi][ni][r] + bv[r];
      *(f32x4*)(base + (long)elem * 64 + chb) = o;
    }
  }
}

extern "C" void kernel_launch(void* const* d_in, const int* in_sizes, int n_in,
                              void* d_out, int out_size, void* d_ws, size_t ws_size,
                              hipStream_t stream) {
  const float* x = (const float*)d_in[0];
  const float* pair = (const float*)d_in[1];
  const float* attn_mask = (const float*)d_in[2];
  const float* op_mask = (const float*)d_in[3];
  const float* op_norm = (const float*)d_in[4];
  const float* wq = (const float*)d_in[6];
  const float* wk = (const float*)d_in[7];
  const float* wv_ = (const float*)d_in[8];
  const float* wg = (const float*)d_in[9];
  const float* bg = (const float*)d_in[10];
  const float* wo = (const float*)d_in[11];
  const float* bo = (const float*)d_in[12];
  const float* ln_pair_g = (const float*)d_in[13];
  const float* ln_pair_b = (const float*)d_in[14];
  const float* wb = (const float*)d_in[15];
  const float* bb = (const float*)d_in[16];
  const float* ln_attn_g = (const float*)d_in[17];
  const float* ln_attn_b = (const float*)d_in[18];
  const float* ln_ffn_g = (const float*)d_in[19];
  const float* ln_ffn_b = (const float*)d_in[20];
  const float* w_ffn1 = (const float*)d_in[21];
  const float* b_ffn1 = (const float*)d_in[22];
  const float* w_ffn2 = (const float*)d_in[23];
  const float* b_ffn2 = (const float*)d_in[24];
  const float* ln_opm_g = (const float*)d_in[25];
  const float* ln_opm_b = (const float*)d_in[26];
  const float* w_opm_in = (const float*)d_in[27];
  const float* b_opm_in = (const float*)d_in[28];
  const float* w_opm_out = (const float*)d_in[29];
  const float* b_opm_out = (const float*)d_in[30];
  const float* ln_tm_g = (const float*)d_in[31];
  const float* ln_tm_b = (const float*)d_in[32];
  const float* w_tm_abp = (const float*)d_in[33];
  const float* b_tm_abp = (const float*)d_in[34];
  const float* w_tm_abg = (const float*)d_in[35];
  const float* b_tm_abg = (const float*)d_in[36];
  const float* w_tm_g = (const float*)d_in[37];
  const float* b_tm_g = (const float*)d_in[38];
  const float* w_tm_z = (const float*)d_in[39];
  const float* b_tm_z = (const float*)d_in[40];
  const float* ln_tmo_g = (const float*)d_in[41];
  const float* ln_tmo_b = (const float*)d_in[42];
  const float* ln_pffn_g = (const float*)d_in[43];
  const float* ln_pffn_b = (const float*)d_in[44];
  const float* w_pffn1 = (const float*)d_in[45];
  const float* b_pffn1 = (const float*)d_in[46];
  const float* w_pffn2 = (const float*)d_in[47];
  const float* b_pffn2 = (const float*)d_in[48];

  float* ws = (float*)d_ws;
  // bf16 weight arena (offsets in bf16 elements)
  short* wbf = (short*)ws;
  short* wq_bf = wbf + 0;
  short* wk_bf = wbf + 589824;
  short* wv_bf = wbf + 1179648;
  short* wg_bf = wbf + 1769472;
  short* wo_bf = wbf + 2359296;
  short* wf1_bf = wbf + 2949120;
  short* wf2_bf = wbf + 5308416;
  short* wop_bf = wbf + 7667712;
  short* wb_a = wbf + 7716864;
  short* wabp_a = wbf + 7717376;
  short* wabg_a = wbf + 7721472;
  short* wtg_a = wbf + 7725568;
  short* wtz_a = wbf + 7729664;
  short* wp1_a = wbf + 7731712;
  short* wp2_a = wbf + 7735808;     // arena ends at 7739904 bf16 = 3869952 floats

  short* h_bf = (short*)(ws + 3869952);
  short* q_bf = (short*)(ws + 4656384);
  short* k_bf = (short*)(ws + 5442816);
  short* vT_bf = (short*)(ws + 6229248);
  float* gb = ws + 7015680;
  float* ob = ws + 8588544;
  short* gb_bf = (short*)(ws + 10161408);
  float* x1b = ws + 10947840;
  short* biasb_bf = (short*)(ws + 12520704);   // 8388608 bf16
  short* attn_bf = (short*)(ws + 16715008);    // 8388608 bf16
  short* mffn_bf = (short*)(ws + 20909312);    // 6291456 bf16
  float* abb = ws + 24055040;                  // 131072 f32
  short* abb_bf = (short*)(ws + 24186112);     // 65536 bf16
  short* Tb_bf = (short*)(ws + 24218880);      // 4194304 bf16
  // triangle-stage overlays (attention/ffn buffers dead by then)
  short* aNb = (short*)(ws + 4656384);         // 8388608 bf16
  short* bNb = (short*)(ws + 8850688);         // 8388608 bf16
  short* t_bf = (short*)(ws + 13044992);       // 8388608 bf16

  float* xo = (float*)d_out;
  float* pair1 = xo + 1572864;

  const float qscale = 0.1020620726159658f;  // 96^-0.5

  // --- weight casts ---
  castw_kernel<<<30144, 256, 0, stream>>>(wq, wk, wv_, wg, wo, w_ffn1, w_ffn2, w_opm_in,
                                          wbf, qscale);
  castw2_kernel<<<90, 256, 0, stream>>>(wb, w_tm_abp, w_tm_abg, w_tm_g, w_tm_z,
                                        w_pffn1, w_pffn2, wb_a);
  // --- attention ---
  ln_bf_kernel<<<2048, 256, 0, stream>>>(x, h_bf, ln_attn_g, ln_attn_b, 768);
  gemm_bf<<<dim3(12, 32, 1), 256, 0, stream>>>(h_bf, 768, 0, 0, wq_bf, 768, 0, 0,
                                               nullptr, 0, 0, 0, q_bf, 768,
                                               nullptr, 0, 0, 0, nullptr,
                                               2048, 768, 768, 0, 0, 1);
  gemm_bf<<<dim3(12, 32, 1), 256, 0, stream>>>(h_bf, 768, 0, 0, wk_bf, 768, 0, 0,
                                               nullptr, 0, 0, 0, k_bf, 768,
                                               nullptr, 0, 0, 0, nullptr,
                                               2048, 768, 768, 0, 0, 1);
  gemm_bf<<<dim3(12, 32, 1), 256, 0, stream>>>(h_bf, 768, 0, 0, wv_bf, 768, 0, 0,
                                               nullptr, 0, 0, 0, vT_bf, 0,
                                               nullptr, 0, 0, 0, nullptr,
                                               2048, 768, 768, 0, 1, 1);
  gemm_bf<<<dim3(12, 32, 1), 256, 0, stream>>>(h_bf, 768, 0, 0, wg_bf, 768, 0, 0,
                                               gb, 768, 0, 0, nullptr, 0,
                                               nullptr, 0, 0, 0, bg,
                                               2048, 768, 768, 0, 0, 1);
  pair_bias_mfma<<<16384, 256, 0, stream>>>(pair, ln_pair_g, ln_pair_b, wb_a, bb, biasb_bf);
  attn_fused<<<dim3(32, 8, 4), 256, 0, stream>>>(q_bf, k_bf, biasb_bf, attn_mask, attn_bf);
  gemm_bf<<<dim3(2, 8, 32), 256, 0, stream>>>(attn_bf, 512, 2097152, 262144,
                                              vT_bf, 512, 393216, 49152,
                                              ob, 768, 393216, 96, nullptr, 0,
                                              nullptr, 0, 0, 0, nullptr,
                                              512, 96, 512, 0, 0, 8);
  og_bf<<<6144, 256, 0, stream>>>(gb, ob, gb_bf, 1572864);
  gemm_bf<<<dim3(12, 32, 1), 256, 0, stream>>>(gb_bf, 768, 0, 0, wo_bf, 768, 0, 0,
                                               x1b, 768, 0, 0, nullptr, 0,
                                               x, 768, 0, 0, bo,
                                               2048, 768, 768, 0, 0, 1);
  // --- FFN ---
  ln_bf_kernel<<<2048, 256, 0, stream>>>(x1b, h_bf, ln_ffn_g, ln_ffn_b, 768);
  gemm_bf<<<dim3(48, 32, 1), 256, 0, stream>>>(h_bf, 768, 0, 0, wf1_bf, 768, 0, 0,
                                               nullptr, 0, 0, 0, mffn_bf, 3072,
                                               nullptr, 0, 0, 0, b_ffn1,
                                               2048, 3072, 768, 1, 0, 1);
  gemm_bf<<<dim3(12, 32, 1), 256, 0, stream>>>(mffn_bf, 3072, 0, 0, wf2_bf, 3072, 0, 0,
                                               xo, 768, 0, 0, nullptr, 0,
                                               x1b, 768, 0, 0, b_ffn2,
                                               2048, 768, 3072, 0, 0, 1);
  // --- outer product mean prep ---
  ln_bf_kernel<<<2048, 256, 0, stream>>>(xo, h_bf, ln_opm_g, ln_opm_b, 768);
  gemm_bf<<<dim3(1, 32, 1), 256, 0, stream>>>(h_bf, 768, 0, 0, wop_bf, 768, 0, 0,
                                              abb, 64, 0, 0, nullptr, 0,
                                              nullptr, 0, 0, 0, b_opm_in,
                                              2048, 64, 768, 0, 0, 1);
  opmask_kernel<<<512, 256, 0, stream>>>(abb, op_mask, abb_bf);
  opm_T_kernel<<<dim3(256, 64, 1), dim3(32, 8, 1), 0, stream>>>(abb, w_opm_out, Tb_bf);
  // --- pair stack per batch: opm update + tri-ab, triangle, update + pffn ---
  for (int b = 0; b < 4; ++b) {
    const float* pin = pair + (long)b * NNe * 64;
    float* pbb = pair1 + (long)b * NNe * 64;
    opm_ab_fused<<<dim3(8, 512, 1), 256, 0, stream>>>(
        pin, Tb_bf + (long)b * 1048576, abb_bf + (long)b * 16384, b_opm_out, op_norm,
        ln_tm_g, ln_tm_b, wabp_a, b_tm_abp, wabg_a, b_tm_abg, pbb, aNb, bNb);
    tm_tri_mfma<<<dim3(8, 8, 32), 256, 0, stream>>>(aNb, bNb, t_bf);
    upd_pffn_fused<<<4096, 256, 0, stream>>>(
        pbb, t_bf, ln_tm_g, ln_tm_b, wtg_a, b_tm_g, wtz_a, b_tm_z,
        ln_tmo_g, ln_tmo_b, ln_pffn_g, ln_pffn_b, wp1_a, b_pffn1, wp2_a, b_pffn2);
  }
}

// Round 5
// 1161.797 us; speedup vs baseline: 5.9029x; 1.3839x over previous
//
#include <hip/hip_runtime.h>
#include <hip/hip_bf16.h>
#include <math.h>

#define Nn 512
#define Ee 768
#define Pp 64
#define PHh 32
#define Hh 8
#define Dd 96
#define NNe 262144      // N*N
#define LNEPS 1e-5f

typedef __attribute__((ext_vector_type(8))) short bf8;
typedef __attribute__((ext_vector_type(4))) short bf4;
typedef __attribute__((ext_vector_type(4))) float f32x4;
#define MFMA(a,b,c) __builtin_amdgcn_mfma_f32_16x16x32_bf16(a,b,c,0,0,0)

__device__ __forceinline__ short f2bf(float f) {
  unsigned u = __builtin_bit_cast(unsigned, f);
  unsigned r = (u + 0x7fffu + ((u >> 16) & 1u)) >> 16;
  return (short)r;
}
__device__ __forceinline__ float bf2f(short s) {
  unsigned u = ((unsigned)(unsigned short)s) << 16;
  return __builtin_bit_cast(float, u);
}

__device__ __forceinline__ float wave_red_sum(float v) {
#pragma unroll
  for (int off = 32; off > 0; off >>= 1) v += __shfl_xor(v, off);
  return v;
}
__device__ __forceinline__ float gelu_exact(float v) {
  return 0.5f * v * (1.f + erff(v * 0.70710678118654752f));
}
__device__ __forceinline__ float sigmoidf_(float v) {
  return 1.f / (1.f + expf(-v));
}

// ---------------- weight casts to bf16 arena ----------------
__global__ __launch_bounds__(256) void castw_kernel(
    const float* __restrict__ wq, const float* __restrict__ wk,
    const float* __restrict__ wv, const float* __restrict__ wg,
    const float* __restrict__ wo, const float* __restrict__ f1,
    const float* __restrict__ f2, const float* __restrict__ wop,
    short* __restrict__ dst, float qs) {
  long i = (long)blockIdx.x * 256 + threadIdx.x;
  float v;
  if (i < 589824) v = wq[i] * qs;
  else if (i < 1179648) v = wk[i - 589824];
  else if (i < 1769472) v = wv[i - 1179648];
  else if (i < 2359296) v = wg[i - 1769472];
  else if (i < 2949120) v = wo[i - 2359296];
  else if (i < 5308416) v = f1[i - 2949120];
  else if (i < 7667712) v = f2[i - 5308416];
  else if (i < 7716864) v = wop[i - 7667712];
  else return;
  dst[i] = f2bf(v);
}

__global__ __launch_bounds__(256) void castw2_kernel(
    const float* __restrict__ wb, const float* __restrict__ abp,
    const float* __restrict__ abg, const float* __restrict__ wtg,
    const float* __restrict__ wtz, const float* __restrict__ p1,
    const float* __restrict__ p2, short* __restrict__ dst) {
  int i = blockIdx.x * 256 + threadIdx.x;
  float v;
  if (i < 512) v = wb[i];
  else if (i < 4608) v = abp[i - 512];
  else if (i < 8704) v = abg[i - 4608];
  else if (i < 12800) v = wtg[i - 8704];
  else if (i < 14848) v = wtz[i - 12800];
  else if (i < 18944) v = p1[i - 14848];
  else if (i < 23040) v = p2[i - 18944];
  else return;
  dst[i] = f2bf(v);
}

// ---------------- LayerNorm over last dim C -> bf16 out ----------------
__global__ __launch_bounds__(256) void ln_bf_kernel(const float* __restrict__ in,
                                                    short* __restrict__ out,
                                                    const float* __restrict__ gam,
                                                    const float* __restrict__ bet, int C) {
  int row = blockIdx.x;
  const float* xr = in + (long)row * C;
  short* yr = out + (long)row * C;
  float s = 0.f, ss = 0.f;
  for (int c = threadIdx.x; c < C; c += 256) { float v = xr[c]; s += v; ss += v * v; }
  s = wave_red_sum(s); ss = wave_red_sum(ss);
  __shared__ float sm[4][2];
  int wv = threadIdx.x >> 6, lane = threadIdx.x & 63;
  if (lane == 0) { sm[wv][0] = s; sm[wv][1] = ss; }
  __syncthreads();
  float ts = sm[0][0] + sm[1][0] + sm[2][0] + sm[3][0];
  float tss = sm[0][1] + sm[1][1] + sm[2][1] + sm[3][1];
  float mu = ts / C;
  float var = tss / C - mu * mu;
  float rs = rsqrtf(var + LNEPS);
  for (int c = threadIdx.x; c < C; c += 256) {
    float v = xr[c];
    yr[c] = f2bf((v - mu) * rs * gam[c] + bet[c]);
  }
}

// ---------------- bf16 MFMA NT GEMM ----------------
// act: 0=none, 1=gelu, 2=out = sigmoid(resid)*acc (gate fusion, no bias)
__global__ __launch_bounds__(256) void gemm_bf(
    const short* __restrict__ A, int lda, long asB, long asH,
    const short* __restrict__ Bm, int ldb, long bsB, long bsH,
    float* __restrict__ outF, int ldf, long fsB, long fsH,
    short* __restrict__ outB, int ldob,
    const float* __restrict__ resid, int ldr, long rsB, long rsH,
    const float* __restrict__ bias,
    int M, int N, int K, int act, int vtrans, int Hdim) {
  int bz = blockIdx.z, bb = bz / Hdim, hh = bz % Hdim;
  A += bb * asB + hh * asH;
  Bm += bb * bsB + hh * bsH;
  if (outF) outF += bb * fsB + hh * fsH;
  if (outB) outB += bb * fsB + hh * fsH;
  if (resid) resid += bb * rsB + hh * rsH;
  __shared__ __align__(16) short As[64 * 40];
  __shared__ __align__(16) short Bs[64 * 40];
  int m0 = blockIdx.y * 64, n0 = blockIdx.x * 64;
  int tid = threadIdx.x;
  int wv = tid >> 6, lane = tid & 63;
  int wr = wv >> 1, wc = wv & 1;
  int lhi = lane >> 4, llo = lane & 15;
  int r4 = tid >> 2, c8 = (tid & 3) * 8;
  f32x4 acc[2][2] = {};
  for (int k0 = 0; k0 < K; k0 += 32) {
    *(bf8*)&As[r4 * 40 + c8] = *(const bf8*)(A + (long)(m0 + r4) * lda + k0 + c8);
    bf8 bv = {};
    if (n0 + r4 < N) bv = *(const bf8*)(Bm + (long)(n0 + r4) * ldb + k0 + c8);
    *(bf8*)&Bs[r4 * 40 + c8] = bv;
    __syncthreads();
    bf8 a0 = *(const bf8*)&As[(wr * 32 + llo) * 40 + lhi * 8];
    bf8 a1 = *(const bf8*)&As[(wr * 32 + 16 + llo) * 40 + lhi * 8];
    bf8 b0 = *(const bf8*)&Bs[(wc * 32 + llo) * 40 + lhi * 8];
    bf8 b1 = *(const bf8*)&Bs[(wc * 32 + 16 + llo) * 40 + lhi * 8];
    acc[0][0] = MFMA(a0, b0, acc[0][0]);
    acc[0][1] = MFMA(a0, b1, acc[0][1]);
    acc[1][0] = MFMA(a1, b0, acc[1][0]);
    acc[1][1] = MFMA(a1, b1, acc[1][1]);
    __syncthreads();
  }
#pragma unroll
  for (int mi = 0; mi < 2; ++mi) {
    int gmb = m0 + wr * 32 + mi * 16 + lhi * 4;
#pragma unroll
    for (int ni = 0; ni < 2; ++ni) {
      int gn = n0 + wc * 32 + ni * 16 + llo;
      if (gn >= N) continue;
      float bv = bias ? bias[gn] : 0.f;
      float vr[4];
#pragma unroll
      for (int r = 0; r < 4; ++r) {
        float v = acc[mi][ni][r] + bv;
        if (resid) {
          float rv = resid[(long)(gmb + r) * ldr + gn];
          if (act == 2) v = sigmoidf_(rv) * acc[mi][ni][r];
          else v += rv;
        }
        if (act == 1) v = gelu_exact(v);
        vr[r] = v;
      }
      if (outF) {
#pragma unroll
        for (int r = 0; r < 4; ++r) outF[(long)(gmb + r) * ldf + gn] = vr[r];
      }
      if (outB) {
        if (vtrans) {
          bf4 pk;
#pragma unroll
          for (int r = 0; r < 4; ++r) pk[r] = f2bf(vr[r]);
          *(bf4*)(outB + ((long)((gmb >> 9) * 768 + gn) * 512 + (gmb & 511))) = pk;
        } else {
#pragma unroll
          for (int r = 0; r < 4; ++r) outB[(long)(gmb + r) * ldob + gn] = f2bf(vr[r]);
        }
      }
    }
  }
}

// ---------------- QKVG combined projection: W rows 0..3071 = wq|wk|wv|wg ----------------
__global__ __launch_bounds__(256) void gemm_qkvg(
    const short* __restrict__ A, const short* __restrict__ W,
    short* __restrict__ q_bf, short* __restrict__ k_bf,
    short* __restrict__ vT_bf, float* __restrict__ gb,
    const float* __restrict__ bg) {
  __shared__ __align__(16) short As[64 * 40];
  __shared__ __align__(16) short Bs[64 * 40];
  int m0 = blockIdx.y * 64, n0 = blockIdx.x * 64;
  int sec = n0 / 768;
  int cbase = n0 - sec * 768;
  int tid = threadIdx.x;
  int wv = tid >> 6, lane = tid & 63;
  int wr = wv >> 1, wc = wv & 1;
  int lhi = lane >> 4, llo = lane & 15;
  int r4 = tid >> 2, c8 = (tid & 3) * 8;
  f32x4 acc[2][2] = {};
  for (int k0 = 0; k0 < 768; k0 += 32) {
    *(bf8*)&As[r4 * 40 + c8] = *(const bf8*)(A + (long)(m0 + r4) * 768 + k0 + c8);
    *(bf8*)&Bs[r4 * 40 + c8] = *(const bf8*)(W + (long)(n0 + r4) * 768 + k0 + c8);
    __syncthreads();
    bf8 a0 = *(const bf8*)&As[(wr * 32 + llo) * 40 + lhi * 8];
    bf8 a1 = *(const bf8*)&As[(wr * 32 + 16 + llo) * 40 + lhi * 8];
    bf8 b0 = *(const bf8*)&Bs[(wc * 32 + llo) * 40 + lhi * 8];
    bf8 b1 = *(const bf8*)&Bs[(wc * 32 + 16 + llo) * 40 + lhi * 8];
    acc[0][0] = MFMA(a0, b0, acc[0][0]);
    acc[0][1] = MFMA(a0, b1, acc[0][1]);
    acc[1][0] = MFMA(a1, b0, acc[1][0]);
    acc[1][1] = MFMA(a1, b1, acc[1][1]);
    __syncthreads();
  }
#pragma unroll
  for (int mi = 0; mi < 2; ++mi) {
    int gmb = m0 + wr * 32 + mi * 16 + lhi * 4;
#pragma unroll
    for (int ni = 0; ni < 2; ++ni) {
      int cn = cbase + wc * 32 + ni * 16 + llo;
      if (sec == 0) {
#pragma unroll
        for (int r = 0; r < 4; ++r) q_bf[(long)(gmb + r) * 768 + cn] = f2bf(acc[mi][ni][r]);
      } else if (sec == 1) {
#pragma unroll
        for (int r = 0; r < 4; ++r) k_bf[(long)(gmb + r) * 768 + cn] = f2bf(acc[mi][ni][r]);
      } else if (sec == 2) {
        bf4 pk;
#pragma unroll
        for (int r = 0; r < 4; ++r) pk[r] = f2bf(acc[mi][ni][r]);
        *(bf4*)(vT_bf + ((long)((gmb >> 9) * 768 + cn) * 512 + (gmb & 511))) = pk;
      } else {
        float bv = bg[cn];
#pragma unroll
        for (int r = 0; r < 4; ++r) gb[(long)(gmb + r) * 768 + cn] = acc[mi][ni][r] + bv;
      }
    }
  }
}

// ---------------- fused scores + softmax (flash-row, 16 rows/block) ----------------
__global__ __launch_bounds__(256) void attn_fused(
    const short* __restrict__ q_bf, const short* __restrict__ k_bf,
    const short* __restrict__ bias_bf, const float* __restrict__ mask,
    short* __restrict__ out_bf) {
  int it = blockIdx.x, h = blockIdx.y, b = blockIdx.z;
  int tid = threadIdx.x;
  int wv = tid >> 6, lane = tid & 63;
  int lhi = lane >> 4, llo = lane & 15;
  int i0 = it * 16;
  long qoff = ((long)(b * 512 + i0)) * 768 + h * 96;
  bf8 qf[3];
#pragma unroll
  for (int ks = 0; ks < 3; ++ks)
    qf[ks] = *(const bf8*)(q_bf + qoff + (long)llo * 768 + ks * 32 + lhi * 8);
  long koff = ((long)b * 512) * 768 + h * 96;
  long bioff = (long)(b * 8 + h) * NNe + (long)i0 * 512;
  long moff = (long)b * NNe + (long)i0 * 512;
  float sv[8][4];
  int jb0 = wv * 128;
#pragma unroll
  for (int jf = 0; jf < 8; ++jf) {
    int jb = jb0 + jf * 16;
    f32x4 acc = {0.f, 0.f, 0.f, 0.f};
#pragma unroll
    for (int ks = 0; ks < 3; ++ks) {
      bf8 kf = *(const bf8*)(k_bf + koff + (long)(jb + llo) * 768 + ks * 32 + lhi * 8);
      acc = MFMA(qf[ks], kf, acc);
    }
#pragma unroll
    for (int r = 0; r < 4; ++r) {
      int irow = lhi * 4 + r;
      int j = jb + llo;
      float bia = bf2f(bias_bf[bioff + (long)irow * 512 + j]);
      float mk = mask[moff + (long)irow * 512 + j];
      sv[jf][r] = acc[r] + bia + mk;
    }
  }
  __shared__ float redA[4][20];
  __shared__ float redB[4][20];
  float rmax[4];
#pragma unroll
  for (int r = 0; r < 4; ++r) {
    float m = sv[0][r];
#pragma unroll
    for (int jf = 1; jf < 8; ++jf) m = fmaxf(m, sv[jf][r]);
#pragma unroll
    for (int off = 1; off < 16; off <<= 1) m = fmaxf(m, __shfl_xor(m, off, 16));
    if (llo == 0) redA[wv][lhi * 4 + r] = m;
  }
  __syncthreads();
#pragma unroll
  for (int r = 0; r < 4; ++r) {
    int row = lhi * 4 + r;
    rmax[r] = fmaxf(fmaxf(redA[0][row], redA[1][row]),
                    fmaxf(redA[2][row], redA[3][row]));
  }
  float rsum[4] = {0.f, 0.f, 0.f, 0.f};
#pragma unroll
  for (int jf = 0; jf < 8; ++jf)
#pragma unroll
    for (int r = 0; r < 4; ++r) {
      float e = __expf(sv[jf][r] - rmax[r]);
      sv[jf][r] = e;
      rsum[r] += e;
    }
#pragma unroll
  for (int r = 0; r < 4; ++r) {
#pragma unroll
    for (int off = 1; off < 16; off <<= 1) rsum[r] += __shfl_xor(rsum[r], off, 16);
    if (llo == 0) redB[wv][lhi * 4 + r] = rsum[r];
  }
  __syncthreads();
#pragma unroll
  for (int r = 0; r < 4; ++r) {
    int row = lhi * 4 + r;
    float s = redB[0][row] + redB[1][row] + redB[2][row] + redB[3][row];
    float inv = 1.f / s;
#pragma unroll
    for (int jf = 0; jf < 8; ++jf) {
      int j = jb0 + jf * 16 + llo;
      out_bf[bioff + (long)row * 512 + j] = f2bf(sv[jf][r] * inv);
    }
  }
}

// ---------------- ab *= op_mask ; emit b-half bf16 ----------------
__global__ __launch_bounds__(256) void opmask_kernel(float* __restrict__ ab,
                                                     const float* __restrict__ mask,
                                                     short* __restrict__ bo_bf) {
  int idx = blockIdx.x * 256 + threadIdx.x;
  if (idx < 131072) {
    float v = ab[idx] * mask[idx >> 6];
    ab[idx] = v;
    int ch = idx & 63;
    if (ch >= 32) bo_bf[(idx >> 6) * 32 + ch - 32] = f2bf(v);
  }
}

// ---------------- T[row,p,e] (bf16) = sum_d a_o[row,d] * w[p, d*32+e] ----------------
__global__ __launch_bounds__(256) void opm_T_kernel(const float* __restrict__ ab,
                                                    const float* __restrict__ w,
                                                    short* __restrict__ T) {
  int p = blockIdx.y;
  int row = blockIdx.x * 8 + threadIdx.y;
  int e = threadIdx.x;
  const float* a = ab + (long)row * 64;
  const float* wp = w + p * 1024 + e;
  float acc = 0.f;
#pragma unroll
  for (int d = 0; d < 32; ++d) acc += a[d] * wp[d * 32];
  T[((long)row * 64 + p) * 32 + e] = f2bf(acc);
}

// ---------------- pair bias v2: register LN, no shuffles ----------------
__global__ __launch_bounds__(256) void pair_bias_mfma(
    const float* __restrict__ pair, const float* __restrict__ gam,
    const float* __restrict__ bet, const short* __restrict__ wb_a,
    const float* __restrict__ bbv, short* __restrict__ bias) {
  __shared__ __align__(16) short Zb[64 * 72];
  __shared__ __align__(16) short Wb[16 * 72];
  __shared__ float sp[4][2][72];
  int tid = threadIdx.x;
  long e0 = (long)blockIdx.x * 64;
  int b = (int)(e0 >> 18);
  long ein = e0 & (NNe - 1);
  const float* base = pair + e0 * 64;
  for (int l = tid; l < 1024; l += 256) {
    int h = l >> 6, c = l & 63;
    Wb[h * 72 + c] = (h < 8) ? wb_a[h * 64 + c] : (short)0;
  }
  int e = tid & 63, q = tid >> 6;
  f32x4 v4[4];
  float s = 0.f, ss = 0.f;
#pragma unroll
  for (int k = 0; k < 4; ++k) {
    v4[k] = *(const f32x4*)(base + (long)e * 64 + q * 16 + k * 4);
#pragma unroll
    for (int u = 0; u < 4; ++u) { float v = v4[k][u]; s += v; ss += v * v; }
  }
  sp[q][0][e] = s; sp[q][1][e] = ss;
  __syncthreads();
  float ts = sp[0][0][e] + sp[1][0][e] + sp[2][0][e] + sp[3][0][e];
  float tss = sp[0][1][e] + sp[1][1][e] + sp[2][1][e] + sp[3][1][e];
  float mu = ts * 0.015625f, var = tss * 0.015625f - mu * mu;
  float rs = rsqrtf(var + LNEPS);
#pragma unroll
  for (int k = 0; k < 4; ++k) {
    bf4 pk;
#pragma unroll
    for (int u = 0; u < 4; ++u) {
      int c = q * 16 + k * 4 + u;
      pk[u] = f2bf((v4[k][u] - mu) * rs * gam[c] + bet[c]);
    }
    *(bf4*)&Zb[e * 72 + q * 16 + k * 4] = pk;
  }
  __syncthreads();
  int wv = tid >> 6, lane = tid & 63;
  int lhi = lane >> 4, llo = lane & 15;
  int n0 = wv * 16;
  f32x4 acc = {0.f, 0.f, 0.f, 0.f};
#pragma unroll
  for (int ks = 0; ks < 2; ++ks) {
    bf8 a = *(const bf8*)&Wb[llo * 72 + ks * 32 + lhi * 8];
    bf8 bz = *(const bf8*)&Zb[(n0 + llo) * 72 + ks * 32 + lhi * 8];
    acc = MFMA(a, bz, acc);
  }
  int elem = n0 + llo;
#pragma unroll
  for (int r = 0; r < 4; ++r) {
    int h = lhi * 4 + r;
    if (h < 8) bias[(long)(b * 8 + h) * NNe + ein + elem] = f2bf(acc[r] + bbv[h]);
  }
}

// ---------------- fused opm update + triangle ab v2 ----------------
__global__ __launch_bounds__(256) void opm_ab_fused(
    const float* __restrict__ pair_in, const short* __restrict__ Tb,
    const short* __restrict__ bo_bf, const float* __restrict__ b_out,
    const float* __restrict__ op_norm, const float* __restrict__ gam,
    const float* __restrict__ bet, const short* __restrict__ wp_a,
    const float* __restrict__ b_abp, const short* __restrict__ wg_a,
    const float* __restrict__ b_abg, float* __restrict__ pair1,
    short* __restrict__ aN, short* __restrict__ bN) {
  int jt = blockIdx.x;   // 0..7
  int i = blockIdx.y;    // 0..511
  int tid = threadIdx.x;
  __shared__ __align__(16) short Tsb[64 * 40];
  __shared__ __align__(16) short Bob[64 * 40];
  __shared__ float Xs[64 * 65];
  __shared__ __align__(16) short Zb[64 * 72];
  __shared__ __align__(16) short Wp[64 * 72];
  __shared__ __align__(16) short Wg[64 * 72];
  __shared__ float sp[4][2][72];
  {
    int p = tid >> 2, e8 = (tid & 3) * 8;
    *(bf8*)&Tsb[p * 40 + e8] = *(const bf8*)(Tb + (long)i * 2048 + p * 32 + e8);
    *(bf8*)&Bob[p * 40 + e8] = *(const bf8*)(bo_bf + (long)(jt * 64 + p) * 32 + e8);
  }
  for (int l = tid; l < 512; l += 256) {
    int r = l >> 3, c8 = (l & 7) * 8;
    *(bf8*)&Wp[r * 72 + c8] = *(const bf8*)(wp_a + r * 64 + c8);
    *(bf8*)&Wg[r * 72 + c8] = *(const bf8*)(wg_a + r * 64 + c8);
  }
  long ebase = (long)i * 512 + jt * 64;
  const float* pbase = pair_in + ebase * 64;
#pragma unroll
  for (int it2 = 0; it2 < 4; ++it2) {
    int idx = tid + it2 * 256;
    int j = idx >> 4, c4 = (idx & 15) * 4;
    f32x4 v = *(const f32x4*)(pbase + (long)j * 64 + c4);
#pragma unroll
    for (int u = 0; u < 4; ++u) Xs[j * 65 + c4 + u] = v[u];
  }
  __syncthreads();
  int wv = tid >> 6, lane = tid & 63;
  int wr = wv >> 1, wc = wv & 1;
  int lhi = lane >> 4, llo = lane & 15;
  // opm: D[j][p] = sum_e Bo[j][e] * T[p][e]
  f32x4 acc[2][2] = {};
  {
    bf8 a0 = *(const bf8*)&Bob[(wr * 32 + llo) * 40 + lhi * 8];
    bf8 a1 = *(const bf8*)&Bob[(wr * 32 + 16 + llo) * 40 + lhi * 8];
    bf8 b0 = *(const bf8*)&Tsb[(wc * 32 + llo) * 40 + lhi * 8];
    bf8 b1 = *(const bf8*)&Tsb[(wc * 32 + 16 + llo) * 40 + lhi * 8];
    acc[0][0] = MFMA(a0, b0, acc[0][0]);
    acc[0][1] = MFMA(a0, b1, acc[0][1]);
    acc[1][0] = MFMA(a1, b0, acc[1][0]);
    acc[1][1] = MFMA(a1, b1, acc[1][1]);
  }
  float nrm = op_norm[0];
#pragma unroll
  for (int mi = 0; mi < 2; ++mi) {
    int jrow = wr * 32 + mi * 16 + lhi * 4;
#pragma unroll
    for (int ni = 0; ni < 2; ++ni) {
      int p = wc * 32 + ni * 16 + llo;
      float bo = b_out[p];
#pragma unroll
      for (int r = 0; r < 4; ++r)
        Xs[(jrow + r) * 65 + p] += (acc[mi][ni][r] + bo) * nrm;
    }
  }
  __syncthreads();
  // coalesced pair1 writeout
#pragma unroll
  for (int it2 = 0; it2 < 4; ++it2) {
    int idx = tid + it2 * 256;
    int j = idx >> 4, c4 = (idx & 15) * 4;
    f32x4 o;
#pragma unroll
    for (int u = 0; u < 4; ++u) o[u] = Xs[j * 65 + c4 + u];
    *(f32x4*)(pair1 + ebase * 64 + (long)j * 64 + c4) = o;
  }
  // LN (register partials)
  int e = tid & 63, q = tid >> 6;
  float vv[16], s = 0.f, ss = 0.f;
#pragma unroll
  for (int k = 0; k < 16; ++k) {
    float v = Xs[e * 65 + q * 16 + k];
    vv[k] = v; s += v; ss += v * v;
  }
  sp[q][0][e] = s; sp[q][1][e] = ss;
  __syncthreads();
  {
    float ts = sp[0][0][e] + sp[1][0][e] + sp[2][0][e] + sp[3][0][e];
    float tss = sp[0][1][e] + sp[1][1][e] + sp[2][1][e] + sp[3][1][e];
    float mu = ts * 0.015625f, var = tss * 0.015625f - mu * mu;
    float rs = rsqrtf(var + LNEPS);
#pragma unroll
    for (int k = 0; k < 4; ++k) {
      bf4 pk;
#pragma unroll
      for (int u = 0; u < 4; ++u) {
        int c = q * 16 + k * 4 + u;
        pk[u] = f2bf((vv[k * 4 + u] - mu) * rs * gam[c] + bet[c]);
      }
      *(bf4*)&Zb[e * 72 + q * 16 + k * 4] = pk;
    }
  }
  __syncthreads();
  f32x4 ap[2][2] = {};
  f32x4 ag[2][2] = {};
#pragma unroll
  for (int ks = 0; ks < 2; ++ks) {
    bf8 z0 = *(const bf8*)&Zb[(wr * 32 + llo) * 72 + ks * 32 + lhi * 8];
    bf8 z1 = *(const bf8*)&Zb[(wr * 32 + 16 + llo) * 72 + ks * 32 + lhi * 8];
    bf8 p0 = *(const bf8*)&Wp[(wc * 32 + llo) * 72 + ks * 32 + lhi * 8];
    bf8 p1 = *(const bf8*)&Wp[(wc * 32 + 16 + llo) * 72 + ks * 32 + lhi * 8];
    bf8 g0 = *(const bf8*)&Wg[(wc * 32 + llo) * 72 + ks * 32 + lhi * 8];
    bf8 g1 = *(const bf8*)&Wg[(wc * 32 + 16 + llo) * 72 + ks * 32 + lhi * 8];
    ap[0][0] = MFMA(z0, p0, ap[0][0]);
    ap[0][1] = MFMA(z0, p1, ap[0][1]);
    ap[1][0] = MFMA(z1, p0, ap[1][0]);
    ap[1][1] = MFMA(z1, p1, ap[1][1]);
    ag[0][0] = MFMA(z0, g0, ag[0][0]);
    ag[0][1] = MFMA(z0, g1, ag[0][1]);
    ag[1][0] = MFMA(z1, g0, ag[1][0]);
    ag[1][1] = MFMA(z1, g1, ag[1][1]);
  }
#pragma unroll
  for (int mi = 0; mi < 2; ++mi) {
    int elemb = wr * 32 + mi * 16 + lhi * 4;
#pragma unroll
    for (int ni = 0; ni < 2; ++ni) {
      int ch = wc * 32 + ni * 16 + llo;
      float bp = b_abp[ch], bg = b_abg[ch];
      bf4 pack;
#pragma unroll
      for (int r = 0; r < 4; ++r)
        pack[r] = f2bf((ap[mi][ni][r] + bp) * sigmoidf_(ag[mi][ni][r] + bg));
      short* dst = (ch < 32) ? (aN + (long)ch * NNe) : (bN + (long)(ch - 32) * NNe);
      *(bf4*)(dst + ebase + elemb) = pack;
    }
  }
}

// ---------------- triangle einsum -> t bf16 ----------------
__global__ __launch_bounds__(256) void tm_tri_mfma(const short* __restrict__ aN,
                                                   const short* __restrict__ bN,
                                                   short* __restrict__ t_out) {
  int h = blockIdx.z;
  int i0 = blockIdx.y * 64, k0 = blockIdx.x * 64;
  const short* A = aN + (long)h * NNe;
  const short* B = bN + (long)h * NNe;
  __shared__ __align__(16) short A1[64 * 40];
  __shared__ __align__(16) short B1[64 * 40];
  __shared__ __align__(16) short A2[64 * 40];
  __shared__ __align__(16) short B2[64 * 40];
  int tid = threadIdx.x;
  int wv = tid >> 6, lane = tid & 63;
  int wr = wv >> 1, wc = wv & 1;
  int lhi = lane >> 4, llo = lane & 15;
  int r1 = tid >> 2, cp = (tid & 3) * 8;
  int rr = tid >> 3, ip = (tid & 7) * 8;
  f32x4 acc[2][2] = {};
  for (int j0 = 0; j0 < 512; j0 += 32) {
    *(bf8*)&A1[r1 * 40 + cp] = *(const bf8*)(A + (long)(i0 + r1) * 512 + j0 + cp);
    *(bf8*)&B1[r1 * 40 + cp] = *(const bf8*)(B + (long)(k0 + r1) * 512 + j0 + cp);
    bf8 va = *(const bf8*)(A + (long)(j0 + rr) * 512 + i0 + ip);
    bf8 vb = *(const bf8*)(B + (long)(j0 + rr) * 512 + k0 + ip);
#pragma unroll
    for (int q = 0; q < 8; ++q) {
      A2[(ip + q) * 40 + rr] = va[q];
      B2[(ip + q) * 40 + rr] = vb[q];
    }
    __syncthreads();
    bf8 a0 = *(const bf8*)&A1[(wr * 32 + llo) * 40 + lhi * 8];
    bf8 a1 = *(const bf8*)&A1[(wr * 32 + 16 + llo) * 40 + lhi * 8];
    bf8 b0 = *(const bf8*)&B1[(wc * 32 + llo) * 40 + lhi * 8];
    bf8 b1 = *(const bf8*)&B1[(wc * 32 + 16 + llo) * 40 + lhi * 8];
    acc[0][0] = MFMA(a0, b0, acc[0][0]);
    acc[0][1] = MFMA(a0, b1, acc[0][1]);
    acc[1][0] = MFMA(a1, b0, acc[1][0]);
    acc[1][1] = MFMA(a1, b1, acc[1][1]);
    bf8 c0 = *(const bf8*)&A2[(wr * 32 + llo) * 40 + lhi * 8];
    bf8 c1 = *(const bf8*)&A2[(wr * 32 + 16 + llo) * 40 + lhi * 8];
    bf8 d0 = *(const bf8*)&B2[(wc * 32 + llo) * 40 + lhi * 8];
    bf8 d1 = *(const bf8*)&B2[(wc * 32 + 16 + llo) * 40 + lhi * 8];
    acc[0][0] = MFMA(c0, d0, acc[0][0]);
    acc[0][1] = MFMA(c0, d1, acc[0][1]);
    acc[1][0] = MFMA(c1, d0, acc[1][0]);
    acc[1][1] = MFMA(c1, d1, acc[1][1]);
    __syncthreads();
  }
  short* tp = t_out + (long)h * NNe;
#pragma unroll
  for (int mi = 0; mi < 2; ++mi)
#pragma unroll
    for (int ni = 0; ni < 2; ++ni) {
      int row = i0 + wr * 32 + mi * 16 + lhi * 4;
      int col = k0 + wc * 32 + ni * 16 + llo;
#pragma unroll
      for (int r = 0; r < 4; ++r) tp[(long)(row + r) * 512 + col] = f2bf(acc[mi][ni][r]);
    }
}

// ---------------- fused triangle update + pair FFN v2 (in place) ----------------
__global__ __launch_bounds__(256) void upd_pffn_fused(
    float* __restrict__ pb, const short* __restrict__ t_in,
    const float* __restrict__ g_tm, const float* __restrict__ b_tm,
    const short* __restrict__ wg_a, const float* __restrict__ b_g,
    const short* __restrict__ wz_a, const float* __restrict__ b_z,
    const float* __restrict__ g_tmo, const float* __restrict__ b_tmo,
    const float* __restrict__ g_pf, const float* __restrict__ b_pf,
    const short* __restrict__ w1_a, const float* __restrict__ b1,
    const short* __restrict__ w2_a, const float* __restrict__ b2) {
  __shared__ float Xs[64 * 65];
  __shared__ __align__(16) short Zb[64 * 72];
  __shared__ __align__(16) short Tlb[64 * 40];
  __shared__ __align__(16) short Wgb[64 * 72];
  __shared__ __align__(16) short Wzb[64 * 40];
  __shared__ __align__(16) short W1b[64 * 72];
  __shared__ __align__(16) short W2b[64 * 72];
  __shared__ float spA[4][2][72];
  __shared__ float spB[4][2][72];
  int tid = threadIdx.x;
  long e0 = (long)blockIdx.x * 64;
  float* base = pb + e0 * 64;
  for (int l = tid; l < 512; l += 256) {
    int r = l >> 3, c8 = (l & 7) * 8;
    *(bf8*)&Wgb[r * 72 + c8] = *(const bf8*)(wg_a + r * 64 + c8);
    *(bf8*)&W1b[r * 72 + c8] = *(const bf8*)(w1_a + r * 64 + c8);
    *(bf8*)&W2b[r * 72 + c8] = *(const bf8*)(w2_a + r * 64 + c8);
  }
  {
    int r = tid >> 2, c8 = (tid & 3) * 8;
    *(bf8*)&Wzb[r * 40 + c8] = *(const bf8*)(wz_a + r * 32 + c8);
  }
#pragma unroll
  for (int it2 = 0; it2 < 4; ++it2) {
    int idx = tid + it2 * 256;
    int j = idx >> 4, c4 = (idx & 15) * 4;
    f32x4 v = *(const f32x4*)(base + (long)j * 64 + c4);
#pragma unroll
    for (int u = 0; u < 4; ++u) Xs[j * 65 + c4 + u] = v[u];
  }
  int e = tid & 63, q = tid >> 6;
  // t loads + LN32 partials (global reads, independent)
  float tt[8];
  {
    float sB = 0.f, ssB = 0.f;
#pragma unroll
    for (int k = 0; k < 8; ++k) {
      float v = bf2f(t_in[(long)(q * 8 + k) * NNe + e0 + e]);
      tt[k] = v; sB += v; ssB += v * v;
    }
    spB[q][0][e] = sB; spB[q][1][e] = ssB;
  }
  __syncthreads();   // (1) Xs, spB, weights
  {
    float ts = spB[0][0][e] + spB[1][0][e] + spB[2][0][e] + spB[3][0][e];
    float tss = spB[0][1][e] + spB[1][1][e] + spB[2][1][e] + spB[3][1][e];
    float mu = ts * 0.03125f, var = tss * 0.03125f - mu * mu;
    float rs = rsqrtf(var + LNEPS);
    bf8 pk;
#pragma unroll
    for (int k = 0; k < 8; ++k) {
      int c = q * 8 + k;
      pk[k] = f2bf((tt[k] - mu) * rs * g_tmo[c] + b_tmo[c]);
    }
    *(bf8*)&Tlb[e * 40 + q * 8] = pk;
  }
  float vv[16];
  {
    float s = 0.f, ss = 0.f;
#pragma unroll
    for (int k = 0; k < 16; ++k) {
      float v = Xs[e * 65 + q * 16 + k];
      vv[k] = v; s += v; ss += v * v;
    }
    spA[q][0][e] = s; spA[q][1][e] = ss;
  }
  __syncthreads();   // (2)
  {
    float ts = spA[0][0][e] + spA[1][0][e] + spA[2][0][e] + spA[3][0][e];
    float tss = spA[0][1][e] + spA[1][1][e] + spA[2][1][e] + spA[3][1][e];
    float mu = ts * 0.015625f, var = tss * 0.015625f - mu * mu;
    float rs = rsqrtf(var + LNEPS);
#pragma unroll
    for (int k = 0; k < 4; ++k) {
      bf4 pk;
#pragma unroll
      for (int u = 0; u < 4; ++u) {
        int c = q * 16 + k * 4 + u;
        pk[u] = f2bf((vv[k * 4 + u] - mu) * rs * g_tm[c] + b_tm[c]);
      }
      *(bf4*)&Zb[e * 72 + q * 16 + k * 4] = pk;
    }
  }
  __syncthreads();   // (3) Zb, Tlb ready
  int wv = tid >> 6, lane = tid & 63;
  int wr = wv >> 1, wc = wv & 1;
  int lhi = lane >> 4, llo = lane & 15;
  f32x4 accg[2][2] = {};
  f32x4 accz[2][2] = {};
#pragma unroll
  for (int ks = 0; ks < 2; ++ks) {
    bf8 a0 = *(const bf8*)&Wgb[(wr * 32 + llo) * 72 + ks * 32 + lhi * 8];
    bf8 a1 = *(const bf8*)&Wgb[(wr * 32 + 16 + llo) * 72 + ks * 32 + lhi * 8];
    bf8 z0 = *(const bf8*)&Zb[(wc * 32 + llo) * 72 + ks * 32 + lhi * 8];
    bf8 z1 = *(const bf8*)&Zb[(wc * 32 + 16 + llo) * 72 + ks * 32 + lhi * 8];
    accg[0][0] = MFMA(a0, z0, accg[0][0]);
    accg[0][1] = MFMA(a0, z1, accg[0][1]);
    accg[1][0] = MFMA(a1, z0, accg[1][0]);
    accg[1][1] = MFMA(a1, z1, accg[1][1]);
  }
  {
    bf8 a0 = *(const bf8*)&Wzb[(wr * 32 + llo) * 40 + lhi * 8];
    bf8 a1 = *(const bf8*)&Wzb[(wr * 32 + 16 + llo) * 40 + lhi * 8];
    bf8 t0 = *(const bf8*)&Tlb[(wc * 32 + llo) * 40 + lhi * 8];
    bf8 t1 = *(const bf8*)&Tlb[(wc * 32 + 16 + llo) * 40 + lhi * 8];
    accz[0][0] = MFMA(a0, t0, accz[0][0]);
    accz[0][1] = MFMA(a0, t1, accz[0][1]);
    accz[1][0] = MFMA(a1, t0, accz[1][0]);
    accz[1][1] = MFMA(a1, t1, accz[1][1]);
  }
#pragma unroll
  for (int mi = 0; mi < 2; ++mi) {
    int chb = wr * 32 + mi * 16 + lhi * 4;
    f32x4 bgv = *(const f32x4*)(b_g + chb);
    f32x4 bzv = *(const f32x4*)(b_z + chb);
#pragma unroll
    for (int ni = 0; ni < 2; ++ni) {
      int elem = wc * 32 + ni * 16 + llo;
#pragma unroll
      for (int r = 0; r < 4; ++r)
        Xs[elem * 65 + chb + r] +=
            (accg[mi][ni][r] + bgv[r]) * (accz[mi][ni][r] + bzv[r]);
    }
  }
  __syncthreads();   // (4)
  // pffn LN partials
  {
    float s = 0.f, ss = 0.f;
#pragma unroll
    for (int k = 0; k < 16; ++k) {
      float v = Xs[e * 65 + q * 16 + k];
      vv[k] = v; s += v; ss += v * v;
    }
    spA[q][0][e] = s; spA[q][1][e] = ss;
  }
  __syncthreads();   // (5)
  {
    float ts = spA[0][0][e] + spA[1][0][e] + spA[2][0][e] + spA[3][0][e];
    float tss = spA[0][1][e] + spA[1][1][e] + spA[2][1][e] + spA[3][1][e];
    float mu = ts * 0.015625f, var = tss * 0.015625f - mu * mu;
    float rs = rsqrtf(var + LNEPS);
#pragma unroll
    for (int k = 0; k < 4; ++k) {
      bf4 pk;
#pragma unroll
      for (int u = 0; u < 4; ++u) {
        int c = q * 16 + k * 4 + u;
        pk[u] = f2bf((vv[k * 4 + u] - mu) * rs * g_pf[c] + b_pf[c]);
      }
      *(bf4*)&Zb[e * 72 + q * 16 + k * 4] = pk;
    }
  }
  __syncthreads();   // (6)
  f32x4 acc1[2][2] = {};
#pragma unroll
  for (int ks = 0; ks < 2; ++ks) {
    bf8 a0 = *(const bf8*)&W1b[(wr * 32 + llo) * 72 + ks * 32 + lhi * 8];
    bf8 a1 = *(const bf8*)&W1b[(wr * 32 + 16 + llo) * 72 + ks * 32 + lhi * 8];
    bf8 z0 = *(const bf8*)&Zb[(wc * 32 + llo) * 72 + ks * 32 + lhi * 8];
    bf8 z1 = *(const bf8*)&Zb[(wc * 32 + 16 + llo) * 72 + ks * 32 + lhi * 8];
    acc1[0][0] = MFMA(a0, z0, acc1[0][0]);
    acc1[0][1] = MFMA(a0, z1, acc1[0][1]);
    acc1[1][0] = MFMA(a1, z0, acc1[1][0]);
    acc1[1][1] = MFMA(a1, z1, acc1[1][1]);
  }
  __syncthreads();   // (7)
#pragma unroll
  for (int mi = 0; mi < 2; ++mi) {
    int chb = wr * 32 + mi * 16 + lhi * 4;
    f32x4 bv = *(const f32x4*)(b1 + chb);
#pragma unroll
    for (int ni = 0; ni < 2; ++ni) {
      int elem = wc * 32 + ni * 16 + llo;
      bf4 pack;
#pragma unroll
      for (int r = 0; r < 4; ++r) pack[r] = f2bf(gelu_exact(acc1[mi][ni][r] + bv[r]));
      *(bf4*)&Zb[elem * 72 + chb] = pack;
    }
  }
  __syncthreads();   // (8)
  f32x4 acc2[2][2] = {};
#pragma unroll
  for (int ks = 0; ks < 2; ++ks) {
    bf8 a0 = *(const bf8*)&W2b[(wr * 32 + llo) * 72 + ks * 32 + lhi * 8];
    bf8 a1 = *(const bf8*)&W2b[(wr * 32 + 16 + llo) * 72 + ks * 32 + lhi * 8];
    bf8 z0 = *(const bf8*)&Zb[(wc * 32 + llo) * 72 + ks * 32 + lhi * 8];
    bf8 z1 = *(const bf8*)&Zb[(wc * 32 + 16 + llo) * 72 + ks * 32 + lhi * 8];
    acc2[0][0] = MFMA(a0, z0, acc2[0][0]);
    acc2[0][1] = MFMA(a0, z1, acc2[0][1]);
    acc2[1][0] = MFMA(a1, z0, acc2[1][0]);
    acc2[1][1] = MFMA(a1, z1, acc2[1][1]);
  }
#pragma unroll
  for (int mi = 0; mi < 2; ++mi) {
    int chb = wr * 32 + mi * 16 + lhi * 4;
    f32x4 bv = *(const f32x4*)(b2 + chb);
#pragma unroll
    for (int ni = 0; ni < 2; ++ni) {
      int elem = wc * 32 + ni * 16 + llo;
#pragma unroll
      for (int r = 0; r < 4; ++r)
        Xs[elem * 65 + chb + r] += acc2[mi][ni][r] + bv[r];
    }
  }
  __syncthreads();   // (9)
#pragma unroll
  for (int it2 = 0; it2 < 4; ++it2) {
    int idx = tid + it2 * 256;
    int j = idx >> 4, c4 = (idx & 15) * 4;
    f32x4 o;
#pragma unroll
    for (int u = 0; u < 4; ++u) o[u] = Xs[j * 65 + c4 + u];
    *(f32x4*)(base + (long)j * 64 + c4) = o;
  }
}

extern "C" void kernel_launch(void* const* d_in, const int* in_sizes, int n_in,
                              void* d_out, int out_size, void* d_ws, size_t ws_size,
                              hipStream_t stream) {
  const float* x = (const float*)d_in[0];
  const float* pair = (const float*)d_in[1];
  const float* attn_mask = (const float*)d_in[2];
  const float* op_mask = (const float*)d_in[3];
  const float* op_norm = (const float*)d_in[4];
  const float* wq = (const float*)d_in[6];
  const float* wk = (const float*)d_in[7];
  const float* wv_ = (const float*)d_in[8];
  const float* wg = (const float*)d_in[9];
  const float* bg = (const float*)d_in[10];
  const float* wo = (const float*)d_in[11];
  const float* bo = (const float*)d_in[12];
  const float* ln_pair_g = (const float*)d_in[13];
  const float* ln_pair_b = (const float*)d_in[14];
  const float* wb = (const float*)d_in[15];
  const float* bb = (const float*)d_in[16];
  const float* ln_attn_g = (const float*)d_in[17];
  const float* ln_attn_b = (const float*)d_in[18];
  const float* ln_ffn_g = (const float*)d_in[19];
  const float* ln_ffn_b = (const float*)d_in[20];
  const float* w_ffn1 = (const float*)d_in[21];
  const float* b_ffn1 = (const float*)d_in[22];
  const float* w_ffn2 = (const float*)d_in[23];
  const float* b_ffn2 = (const float*)d_in[24];
  const float* ln_opm_g = (const float*)d_in[25];
  const float* ln_opm_b = (const float*)d_in[26];
  const float* w_opm_in = (const float*)d_in[27];
  const float* b_opm_in = (const float*)d_in[28];
  const float* w_opm_out = (const float*)d_in[29];
  const float* b_opm_out = (const float*)d_in[30];
  const float* ln_tm_g = (const float*)d_in[31];
  const float* ln_tm_b = (const float*)d_in[32];
  const float* w_tm_abp = (const float*)d_in[33];
  const float* b_tm_abp = (const float*)d_in[34];
  const float* w_tm_abg = (const float*)d_in[35];
  const float* b_tm_abg = (const float*)d_in[36];
  const float* w_tm_g = (const float*)d_in[37];
  const float* b_tm_g = (const float*)d_in[38];
  const float* w_tm_z = (const float*)d_in[39];
  const float* b_tm_z = (const float*)d_in[40];
  const float* ln_tmo_g = (const float*)d_in[41];
  const float* ln_tmo_b = (const float*)d_in[42];
  const float* ln_pffn_g = (const float*)d_in[43];
  const float* ln_pffn_b = (const float*)d_in[44];
  const float* w_pffn1 = (const float*)d_in[45];
  const float* b_pffn1 = (const float*)d_in[46];
  const float* w_pffn2 = (const float*)d_in[47];
  const float* b_pffn2 = (const float*)d_in[48];

  float* ws = (float*)d_ws;
  // bf16 weight arena (offsets in bf16 elements)
  short* wbf = (short*)ws;
  short* wq_bf = wbf + 0;            // base of contiguous [3072][768] qkvg block
  short* wk_bf = wbf + 589824;
  short* wv_bf = wbf + 1179648;
  short* wg_bf = wbf + 1769472;
  short* wo_bf = wbf + 2359296;
  short* wf1_bf = wbf + 2949120;
  short* wf2_bf = wbf + 5308416;
  short* wop_bf = wbf + 7667712;
  short* wb_a = wbf + 7716864;
  short* wabp_a = wbf + 7717376;
  short* wabg_a = wbf + 7721472;
  short* wtg_a = wbf + 7725568;
  short* wtz_a = wbf + 7729664;
  short* wp1_a = wbf + 7731712;
  short* wp2_a = wbf + 7735808;
  (void)wk_bf; (void)wv_bf; (void)wg_bf;

  short* h_bf = (short*)(ws + 3869952);
  short* q_bf = (short*)(ws + 4656384);
  short* k_bf = (short*)(ws + 5442816);
  short* vT_bf = (short*)(ws + 6229248);
  float* gb = ws + 7015680;
  short* gb_bf = (short*)(ws + 10161408);
  float* x1b = ws + 10947840;
  short* biasb_bf = (short*)(ws + 12520704);   // 8388608 bf16
  short* attn_bf = (short*)(ws + 16715008);    // 8388608 bf16
  short* mffn_bf = (short*)(ws + 20909312);    // 6291456 bf16
  float* abb = ws + 24055040;                  // 131072 f32
  short* abb_bf = (short*)(ws + 24186112);     // 65536 bf16
  short* Tb_bf = (short*)(ws + 24218880);      // 4194304 bf16
  // triangle-stage overlays (attention/ffn buffers dead by then)
  short* aNb = (short*)(ws + 4656384);         // 8388608 bf16
  short* bNb = (short*)(ws + 8850688);         // 8388608 bf16
  short* t_bf = (short*)(ws + 13044992);       // 8388608 bf16

  float* xo = (float*)d_out;
  float* pair1 = xo + 1572864;

  const float qscale = 0.1020620726159658f;  // 96^-0.5

  // --- weight casts ---
  castw_kernel<<<30144, 256, 0, stream>>>(wq, wk, wv_, wg, wo, w_ffn1, w_ffn2, w_opm_in,
                                          wbf, qscale);
  castw2_kernel<<<90, 256, 0, stream>>>(wb, w_tm_abp, w_tm_abg, w_tm_g, w_tm_z,
                                        w_pffn1, w_pffn2, wb_a);
  // --- attention ---
  ln_bf_kernel<<<2048, 256, 0, stream>>>(x, h_bf, ln_attn_g, ln_attn_b, 768);
  gemm_qkvg<<<dim3(48, 32, 1), 256, 0, stream>>>(h_bf, wq_bf, q_bf, k_bf, vT_bf, gb, bg);
  pair_bias_mfma<<<16384, 256, 0, stream>>>(pair, ln_pair_g, ln_pair_b, wb_a, bb, biasb_bf);
  attn_fused<<<dim3(32, 8, 4), 256, 0, stream>>>(q_bf, k_bf, biasb_bf, attn_mask, attn_bf);
  // AV with fused output gate: gb_bf = sigmoid(gb) * (attn @ V)
  gemm_bf<<<dim3(2, 8, 32), 256, 0, stream>>>(attn_bf, 512, 2097152, 262144,
                                              vT_bf, 512, 393216, 49152,
                                              nullptr, 0, 393216, 96, gb_bf, 768,
                                              gb, 768, 393216, 96, nullptr,
                                              512, 96, 512, 2, 0, 8);
  gemm_bf<<<dim3(12, 32, 1), 256, 0, stream>>>(gb_bf, 768, 0, 0, wo_bf, 768, 0, 0,
                                               x1b, 768, 0, 0, nullptr, 0,
                                               x, 768, 0, 0, bo,
                                               2048, 768, 768, 0, 0, 1);
  // --- FFN ---
  ln_bf_kernel<<<2048, 256, 0, stream>>>(x1b, h_bf, ln_ffn_g, ln_ffn_b, 768);
  gemm_bf<<<dim3(48, 32, 1), 256, 0, stream>>>(h_bf, 768, 0, 0, wf1_bf, 768, 0, 0,
                                               nullptr, 0, 0, 0, mffn_bf, 3072,
                                               nullptr, 0, 0, 0, b_ffn1,
                                               2048, 3072, 768, 1, 0, 1);
  gemm_bf<<<dim3(12, 32, 1), 256, 0, stream>>>(mffn_bf, 3072, 0, 0, wf2_bf, 3072, 0, 0,
                                               xo, 768, 0, 0, nullptr, 0,
                                               x1b, 768, 0, 0, b_ffn2,
                                               2048, 768, 3072, 0, 0, 1);
  // --- outer product mean prep ---
  ln_bf_kernel<<<2048, 256, 0, stream>>>(xo, h_bf, ln_opm_g, ln_opm_b, 768);
  gemm_bf<<<dim3(1, 32, 1), 256, 0, stream>>>(h_bf, 768, 0, 0, wop_bf, 768, 0, 0,
                                              abb, 64, 0, 0, nullptr, 0,
                                              nullptr, 0, 0, 0, b_opm_in,
                                              2048, 64, 768, 0, 0, 1);
  opmask_kernel<<<512, 256, 0, stream>>>(abb, op_mask, abb_bf);
  opm_T_kernel<<<dim3(256, 64, 1), dim3(32, 8, 1), 0, stream>>>(abb, w_opm_out, Tb_bf);
  // --- pair stack per batch ---
  for (int b = 0; b < 4; ++b) {
    const float* pin = pair + (long)b * NNe * 64;
    float* pbb = pair1 + (long)b * NNe * 64;
    opm_ab_fused<<<dim3(8, 512, 1), 256, 0, stream>>>(
        pin, Tb_bf + (long)b * 1048576, abb_bf + (long)b * 16384, b_opm_out, op_norm,
        ln_tm_g, ln_tm_b, wabp_a, b_tm_abp, wabg_a, b_tm_abg, pbb, aNb, bNb);
    tm_tri_mfma<<<dim3(8, 8, 32), 256, 0, stream>>>(aNb, bNb, t_bf);
    upd_pffn_fused<<<4096, 256, 0, stream>>>(
        pbb, t_bf, ln_tm_g, ln_tm_b, wtg_a, b_tm_g, wtz_a, b_tm_z,
        ln_tmo_g, ln_tmo_b, ln_pffn_g, ln_pffn_b, wp1_a, b_pffn1, wp2_a, b_pffn2);
  }
}

// Round 6
// 987.191 us; speedup vs baseline: 6.9470x; 1.1769x over previous
//
#include <hip/hip_runtime.h>
#include <hip/hip_bf16.h>
#include <math.h>

#define Nn 512
#define Ee 768
#define Pp 64
#define PHh 32
#define Hh 8
#define Dd 96
#define NNe 262144      // N*N
#define LNEPS 1e-5f

typedef __attribute__((ext_vector_type(8))) short bf8;
typedef __attribute__((ext_vector_type(4))) short bf4;
typedef __attribute__((ext_vector_type(4))) float f32x4;
#define MFMA(a,b,c) __builtin_amdgcn_mfma_f32_16x16x32_bf16(a,b,c,0,0,0)

__device__ __forceinline__ short f2bf(float f) {
  unsigned u = __builtin_bit_cast(unsigned, f);
  unsigned r = (u + 0x7fffu + ((u >> 16) & 1u)) >> 16;
  return (short)r;
}
__device__ __forceinline__ float bf2f(short s) {
  unsigned u = ((unsigned)(unsigned short)s) << 16;
  return __builtin_bit_cast(float, u);
}

__device__ __forceinline__ float wave_red_sum(float v) {
#pragma unroll
  for (int off = 32; off > 0; off >>= 1) v += __shfl_xor(v, off);
  return v;
}
__device__ __forceinline__ float gelu_exact(float v) {
  return 0.5f * v * (1.f + erff(v * 0.70710678118654752f));
}
__device__ __forceinline__ float sigmoidf_(float v) {
  return 1.f / (1.f + expf(-v));
}

// ---------------- weight casts to bf16 arena ----------------
__global__ __launch_bounds__(256) void castw_kernel(
    const float* __restrict__ wq, const float* __restrict__ wk,
    const float* __restrict__ wv, const float* __restrict__ wg,
    const float* __restrict__ wo, const float* __restrict__ f1,
    const float* __restrict__ f2, const float* __restrict__ wop,
    short* __restrict__ dst, float qs) {
  long i = (long)blockIdx.x * 256 + threadIdx.x;
  float v;
  if (i < 589824) v = wq[i] * qs;
  else if (i < 1179648) v = wk[i - 589824];
  else if (i < 1769472) v = wv[i - 1179648];
  else if (i < 2359296) v = wg[i - 1769472];
  else if (i < 2949120) v = wo[i - 2359296];
  else if (i < 5308416) v = f1[i - 2949120];
  else if (i < 7667712) v = f2[i - 5308416];
  else if (i < 7716864) v = wop[i - 7667712];
  else return;
  dst[i] = f2bf(v);
}

__global__ __launch_bounds__(256) void castw2_kernel(
    const float* __restrict__ wb, const float* __restrict__ abp,
    const float* __restrict__ abg, const float* __restrict__ wtg,
    const float* __restrict__ wtz, const float* __restrict__ p1,
    const float* __restrict__ p2, short* __restrict__ dst) {
  int i = blockIdx.x * 256 + threadIdx.x;
  float v;
  if (i < 512) v = wb[i];
  else if (i < 4608) v = abp[i - 512];
  else if (i < 8704) v = abg[i - 4608];
  else if (i < 12800) v = wtg[i - 8704];
  else if (i < 14848) v = wtz[i - 12800];
  else if (i < 18944) v = p1[i - 14848];
  else if (i < 23040) v = p2[i - 18944];
  else return;
  dst[i] = f2bf(v);
}

// ---------------- LayerNorm over last dim C -> bf16 out ----------------
__global__ __launch_bounds__(256) void ln_bf_kernel(const float* __restrict__ in,
                                                    short* __restrict__ out,
                                                    const float* __restrict__ gam,
                                                    const float* __restrict__ bet, int C) {
  int row = blockIdx.x;
  const float* xr = in + (long)row * C;
  short* yr = out + (long)row * C;
  float s = 0.f, ss = 0.f;
  for (int c = threadIdx.x; c < C; c += 256) { float v = xr[c]; s += v; ss += v * v; }
  s = wave_red_sum(s); ss = wave_red_sum(ss);
  __shared__ float sm[4][2];
  int wv = threadIdx.x >> 6, lane = threadIdx.x & 63;
  if (lane == 0) { sm[wv][0] = s; sm[wv][1] = ss; }
  __syncthreads();
  float ts = sm[0][0] + sm[1][0] + sm[2][0] + sm[3][0];
  float tss = sm[0][1] + sm[1][1] + sm[2][1] + sm[3][1];
  float mu = ts / C;
  float var = tss / C - mu * mu;
  float rs = rsqrtf(var + LNEPS);
  for (int c = threadIdx.x; c < C; c += 256) {
    float v = xr[c];
    yr[c] = f2bf((v - mu) * rs * gam[c] + bet[c]);
  }
}

// ---------------- bf16 MFMA NT GEMM ----------------
// act: 0=none, 1=gelu, 2=out = sigmoid(resid)*acc (gate fusion, no bias)
__global__ __launch_bounds__(256) void gemm_bf(
    const short* __restrict__ A, int lda, long asB, long asH,
    const short* __restrict__ Bm, int ldb, long bsB, long bsH,
    float* __restrict__ outF, int ldf, long fsB, long fsH,
    short* __restrict__ outB, int ldob,
    const float* __restrict__ resid, int ldr, long rsB, long rsH,
    const float* __restrict__ bias,
    int M, int N, int K, int act, int vtrans, int Hdim) {
  int bz = blockIdx.z, bb = bz / Hdim, hh = bz % Hdim;
  A += bb * asB + hh * asH;
  Bm += bb * bsB + hh * bsH;
  if (outF) outF += bb * fsB + hh * fsH;
  if (outB) outB += bb * fsB + hh * fsH;
  if (resid) resid += bb * rsB + hh * rsH;
  __shared__ __align__(16) short As[64 * 40];
  __shared__ __align__(16) short Bs[64 * 40];
  int m0 = blockIdx.y * 64, n0 = blockIdx.x * 64;
  int tid = threadIdx.x;
  int wv = tid >> 6, lane = tid & 63;
  int wr = wv >> 1, wc = wv & 1;
  int lhi = lane >> 4, llo = lane & 15;
  int r4 = tid >> 2, c8 = (tid & 3) * 8;
  f32x4 acc[2][2] = {};
  for (int k0 = 0; k0 < K; k0 += 32) {
    *(bf8*)&As[r4 * 40 + c8] = *(const bf8*)(A + (long)(m0 + r4) * lda + k0 + c8);
    bf8 bv = {};
    if (n0 + r4 < N) bv = *(const bf8*)(Bm + (long)(n0 + r4) * ldb + k0 + c8);
    *(bf8*)&Bs[r4 * 40 + c8] = bv;
    __syncthreads();
    bf8 a0 = *(const bf8*)&As[(wr * 32 + llo) * 40 + lhi * 8];
    bf8 a1 = *(const bf8*)&As[(wr * 32 + 16 + llo) * 40 + lhi * 8];
    bf8 b0 = *(const bf8*)&Bs[(wc * 32 + llo) * 40 + lhi * 8];
    bf8 b1 = *(const bf8*)&Bs[(wc * 32 + 16 + llo) * 40 + lhi * 8];
    acc[0][0] = MFMA(a0, b0, acc[0][0]);
    acc[0][1] = MFMA(a0, b1, acc[0][1]);
    acc[1][0] = MFMA(a1, b0, acc[1][0]);
    acc[1][1] = MFMA(a1, b1, acc[1][1]);
    __syncthreads();
  }
#pragma unroll
  for (int mi = 0; mi < 2; ++mi) {
    int gmb = m0 + wr * 32 + mi * 16 + lhi * 4;
#pragma unroll
    for (int ni = 0; ni < 2; ++ni) {
      int gn = n0 + wc * 32 + ni * 16 + llo;
      if (gn >= N) continue;
      float bv = bias ? bias[gn] : 0.f;
      float vr[4];
#pragma unroll
      for (int r = 0; r < 4; ++r) {
        float v = acc[mi][ni][r] + bv;
        if (resid) {
          float rv = resid[(long)(gmb + r) * ldr + gn];
          if (act == 2) v = sigmoidf_(rv) * acc[mi][ni][r];
          else v += rv;
        }
        if (act == 1) v = gelu_exact(v);
        vr[r] = v;
      }
      if (outF) {
#pragma unroll
        for (int r = 0; r < 4; ++r) outF[(long)(gmb + r) * ldf + gn] = vr[r];
      }
      if (outB) {
        if (vtrans) {
          bf4 pk;
#pragma unroll
          for (int r = 0; r < 4; ++r) pk[r] = f2bf(vr[r]);
          *(bf4*)(outB + ((long)((gmb >> 9) * 768 + gn) * 512 + (gmb & 511))) = pk;
        } else {
#pragma unroll
          for (int r = 0; r < 4; ++r) outB[(long)(gmb + r) * ldob + gn] = f2bf(vr[r]);
        }
      }
    }
  }
}

// ---------------- QKVG combined projection ----------------
__global__ __launch_bounds__(256) void gemm_qkvg(
    const short* __restrict__ A, const short* __restrict__ W,
    short* __restrict__ q_bf, short* __restrict__ k_bf,
    short* __restrict__ vT_bf, float* __restrict__ gb,
    const float* __restrict__ bg) {
  __shared__ __align__(16) short As[64 * 40];
  __shared__ __align__(16) short Bs[64 * 40];
  int m0 = blockIdx.y * 64, n0 = blockIdx.x * 64;
  int sec = n0 / 768;
  int cbase = n0 - sec * 768;
  int tid = threadIdx.x;
  int wv = tid >> 6, lane = tid & 63;
  int wr = wv >> 1, wc = wv & 1;
  int lhi = lane >> 4, llo = lane & 15;
  int r4 = tid >> 2, c8 = (tid & 3) * 8;
  f32x4 acc[2][2] = {};
  for (int k0 = 0; k0 < 768; k0 += 32) {
    *(bf8*)&As[r4 * 40 + c8] = *(const bf8*)(A + (long)(m0 + r4) * 768 + k0 + c8);
    *(bf8*)&Bs[r4 * 40 + c8] = *(const bf8*)(W + (long)(n0 + r4) * 768 + k0 + c8);
    __syncthreads();
    bf8 a0 = *(const bf8*)&As[(wr * 32 + llo) * 40 + lhi * 8];
    bf8 a1 = *(const bf8*)&As[(wr * 32 + 16 + llo) * 40 + lhi * 8];
    bf8 b0 = *(const bf8*)&Bs[(wc * 32 + llo) * 40 + lhi * 8];
    bf8 b1 = *(const bf8*)&Bs[(wc * 32 + 16 + llo) * 40 + lhi * 8];
    acc[0][0] = MFMA(a0, b0, acc[0][0]);
    acc[0][1] = MFMA(a0, b1, acc[0][1]);
    acc[1][0] = MFMA(a1, b0, acc[1][0]);
    acc[1][1] = MFMA(a1, b1, acc[1][1]);
    __syncthreads();
  }
#pragma unroll
  for (int mi = 0; mi < 2; ++mi) {
    int gmb = m0 + wr * 32 + mi * 16 + lhi * 4;
#pragma unroll
    for (int ni = 0; ni < 2; ++ni) {
      int cn = cbase + wc * 32 + ni * 16 + llo;
      if (sec == 0) {
#pragma unroll
        for (int r = 0; r < 4; ++r) q_bf[(long)(gmb + r) * 768 + cn] = f2bf(acc[mi][ni][r]);
      } else if (sec == 1) {
#pragma unroll
        for (int r = 0; r < 4; ++r) k_bf[(long)(gmb + r) * 768 + cn] = f2bf(acc[mi][ni][r]);
      } else if (sec == 2) {
        bf4 pk;
#pragma unroll
        for (int r = 0; r < 4; ++r) pk[r] = f2bf(acc[mi][ni][r]);
        *(bf4*)(vT_bf + ((long)((gmb >> 9) * 768 + cn) * 512 + (gmb & 511))) = pk;
      } else {
        float bv = bg[cn];
#pragma unroll
        for (int r = 0; r < 4; ++r) gb[(long)(gmb + r) * 768 + cn] = acc[mi][ni][r] + bv;
      }
    }
  }
}

// ---------------- fused scores + softmax (flash-row, 16 rows/block) ----------------
__global__ __launch_bounds__(256) void attn_fused(
    const short* __restrict__ q_bf, const short* __restrict__ k_bf,
    const short* __restrict__ bias_bf, const float* __restrict__ mask,
    short* __restrict__ out_bf) {
  int it = blockIdx.x, h = blockIdx.y, b = blockIdx.z;
  int tid = threadIdx.x;
  int wv = tid >> 6, lane = tid & 63;
  int lhi = lane >> 4, llo = lane & 15;
  int i0 = it * 16;
  long qoff = ((long)(b * 512 + i0)) * 768 + h * 96;
  bf8 qf[3];
#pragma unroll
  for (int ks = 0; ks < 3; ++ks)
    qf[ks] = *(const bf8*)(q_bf + qoff + (long)llo * 768 + ks * 32 + lhi * 8);
  long koff = ((long)b * 512) * 768 + h * 96;
  long bioff = (long)(b * 8 + h) * NNe + (long)i0 * 512;
  long moff = (long)b * NNe + (long)i0 * 512;
  float sv[8][4];
  int jb0 = wv * 128;
#pragma unroll
  for (int jf = 0; jf < 8; ++jf) {
    int jb = jb0 + jf * 16;
    f32x4 acc = {0.f, 0.f, 0.f, 0.f};
#pragma unroll
    for (int ks = 0; ks < 3; ++ks) {
      bf8 kf = *(const bf8*)(k_bf + koff + (long)(jb + llo) * 768 + ks * 32 + lhi * 8);
      acc = MFMA(qf[ks], kf, acc);
    }
#pragma unroll
    for (int r = 0; r < 4; ++r) {
      int irow = lhi * 4 + r;
      int j = jb + llo;
      float bia = bf2f(bias_bf[bioff + (long)irow * 512 + j]);
      float mk = mask[moff + (long)irow * 512 + j];
      sv[jf][r] = acc[r] + bia + mk;
    }
  }
  __shared__ float redA[4][20];
  __shared__ float redB[4][20];
  float rmax[4];
#pragma unroll
  for (int r = 0; r < 4; ++r) {
    float m = sv[0][r];
#pragma unroll
    for (int jf = 1; jf < 8; ++jf) m = fmaxf(m, sv[jf][r]);
#pragma unroll
    for (int off = 1; off < 16; off <<= 1) m = fmaxf(m, __shfl_xor(m, off, 16));
    if (llo == 0) redA[wv][lhi * 4 + r] = m;
  }
  __syncthreads();
#pragma unroll
  for (int r = 0; r < 4; ++r) {
    int row = lhi * 4 + r;
    rmax[r] = fmaxf(fmaxf(redA[0][row], redA[1][row]),
                    fmaxf(redA[2][row], redA[3][row]));
  }
  float rsum[4] = {0.f, 0.f, 0.f, 0.f};
#pragma unroll
  for (int jf = 0; jf < 8; ++jf)
#pragma unroll
    for (int r = 0; r < 4; ++r) {
      float e = __expf(sv[jf][r] - rmax[r]);
      sv[jf][r] = e;
      rsum[r] += e;
    }
#pragma unroll
  for (int r = 0; r < 4; ++r) {
#pragma unroll
    for (int off = 1; off < 16; off <<= 1) rsum[r] += __shfl_xor(rsum[r], off, 16);
    if (llo == 0) redB[wv][lhi * 4 + r] = rsum[r];
  }
  __syncthreads();
#pragma unroll
  for (int r = 0; r < 4; ++r) {
    int row = lhi * 4 + r;
    float s = redB[0][row] + redB[1][row] + redB[2][row] + redB[3][row];
    float inv = 1.f / s;
#pragma unroll
    for (int jf = 0; jf < 8; ++jf) {
      int j = jb0 + jf * 16 + llo;
      out_bf[bioff + (long)row * 512 + j] = f2bf(sv[jf][r] * inv);
    }
  }
}

// ---------------- ab *= op_mask ; emit b-half bf16 ----------------
__global__ __launch_bounds__(256) void opmask_kernel(float* __restrict__ ab,
                                                     const float* __restrict__ mask,
                                                     short* __restrict__ bo_bf) {
  int idx = blockIdx.x * 256 + threadIdx.x;
  if (idx < 131072) {
    float v = ab[idx] * mask[idx >> 6];
    ab[idx] = v;
    int ch = idx & 63;
    if (ch >= 32) bo_bf[(idx >> 6) * 32 + ch - 32] = f2bf(v);
  }
}

// ---------------- T[row,p,e] (bf16) = sum_d a_o[row,d] * w[p, d*32+e] ----------------
__global__ __launch_bounds__(256) void opm_T_kernel(const float* __restrict__ ab,
                                                    const float* __restrict__ w,
                                                    short* __restrict__ T) {
  int p = blockIdx.y;
  int row = blockIdx.x * 8 + threadIdx.y;
  int e = threadIdx.x;
  const float* a = ab + (long)row * 64;
  const float* wp = w + p * 1024 + e;
  float acc = 0.f;
#pragma unroll
  for (int d = 0; d < 32; ++d) acc += a[d] * wp[d * 32];
  T[((long)row * 64 + p) * 32 + e] = f2bf(acc);
}

// ---------------- pair bias: register LN ----------------
__global__ __launch_bounds__(256) void pair_bias_mfma(
    const float* __restrict__ pair, const float* __restrict__ gam,
    const float* __restrict__ bet, const short* __restrict__ wb_a,
    const float* __restrict__ bbv, short* __restrict__ bias) {
  __shared__ __align__(16) short Zb[64 * 72];
  __shared__ __align__(16) short Wb[16 * 72];
  __shared__ float sp[4][2][72];
  int tid = threadIdx.x;
  long e0 = (long)blockIdx.x * 64;
  int b = (int)(e0 >> 18);
  long ein = e0 & (NNe - 1);
  const float* base = pair + e0 * 64;
  for (int l = tid; l < 1024; l += 256) {
    int h = l >> 6, c = l & 63;
    Wb[h * 72 + c] = (h < 8) ? wb_a[h * 64 + c] : (short)0;
  }
  int e = tid & 63, q = tid >> 6;
  f32x4 v4[4];
  float s = 0.f, ss = 0.f;
#pragma unroll
  for (int k = 0; k < 4; ++k) {
    v4[k] = *(const f32x4*)(base + (long)e * 64 + q * 16 + k * 4);
#pragma unroll
    for (int u = 0; u < 4; ++u) { float v = v4[k][u]; s += v; ss += v * v; }
  }
  sp[q][0][e] = s; sp[q][1][e] = ss;
  __syncthreads();
  float ts = sp[0][0][e] + sp[1][0][e] + sp[2][0][e] + sp[3][0][e];
  float tss = sp[0][1][e] + sp[1][1][e] + sp[2][1][e] + sp[3][1][e];
  float mu = ts * 0.015625f, var = tss * 0.015625f - mu * mu;
  float rs = rsqrtf(var + LNEPS);
#pragma unroll
  for (int k = 0; k < 4; ++k) {
    bf4 pk;
#pragma unroll
    for (int u = 0; u < 4; ++u) {
      int c = q * 16 + k * 4 + u;
      pk[u] = f2bf((v4[k][u] - mu) * rs * gam[c] + bet[c]);
    }
    *(bf4*)&Zb[e * 72 + q * 16 + k * 4] = pk;
  }
  __syncthreads();
  int wv = tid >> 6, lane = tid & 63;
  int lhi = lane >> 4, llo = lane & 15;
  int n0 = wv * 16;
  f32x4 acc = {0.f, 0.f, 0.f, 0.f};
#pragma unroll
  for (int ks = 0; ks < 2; ++ks) {
    bf8 a = *(const bf8*)&Wb[llo * 72 + ks * 32 + lhi * 8];
    bf8 bz = *(const bf8*)&Zb[(n0 + llo) * 72 + ks * 32 + lhi * 8];
    acc = MFMA(a, bz, acc);
  }
  int elem = n0 + llo;
#pragma unroll
  for (int r = 0; r < 4; ++r) {
    int h = lhi * 4 + r;
    if (h < 8) bias[(long)(b * 8 + h) * NNe + ein + elem] = f2bf(acc[r] + bbv[h]);
  }
}

// ---------------- fused opm update + triangle ab v3 (register X, C-layout) ----------------
__global__ __launch_bounds__(256) void opm_ab_fused(
    const float* __restrict__ pair_in, const short* __restrict__ Tb,
    const short* __restrict__ bo_bf, const float* __restrict__ b_out,
    const float* __restrict__ op_norm, const float* __restrict__ gam,
    const float* __restrict__ bet, const short* __restrict__ wp_a,
    const float* __restrict__ b_abp, const short* __restrict__ wg_a,
    const float* __restrict__ b_abg, float* __restrict__ pair1,
    short* __restrict__ aN, short* __restrict__ bN) {
  int jt = blockIdx.x;   // 0..7
  int i = blockIdx.y;    // 0..511
  int tid = threadIdx.x;
  __shared__ __align__(16) short Tsb[64 * 40];
  __shared__ __align__(16) short Bob[64 * 40];
  __shared__ __align__(16) short Zb[64 * 72];
  __shared__ __align__(16) short Wp[64 * 72];
  __shared__ __align__(16) short Wg[64 * 72];
  __shared__ float spS[64][9];
  __shared__ float spQ[64][9];
  int wv = tid >> 6, lane = tid & 63;
  int wr = wv >> 1, wc = wv & 1;
  int lhi = lane >> 4, llo = lane & 15;
  int chb = wr * 32 + lhi * 4;
  {
    int p = tid >> 2, e8 = (tid & 3) * 8;
    *(bf8*)&Tsb[p * 40 + e8] = *(const bf8*)(Tb + (long)i * 2048 + p * 32 + e8);
    *(bf8*)&Bob[p * 40 + e8] = *(const bf8*)(bo_bf + (long)(jt * 64 + p) * 32 + e8);
  }
  for (int l = tid; l < 512; l += 256) {
    int r = l >> 3, c8 = (l & 7) * 8;
    *(bf8*)&Wp[r * 72 + c8] = *(const bf8*)(wp_a + r * 64 + c8);
    *(bf8*)&Wg[r * 72 + c8] = *(const bf8*)(wg_a + r * 64 + c8);
  }
  long ebase = (long)i * 512 + jt * 64;
  const float* pbase = pair_in + ebase * 64;
  // X in registers, C-layout: elem = wc*32+ni*16+llo, ch = chb+mi*16+{0..3}
  f32x4 x[2][2];
#pragma unroll
  for (int mi = 0; mi < 2; ++mi)
#pragma unroll
    for (int ni = 0; ni < 2; ++ni)
      x[mi][ni] = *(const f32x4*)(pbase + (long)(wc * 32 + ni * 16 + llo) * 64 +
                                  chb + mi * 16);
  __syncthreads();   // (1)
  // opm MFMA: a=Tsb (rows=p), b=Bob (rows=j) -> D[p][j]
  f32x4 acc[2][2] = {};
  {
    bf8 a0 = *(const bf8*)&Tsb[(wr * 32 + llo) * 40 + lhi * 8];
    bf8 a1 = *(const bf8*)&Tsb[(wr * 32 + 16 + llo) * 40 + lhi * 8];
    bf8 b0 = *(const bf8*)&Bob[(wc * 32 + llo) * 40 + lhi * 8];
    bf8 b1 = *(const bf8*)&Bob[(wc * 32 + 16 + llo) * 40 + lhi * 8];
    acc[0][0] = MFMA(a0, b0, acc[0][0]);
    acc[0][1] = MFMA(a0, b1, acc[0][1]);
    acc[1][0] = MFMA(a1, b0, acc[1][0]);
    acc[1][1] = MFMA(a1, b1, acc[1][1]);
  }
  float nrm = op_norm[0];
#pragma unroll
  for (int mi = 0; mi < 2; ++mi) {
    f32x4 bo4 = *(const f32x4*)(b_out + chb + mi * 16);
#pragma unroll
    for (int ni = 0; ni < 2; ++ni)
#pragma unroll
      for (int r = 0; r < 4; ++r)
        x[mi][ni][r] += (acc[mi][ni][r] + bo4[r]) * nrm;
  }
  // pair1 store from registers
#pragma unroll
  for (int mi = 0; mi < 2; ++mi)
#pragma unroll
    for (int ni = 0; ni < 2; ++ni)
      *(f32x4*)(pair1 + (ebase + wc * 32 + ni * 16 + llo) * 64 + chb + mi * 16) =
          x[mi][ni];
  // LN partials (8 slots per element)
#pragma unroll
  for (int ni = 0; ni < 2; ++ni) {
    float s = 0.f, ss = 0.f;
#pragma unroll
    for (int mi = 0; mi < 2; ++mi)
#pragma unroll
      for (int r = 0; r < 4; ++r) { float v = x[mi][ni][r]; s += v; ss += v * v; }
    int e = wc * 32 + ni * 16 + llo;
    spS[e][wr * 4 + lhi] = s;
    spQ[e][wr * 4 + lhi] = ss;
  }
  __syncthreads();   // (2)
  float mu1[2], rs1[2];
#pragma unroll
  for (int ni = 0; ni < 2; ++ni) {
    int e = wc * 32 + ni * 16 + llo;
    float s = 0.f, q2 = 0.f;
#pragma unroll
    for (int k = 0; k < 8; ++k) { s += spS[e][k]; q2 += spQ[e][k]; }
    float mu = s * 0.015625f, var = q2 * 0.015625f - mu * mu;
    mu1[ni] = mu; rs1[ni] = rsqrtf(var + LNEPS);
  }
#pragma unroll
  for (int mi = 0; mi < 2; ++mi) {
    f32x4 gv = *(const f32x4*)(gam + chb + mi * 16);
    f32x4 bv = *(const f32x4*)(bet + chb + mi * 16);
#pragma unroll
    for (int ni = 0; ni < 2; ++ni) {
      int e = wc * 32 + ni * 16 + llo;
      bf4 pk;
#pragma unroll
      for (int r = 0; r < 4; ++r)
        pk[r] = f2bf((x[mi][ni][r] - mu1[ni]) * rs1[ni] * gv[r] + bv[r]);
      *(bf4*)&Zb[e * 72 + chb + mi * 16] = pk;
    }
  }
  __syncthreads();   // (3)
  f32x4 ap[2][2] = {};
  f32x4 ag[2][2] = {};
#pragma unroll
  for (int ks = 0; ks < 2; ++ks) {
    bf8 z0 = *(const bf8*)&Zb[(wr * 32 + llo) * 72 + ks * 32 + lhi * 8];
    bf8 z1 = *(const bf8*)&Zb[(wr * 32 + 16 + llo) * 72 + ks * 32 + lhi * 8];
    bf8 p0 = *(const bf8*)&Wp[(wc * 32 + llo) * 72 + ks * 32 + lhi * 8];
    bf8 p1 = *(const bf8*)&Wp[(wc * 32 + 16 + llo) * 72 + ks * 32 + lhi * 8];
    bf8 g0 = *(const bf8*)&Wg[(wc * 32 + llo) * 72 + ks * 32 + lhi * 8];
    bf8 g1 = *(const bf8*)&Wg[(wc * 32 + 16 + llo) * 72 + ks * 32 + lhi * 8];
    ap[0][0] = MFMA(z0, p0, ap[0][0]);
    ap[0][1] = MFMA(z0, p1, ap[0][1]);
    ap[1][0] = MFMA(z1, p0, ap[1][0]);
    ap[1][1] = MFMA(z1, p1, ap[1][1]);
    ag[0][0] = MFMA(z0, g0, ag[0][0]);
    ag[0][1] = MFMA(z0, g1, ag[0][1]);
    ag[1][0] = MFMA(z1, g0, ag[1][0]);
    ag[1][1] = MFMA(z1, g1, ag[1][1]);
  }
#pragma unroll
  for (int mi = 0; mi < 2; ++mi) {
    int elemb = wr * 32 + mi * 16 + lhi * 4;
#pragma unroll
    for (int ni = 0; ni < 2; ++ni) {
      int ch = wc * 32 + ni * 16 + llo;
      float bp = b_abp[ch], bg = b_abg[ch];
      bf4 pack;
#pragma unroll
      for (int r = 0; r < 4; ++r)
        pack[r] = f2bf((ap[mi][ni][r] + bp) * sigmoidf_(ag[mi][ni][r] + bg));
      short* dst = (ch < 32) ? (aN + (long)ch * NNe) : (bN + (long)(ch - 32) * NNe);
      *(bf4*)(dst + ebase + elemb) = pack;
    }
  }
}

// ---------------- triangle einsum -> t bf16 (paired-row transpose staging) ----------------
__global__ __launch_bounds__(256) void tm_tri_mfma(const short* __restrict__ aN,
                                                   const short* __restrict__ bN,
                                                   short* __restrict__ t_out) {
  int h = blockIdx.z;
  int i0 = blockIdx.y * 64, k0 = blockIdx.x * 64;
  const short* A = aN + (long)h * NNe;
  const short* B = bN + (long)h * NNe;
  __shared__ __align__(16) short A1[64 * 40];
  __shared__ __align__(16) short B1[64 * 40];
  __shared__ __align__(16) short A2[64 * 40];
  __shared__ __align__(16) short B2[64 * 40];
  int tid = threadIdx.x;
  int wv = tid >> 6, lane = tid & 63;
  int wr = wv >> 1, wc = wv & 1;
  int lhi = lane >> 4, llo = lane & 15;
  int r1 = tid >> 2, cp = (tid & 3) * 8;
  int s2 = tid >> 4;           // row pair 2*s2, 2*s2+1 (0..15 -> rows 0..31)
  int cg = (tid & 15) * 4;     // 4 columns
  f32x4 acc[2][2] = {};
  for (int j0 = 0; j0 < 512; j0 += 32) {
    *(bf8*)&A1[r1 * 40 + cp] = *(const bf8*)(A + (long)(i0 + r1) * 512 + j0 + cp);
    *(bf8*)&B1[r1 * 40 + cp] = *(const bf8*)(B + (long)(k0 + r1) * 512 + j0 + cp);
    bf4 va0 = *(const bf4*)(A + (long)(j0 + 2 * s2) * 512 + i0 + cg);
    bf4 va1 = *(const bf4*)(A + (long)(j0 + 2 * s2 + 1) * 512 + i0 + cg);
    bf4 vb0 = *(const bf4*)(B + (long)(j0 + 2 * s2) * 512 + k0 + cg);
    bf4 vb1 = *(const bf4*)(B + (long)(j0 + 2 * s2 + 1) * 512 + k0 + cg);
#pragma unroll
    for (int q = 0; q < 4; ++q) {
      unsigned pa = (unsigned)(unsigned short)va0[q] |
                    ((unsigned)(unsigned short)va1[q] << 16);
      unsigned pb = (unsigned)(unsigned short)vb0[q] |
                    ((unsigned)(unsigned short)vb1[q] << 16);
      *(unsigned*)&A2[(cg + q) * 40 + 2 * s2] = pa;
      *(unsigned*)&B2[(cg + q) * 40 + 2 * s2] = pb;
    }
    __syncthreads();
    bf8 a0 = *(const bf8*)&A1[(wr * 32 + llo) * 40 + lhi * 8];
    bf8 a1 = *(const bf8*)&A1[(wr * 32 + 16 + llo) * 40 + lhi * 8];
    bf8 b0 = *(const bf8*)&B1[(wc * 32 + llo) * 40 + lhi * 8];
    bf8 b1 = *(const bf8*)&B1[(wc * 32 + 16 + llo) * 40 + lhi * 8];
    acc[0][0] = MFMA(a0, b0, acc[0][0]);
    acc[0][1] = MFMA(a0, b1, acc[0][1]);
    acc[1][0] = MFMA(a1, b0, acc[1][0]);
    acc[1][1] = MFMA(a1, b1, acc[1][1]);
    bf8 c0 = *(const bf8*)&A2[(wr * 32 + llo) * 40 + lhi * 8];
    bf8 c1 = *(const bf8*)&A2[(wr * 32 + 16 + llo) * 40 + lhi * 8];
    bf8 d0 = *(const bf8*)&B2[(wc * 32 + llo) * 40 + lhi * 8];
    bf8 d1 = *(const bf8*)&B2[(wc * 32 + 16 + llo) * 40 + lhi * 8];
    acc[0][0] = MFMA(c0, d0, acc[0][0]);
    acc[0][1] = MFMA(c0, d1, acc[0][1]);
    acc[1][0] = MFMA(c1, d0, acc[1][0]);
    acc[1][1] = MFMA(c1, d1, acc[1][1]);
    __syncthreads();
  }
  short* tp = t_out + (long)h * NNe;
#pragma unroll
  for (int mi = 0; mi < 2; ++mi)
#pragma unroll
    for (int ni = 0; ni < 2; ++ni) {
      int row = i0 + wr * 32 + mi * 16 + lhi * 4;
      int col = k0 + wc * 32 + ni * 16 + llo;
#pragma unroll
      for (int r = 0; r < 4; ++r) tp[(long)(row + r) * 512 + col] = f2bf(acc[mi][ni][r]);
    }
}

// ---------------- fused triangle update + pair FFN v3 (register X, shared Wbuf) ----------------
__global__ __launch_bounds__(256) void upd_pffn_fused(
    float* __restrict__ pb, const short* __restrict__ t_in,
    const float* __restrict__ g_tm, const float* __restrict__ b_tm,
    const short* __restrict__ wg_a, const float* __restrict__ b_g,
    const short* __restrict__ wz_a, const float* __restrict__ b_z,
    const float* __restrict__ g_tmo, const float* __restrict__ b_tmo,
    const float* __restrict__ g_pf, const float* __restrict__ b_pf,
    const short* __restrict__ w1_a, const float* __restrict__ b1,
    const short* __restrict__ w2_a, const float* __restrict__ b2) {
  __shared__ __align__(16) short Zb[64 * 72];
  __shared__ __align__(16) short Tlb[64 * 40];
  __shared__ __align__(16) short Wbuf[64 * 72];
  __shared__ __align__(16) short Wzb[64 * 40];
  __shared__ float spS[64][9];
  __shared__ float spQ[64][9];
  __shared__ float spB[4][2][72];
  int tid = threadIdx.x;
  long e0 = (long)blockIdx.x * 64;
  float* base = pb + e0 * 64;
  int wv = tid >> 6, lane = tid & 63;
  int wr = wv >> 1, wc = wv & 1;
  int lhi = lane >> 4, llo = lane & 15;
  int chb = wr * 32 + lhi * 4;
  int r0 = tid >> 3, c0 = (tid & 7) * 8;
  int r1 = (tid + 256) >> 3, c1 = ((tid + 256) & 7) * 8;
  bf8 w1r0, w1r1, w2r0, w2r1;
  {
    *(bf8*)&Wbuf[r0 * 72 + c0] = *(const bf8*)(wg_a + r0 * 64 + c0);
    *(bf8*)&Wbuf[r1 * 72 + c1] = *(const bf8*)(wg_a + r1 * 64 + c1);
    w1r0 = *(const bf8*)(w1_a + r0 * 64 + c0);
    w1r1 = *(const bf8*)(w1_a + r1 * 64 + c1);
    w2r0 = *(const bf8*)(w2_a + r0 * 64 + c0);
    w2r1 = *(const bf8*)(w2_a + r1 * 64 + c1);
    int rz = tid >> 2, cz = (tid & 3) * 8;
    *(bf8*)&Wzb[rz * 40 + cz] = *(const bf8*)(wz_a + rz * 32 + cz);
  }
  // X registers (C-layout)
  f32x4 x[2][2];
#pragma unroll
  for (int mi = 0; mi < 2; ++mi)
#pragma unroll
    for (int ni = 0; ni < 2; ++ni)
      x[mi][ni] = *(const f32x4*)(base + (long)(wc * 32 + ni * 16 + llo) * 64 +
                                  chb + mi * 16);
  // LN1 partials
#pragma unroll
  for (int ni = 0; ni < 2; ++ni) {
    float s = 0.f, ss = 0.f;
#pragma unroll
    for (int mi = 0; mi < 2; ++mi)
#pragma unroll
      for (int r = 0; r < 4; ++r) { float v = x[mi][ni][r]; s += v; ss += v * v; }
    int e = wc * 32 + ni * 16 + llo;
    spS[e][wr * 4 + lhi] = s;
    spQ[e][wr * 4 + lhi] = ss;
  }
  // t path (independent ownership)
  int te = tid & 63, tq = tid >> 6;
  float tt[8];
  {
    float sB = 0.f, ssB = 0.f;
#pragma unroll
    for (int k = 0; k < 8; ++k) {
      float v = bf2f(t_in[(long)(tq * 8 + k) * NNe + e0 + te]);
      tt[k] = v; sB += v; ssB += v * v;
    }
    spB[tq][0][te] = sB; spB[tq][1][te] = ssB;
  }
  __syncthreads();   // (1)
  // Tlb
  {
    float ts = spB[0][0][te] + spB[1][0][te] + spB[2][0][te] + spB[3][0][te];
    float tss = spB[0][1][te] + spB[1][1][te] + spB[2][1][te] + spB[3][1][te];
    float mu = ts * 0.03125f, var = tss * 0.03125f - mu * mu;
    float rs = rsqrtf(var + LNEPS);
    bf8 pk;
#pragma unroll
    for (int k = 0; k < 8; ++k) {
      int c = tq * 8 + k;
      pk[k] = f2bf((tt[k] - mu) * rs * g_tmo[c] + b_tmo[c]);
    }
    *(bf8*)&Tlb[te * 40 + tq * 8] = pk;
  }
  // LN1 combine + Zb from registers
  float mu1[2], rs1[2];
#pragma unroll
  for (int ni = 0; ni < 2; ++ni) {
    int e = wc * 32 + ni * 16 + llo;
    float s = 0.f, q2 = 0.f;
#pragma unroll
    for (int k = 0; k < 8; ++k) { s += spS[e][k]; q2 += spQ[e][k]; }
    float mu = s * 0.015625f, var = q2 * 0.015625f - mu * mu;
    mu1[ni] = mu; rs1[ni] = rsqrtf(var + LNEPS);
  }
#pragma unroll
  for (int mi = 0; mi < 2; ++mi) {
    f32x4 gv = *(const f32x4*)(g_tm + chb + mi * 16);
    f32x4 bv = *(const f32x4*)(b_tm + chb + mi * 16);
#pragma unroll
    for (int ni = 0; ni < 2; ++ni) {
      int e = wc * 32 + ni * 16 + llo;
      bf4 pk;
#pragma unroll
      for (int r = 0; r < 4; ++r)
        pk[r] = f2bf((x[mi][ni][r] - mu1[ni]) * rs1[ni] * gv[r] + bv[r]);
      *(bf4*)&Zb[e * 72 + chb + mi * 16] = pk;
    }
  }
  __syncthreads();   // (2)
  // MFMA gate + z
  f32x4 accg[2][2] = {};
  f32x4 accz[2][2] = {};
#pragma unroll
  for (int ks = 0; ks < 2; ++ks) {
    bf8 a0 = *(const bf8*)&Wbuf[(wr * 32 + llo) * 72 + ks * 32 + lhi * 8];
    bf8 a1 = *(const bf8*)&Wbuf[(wr * 32 + 16 + llo) * 72 + ks * 32 + lhi * 8];
    bf8 z0 = *(const bf8*)&Zb[(wc * 32 + llo) * 72 + ks * 32 + lhi * 8];
    bf8 z1 = *(const bf8*)&Zb[(wc * 32 + 16 + llo) * 72 + ks * 32 + lhi * 8];
    accg[0][0] = MFMA(a0, z0, accg[0][0]);
    accg[0][1] = MFMA(a0, z1, accg[0][1]);
    accg[1][0] = MFMA(a1, z0, accg[1][0]);
    accg[1][1] = MFMA(a1, z1, accg[1][1]);
  }
  {
    bf8 a0 = *(const bf8*)&Wzb[(wr * 32 + llo) * 40 + lhi * 8];
    bf8 a1 = *(const bf8*)&Wzb[(wr * 32 + 16 + llo) * 40 + lhi * 8];
    bf8 t0 = *(const bf8*)&Tlb[(wc * 32 + llo) * 40 + lhi * 8];
    bf8 t1 = *(const bf8*)&Tlb[(wc * 32 + 16 + llo) * 40 + lhi * 8];
    accz[0][0] = MFMA(a0, t0, accz[0][0]);
    accz[0][1] = MFMA(a0, t1, accz[0][1]);
    accz[1][0] = MFMA(a1, t0, accz[1][0]);
    accz[1][1] = MFMA(a1, t1, accz[1][1]);
  }
  // X += gate*z  (registers)
#pragma unroll
  for (int mi = 0; mi < 2; ++mi) {
    f32x4 bgv = *(const f32x4*)(b_g + chb + mi * 16);
    f32x4 bzv = *(const f32x4*)(b_z + chb + mi * 16);
#pragma unroll
    for (int ni = 0; ni < 2; ++ni)
#pragma unroll
      for (int r = 0; r < 4; ++r)
        x[mi][ni][r] += (accg[mi][ni][r] + bgv[r]) * (accz[mi][ni][r] + bzv[r]);
  }
  // LN2 partials (spS last read before barrier (2))
#pragma unroll
  for (int ni = 0; ni < 2; ++ni) {
    float s = 0.f, ss = 0.f;
#pragma unroll
    for (int mi = 0; mi < 2; ++mi)
#pragma unroll
      for (int r = 0; r < 4; ++r) { float v = x[mi][ni][r]; s += v; ss += v * v; }
    int e = wc * 32 + ni * 16 + llo;
    spS[e][wr * 4 + lhi] = s;
    spQ[e][wr * 4 + lhi] = ss;
  }
  __syncthreads();   // (3) — Wbuf/Zb reads done; spS2 complete
  // stage W1; write Zb2 (pffn LN)
  *(bf8*)&Wbuf[r0 * 72 + c0] = w1r0;
  *(bf8*)&Wbuf[r1 * 72 + c1] = w1r1;
#pragma unroll
  for (int ni = 0; ni < 2; ++ni) {
    int e = wc * 32 + ni * 16 + llo;
    float s = 0.f, q2 = 0.f;
#pragma unroll
    for (int k = 0; k < 8; ++k) { s += spS[e][k]; q2 += spQ[e][k]; }
    float mu = s * 0.015625f, var = q2 * 0.015625f - mu * mu;
    mu1[ni] = mu; rs1[ni] = rsqrtf(var + LNEPS);
  }
#pragma unroll
  for (int mi = 0; mi < 2; ++mi) {
    f32x4 gv = *(const f32x4*)(g_pf + chb + mi * 16);
    f32x4 bv = *(const f32x4*)(b_pf + chb + mi * 16);
#pragma unroll
    for (int ni = 0; ni < 2; ++ni) {
      int e = wc * 32 + ni * 16 + llo;
      bf4 pk;
#pragma unroll
      for (int r = 0; r < 4; ++r)
        pk[r] = f2bf((x[mi][ni][r] - mu1[ni]) * rs1[ni] * gv[r] + bv[r]);
      *(bf4*)&Zb[e * 72 + chb + mi * 16] = pk;
    }
  }
  __syncthreads();   // (4)
  f32x4 acc1[2][2] = {};
#pragma unroll
  for (int ks = 0; ks < 2; ++ks) {
    bf8 a0 = *(const bf8*)&Wbuf[(wr * 32 + llo) * 72 + ks * 32 + lhi * 8];
    bf8 a1 = *(const bf8*)&Wbuf[(wr * 32 + 16 + llo) * 72 + ks * 32 + lhi * 8];
    bf8 z0 = *(const bf8*)&Zb[(wc * 32 + llo) * 72 + ks * 32 + lhi * 8];
    bf8 z1 = *(const bf8*)&Zb[(wc * 32 + 16 + llo) * 72 + ks * 32 + lhi * 8];
    acc1[0][0] = MFMA(a0, z0, acc1[0][0]);
    acc1[0][1] = MFMA(a0, z1, acc1[0][1]);
    acc1[1][0] = MFMA(a1, z0, acc1[1][0]);
    acc1[1][1] = MFMA(a1, z1, acc1[1][1]);
  }
  __syncthreads();   // (5)
  // gelu -> Zb3 ; stage W2
  *(bf8*)&Wbuf[r0 * 72 + c0] = w2r0;
  *(bf8*)&Wbuf[r1 * 72 + c1] = w2r1;
#pragma unroll
  for (int mi = 0; mi < 2; ++mi) {
    f32x4 bv = *(const f32x4*)(b1 + chb + mi * 16);
#pragma unroll
    for (int ni = 0; ni < 2; ++ni) {
      int e = wc * 32 + ni * 16 + llo;
      bf4 pk;
#pragma unroll
      for (int r = 0; r < 4; ++r) pk[r] = f2bf(gelu_exact(acc1[mi][ni][r] + bv[r]));
      *(bf4*)&Zb[e * 72 + chb + mi * 16] = pk;
    }
  }
  __syncthreads();   // (6)
  f32x4 acc2[2][2] = {};
#pragma unroll
  for (int ks = 0; ks < 2; ++ks) {
    bf8 a0 = *(const bf8*)&Wbuf[(wr * 32 + llo) * 72 + ks * 32 + lhi * 8];
    bf8 a1 = *(const bf8*)&Wbuf[(wr * 32 + 16 + llo) * 72 + ks * 32 + lhi * 8];
    bf8 z0 = *(const bf8*)&Zb[(wc * 32 + llo) * 72 + ks * 32 + lhi * 8];
    bf8 z1 = *(const bf8*)&Zb[(wc * 32 + 16 + llo) * 72 + ks * 32 + lhi * 8];
    acc2[0][0] = MFMA(a0, z0, acc2[0][0]);
    acc2[0][1] = MFMA(a0, z1, acc2[0][1]);
    acc2[1][0] = MFMA(a1, z0, acc2[1][0]);
    acc2[1][1] = MFMA(a1, z1, acc2[1][1]);
  }
#pragma unroll
  for (int mi = 0; mi < 2; ++mi) {
    f32x4 bv = *(const f32x4*)(b2 + chb + mi * 16);
#pragma unroll
    for (int ni = 0; ni < 2; ++ni) {
#pragma unroll
      for (int r = 0; r < 4; ++r) x[mi][ni][r] += acc2[mi][ni][r] + bv[r];
      *(f32x4*)(base + (long)(wc * 32 + ni * 16 + llo) * 64 + chb + mi * 16) =
          x[mi][ni];
    }
  }
}

extern "C" void kernel_launch(void* const* d_in, const int* in_sizes, int n_in,
                              void* d_out, int out_size, void* d_ws, size_t ws_size,
                              hipStream_t stream) {
  const float* x = (const float*)d_in[0];
  const float* pair = (const float*)d_in[1];
  const float* attn_mask = (const float*)d_in[2];
  const float* op_mask = (const float*)d_in[3];
  const float* op_norm = (const float*)d_in[4];
  const float* wq = (const float*)d_in[6];
  const float* wk = (const float*)d_in[7];
  const float* wv_ = (const float*)d_in[8];
  const float* wg = (const float*)d_in[9];
  const float* bg = (const float*)d_in[10];
  const float* wo = (const float*)d_in[11];
  const float* bo = (const float*)d_in[12];
  const float* ln_pair_g = (const float*)d_in[13];
  const float* ln_pair_b = (const float*)d_in[14];
  const float* wb = (const float*)d_in[15];
  const float* bb = (const float*)d_in[16];
  const float* ln_attn_g = (const float*)d_in[17];
  const float* ln_attn_b = (const float*)d_in[18];
  const float* ln_ffn_g = (const float*)d_in[19];
  const float* ln_ffn_b = (const float*)d_in[20];
  const float* w_ffn1 = (const float*)d_in[21];
  const float* b_ffn1 = (const float*)d_in[22];
  const float* w_ffn2 = (const float*)d_in[23];
  const float* b_ffn2 = (const float*)d_in[24];
  const float* ln_opm_g = (const float*)d_in[25];
  const float* ln_opm_b = (const float*)d_in[26];
  const float* w_opm_in = (const float*)d_in[27];
  const float* b_opm_in = (const float*)d_in[28];
  const float* w_opm_out = (const float*)d_in[29];
  const float* b_opm_out = (const float*)d_in[30];
  const float* ln_tm_g = (const float*)d_in[31];
  const float* ln_tm_b = (const float*)d_in[32];
  const float* w_tm_abp = (const float*)d_in[33];
  const float* b_tm_abp = (const float*)d_in[34];
  const float* w_tm_abg = (const float*)d_in[35];
  const float* b_tm_abg = (const float*)d_in[36];
  const float* w_tm_g = (const float*)d_in[37];
  const float* b_tm_g = (const float*)d_in[38];
  const float* w_tm_z = (const float*)d_in[39];
  const float* b_tm_z = (const float*)d_in[40];
  const float* ln_tmo_g = (const float*)d_in[41];
  const float* ln_tmo_b = (const float*)d_in[42];
  const float* ln_pffn_g = (const float*)d_in[43];
  const float* ln_pffn_b = (const float*)d_in[44];
  const float* w_pffn1 = (const float*)d_in[45];
  const float* b_pffn1 = (const float*)d_in[46];
  const float* w_pffn2 = (const float*)d_in[47];
  const float* b_pffn2 = (const float*)d_in[48];

  float* ws = (float*)d_ws;
  // bf16 weight arena (offsets in bf16 elements)
  short* wbf = (short*)ws;
  short* wq_bf = wbf + 0;            // base of contiguous [3072][768] qkvg block
  short* wo_bf = wbf + 2359296;
  short* wf1_bf = wbf + 2949120;
  short* wf2_bf = wbf + 5308416;
  short* wop_bf = wbf + 7667712;
  short* wb_a = wbf + 7716864;
  short* wabp_a = wbf + 7717376;
  short* wabg_a = wbf + 7721472;
  short* wtg_a = wbf + 7725568;
  short* wtz_a = wbf + 7729664;
  short* wp1_a = wbf + 7731712;
  short* wp2_a = wbf + 7735808;

  short* h_bf = (short*)(ws + 3869952);
  short* q_bf = (short*)(ws + 4656384);
  short* k_bf = (short*)(ws + 5442816);
  short* vT_bf = (short*)(ws + 6229248);
  float* gb = ws + 7015680;
  short* gb_bf = (short*)(ws + 10161408);
  float* x1b = ws + 10947840;
  short* biasb_bf = (short*)(ws + 12520704);   // 8388608 bf16
  short* attn_bf = (short*)(ws + 16715008);    // 8388608 bf16
  short* mffn_bf = (short*)(ws + 20909312);    // 6291456 bf16
  float* abb = ws + 24055040;                  // 131072 f32
  short* abb_bf = (short*)(ws + 24186112);     // 65536 bf16
  short* Tb_bf = (short*)(ws + 24218880);      // 4194304 bf16
  // triangle-stage overlays (attention/ffn buffers dead by then)
  short* aNb = (short*)(ws + 4656384);         // 8388608 bf16
  short* bNb = (short*)(ws + 8850688);         // 8388608 bf16
  short* t_bf = (short*)(ws + 13044992);       // 8388608 bf16

  float* xo = (float*)d_out;
  float* pair1 = xo + 1572864;

  const float qscale = 0.1020620726159658f;  // 96^-0.5

  // --- weight casts ---
  castw_kernel<<<30144, 256, 0, stream>>>(wq, wk, wv_, wg, wo, w_ffn1, w_ffn2, w_opm_in,
                                          wbf, qscale);
  castw2_kernel<<<90, 256, 0, stream>>>(wb, w_tm_abp, w_tm_abg, w_tm_g, w_tm_z,
                                        w_pffn1, w_pffn2, wb_a);
  // --- attention ---
  ln_bf_kernel<<<2048, 256, 0, stream>>>(x, h_bf, ln_attn_g, ln_attn_b, 768);
  gemm_qkvg<<<dim3(48, 32, 1), 256, 0, stream>>>(h_bf, wq_bf, q_bf, k_bf, vT_bf, gb, bg);
  pair_bias_mfma<<<16384, 256, 0, stream>>>(pair, ln_pair_g, ln_pair_b, wb_a, bb, biasb_bf);
  attn_fused<<<dim3(32, 8, 4), 256, 0, stream>>>(q_bf, k_bf, biasb_bf, attn_mask, attn_bf);
  // AV with fused output gate: gb_bf = sigmoid(gb) * (attn @ V)
  gemm_bf<<<dim3(2, 8, 32), 256, 0, stream>>>(attn_bf, 512, 2097152, 262144,
                                              vT_bf, 512, 393216, 49152,
                                              nullptr, 0, 393216, 96, gb_bf, 768,
                                              gb, 768, 393216, 96, nullptr,
                                              512, 96, 512, 2, 0, 8);
  gemm_bf<<<dim3(12, 32, 1), 256, 0, stream>>>(gb_bf, 768, 0, 0, wo_bf, 768, 0, 0,
                                               x1b, 768, 0, 0, nullptr, 0,
                                               x, 768, 0, 0, bo,
                                               2048, 768, 768, 0, 0, 1);
  // --- FFN ---
  ln_bf_kernel<<<2048, 256, 0, stream>>>(x1b, h_bf, ln_ffn_g, ln_ffn_b, 768);
  gemm_bf<<<dim3(48, 32, 1), 256, 0, stream>>>(h_bf, 768, 0, 0, wf1_bf, 768, 0, 0,
                                               nullptr, 0, 0, 0, mffn_bf, 3072,
                                               nullptr, 0, 0, 0, b_ffn1,
                                               2048, 3072, 768, 1, 0, 1);
  gemm_bf<<<dim3(12, 32, 1), 256, 0, stream>>>(mffn_bf, 3072, 0, 0, wf2_bf, 3072, 0, 0,
                                               xo, 768, 0, 0, nullptr, 0,
                                               x1b, 768, 0, 0, b_ffn2,
                                               2048, 768, 3072, 0, 0, 1);
  // --- outer product mean prep ---
  ln_bf_kernel<<<2048, 256, 0, stream>>>(xo, h_bf, ln_opm_g, ln_opm_b, 768);
  gemm_bf<<<dim3(1, 32, 1), 256, 0, stream>>>(h_bf, 768, 0, 0, wop_bf, 768, 0, 0,
                                              abb, 64, 0, 0, nullptr, 0,
                                              nullptr, 0, 0, 0, b_opm_in,
                                              2048, 64, 768, 0, 0, 1);
  opmask_kernel<<<512, 256, 0, stream>>>(abb, op_mask, abb_bf);
  opm_T_kernel<<<dim3(256, 64, 1), dim3(32, 8, 1), 0, stream>>>(abb, w_opm_out, Tb_bf);
  // --- pair stack per batch ---
  for (int b = 0; b < 4; ++b) {
    const float* pin = pair + (long)b * NNe * 64;
    float* pbb = pair1 + (long)b * NNe * 64;
    opm_ab_fused<<<dim3(8, 512, 1), 256, 0, stream>>>(
        pin, Tb_bf + (long)b * 1048576, abb_bf + (long)b * 16384, b_opm_out, op_norm,
        ln_tm_g, ln_tm_b, wabp_a, b_tm_abp, wabg_a, b_tm_abg, pbb, aNb, bNb);
    tm_tri_mfma<<<dim3(8, 8, 32), 256, 0, stream>>>(aNb, bNb, t_bf);
    upd_pffn_fused<<<4096, 256, 0, stream>>>(
        pbb, t_bf, ln_tm_g, ln_tm_b, wtg_a, b_tm_g, wtz_a, b_tm_z,
        ln_tmo_g, ln_tmo_b, ln_pffn_g, ln_pffn_b, wp1_a, b_pffn1, wp2_a, b_pffn2);
  }
}

// Round 7
// 949.764 us; speedup vs baseline: 7.2208x; 1.0394x over previous
//
#include <hip/hip_runtime.h>
#include <hip/hip_bf16.h>
#include <math.h>

#define Nn 512
#define Ee 768
#define Pp 64
#define PHh 32
#define Hh 8
#define Dd 96
#define NNe 262144      // N*N
#define LNEPS 1e-5f

typedef __attribute__((ext_vector_type(8))) short bf8;
typedef __attribute__((ext_vector_type(4))) short bf4;
typedef __attribute__((ext_vector_type(4))) float f32x4;
#define MFMA(a,b,c) __builtin_amdgcn_mfma_f32_16x16x32_bf16(a,b,c,0,0,0)

__device__ __forceinline__ short f2bf(float f) {
  unsigned u = __builtin_bit_cast(unsigned, f);
  unsigned r = (u + 0x7fffu + ((u >> 16) & 1u)) >> 16;
  return (short)r;
}
__device__ __forceinline__ float bf2f(short s) {
  unsigned u = ((unsigned)(unsigned short)s) << 16;
  return __builtin_bit_cast(float, u);
}

__device__ __forceinline__ float wave_red_sum(float v) {
#pragma unroll
  for (int off = 32; off > 0; off >>= 1) v += __shfl_xor(v, off);
  return v;
}
__device__ __forceinline__ float gelu_exact(float v) {
  return 0.5f * v * (1.f + erff(v * 0.70710678118654752f));
}
__device__ __forceinline__ float sigmoidf_(float v) {
  return 1.f / (1.f + expf(-v));
}

// ---------------- weight casts to bf16 arena ----------------
__global__ __launch_bounds__(256) void castw_kernel(
    const float* __restrict__ wq, const float* __restrict__ wk,
    const float* __restrict__ wv, const float* __restrict__ wg,
    const float* __restrict__ wo, const float* __restrict__ f1,
    const float* __restrict__ f2, const float* __restrict__ wop,
    short* __restrict__ dst, float qs) {
  long i = (long)blockIdx.x * 256 + threadIdx.x;
  float v;
  if (i < 589824) v = wq[i] * qs;
  else if (i < 1179648) v = wk[i - 589824];
  else if (i < 1769472) v = wv[i - 1179648];
  else if (i < 2359296) v = wg[i - 1769472];
  else if (i < 2949120) v = wo[i - 2359296];
  else if (i < 5308416) v = f1[i - 2949120];
  else if (i < 7667712) v = f2[i - 5308416];
  else if (i < 7716864) v = wop[i - 7667712];
  else return;
  dst[i] = f2bf(v);
}

__global__ __launch_bounds__(256) void castw2_kernel(
    const float* __restrict__ wb, const float* __restrict__ abp,
    const float* __restrict__ abg, const float* __restrict__ wtg,
    const float* __restrict__ wtz, const float* __restrict__ p1,
    const float* __restrict__ p2, short* __restrict__ dst) {
  int i = blockIdx.x * 256 + threadIdx.x;
  float v;
  if (i < 512) v = wb[i];
  else if (i < 4608) v = abp[i - 512];
  else if (i < 8704) v = abg[i - 4608];
  else if (i < 12800) v = wtg[i - 8704];
  else if (i < 14848) v = wtz[i - 12800];
  else if (i < 18944) v = p1[i - 14848];
  else if (i < 23040) v = p2[i - 18944];
  else return;
  dst[i] = f2bf(v);
}

// ---------------- LayerNorm over last dim C -> bf16 out ----------------
__global__ __launch_bounds__(256) void ln_bf_kernel(const float* __restrict__ in,
                                                    short* __restrict__ out,
                                                    const float* __restrict__ gam,
                                                    const float* __restrict__ bet, int C) {
  int row = blockIdx.x;
  const float* xr = in + (long)row * C;
  short* yr = out + (long)row * C;
  float s = 0.f, ss = 0.f;
  for (int c = threadIdx.x; c < C; c += 256) { float v = xr[c]; s += v; ss += v * v; }
  s = wave_red_sum(s); ss = wave_red_sum(ss);
  __shared__ float sm[4][2];
  int wv = threadIdx.x >> 6, lane = threadIdx.x & 63;
  if (lane == 0) { sm[wv][0] = s; sm[wv][1] = ss; }
  __syncthreads();
  float ts = sm[0][0] + sm[1][0] + sm[2][0] + sm[3][0];
  float tss = sm[0][1] + sm[1][1] + sm[2][1] + sm[3][1];
  float mu = ts / C;
  float var = tss / C - mu * mu;
  float rs = rsqrtf(var + LNEPS);
  for (int c = threadIdx.x; c < C; c += 256) {
    float v = xr[c];
    yr[c] = f2bf((v - mu) * rs * gam[c] + bet[c]);
  }
}

// ---------------- bf16 MFMA NT GEMM, BK=64 ----------------
// act: 0=none, 1=gelu, 2=out = sigmoid(resid)*acc (gate fusion, no bias)
__global__ __launch_bounds__(256) void gemm_bf(
    const short* __restrict__ A, int lda, long asB, long asH,
    const short* __restrict__ Bm, int ldb, long bsB, long bsH,
    float* __restrict__ outF, int ldf, long fsB, long fsH,
    short* __restrict__ outB, int ldob,
    const float* __restrict__ resid, int ldr, long rsB, long rsH,
    const float* __restrict__ bias,
    int M, int N, int K, int act, int vtrans, int Hdim) {
  int bz = blockIdx.z, bb = bz / Hdim, hh = bz % Hdim;
  A += bb * asB + hh * asH;
  Bm += bb * bsB + hh * bsH;
  if (outF) outF += bb * fsB + hh * fsH;
  if (outB) outB += bb * fsB + hh * fsH;
  if (resid) resid += bb * rsB + hh * rsH;
  __shared__ __align__(16) short As[64 * 72];
  __shared__ __align__(16) short Bs[64 * 72];
  int m0 = blockIdx.y * 64, n0 = blockIdx.x * 64;
  int tid = threadIdx.x;
  int wv = tid >> 6, lane = tid & 63;
  int wr = wv >> 1, wc = wv & 1;
  int lhi = lane >> 4, llo = lane & 15;
  int r4 = tid >> 2, c8 = (tid & 3) * 8;
  f32x4 acc[2][2] = {};
  for (int k0 = 0; k0 < K; k0 += 64) {
    *(bf8*)&As[r4 * 72 + c8] = *(const bf8*)(A + (long)(m0 + r4) * lda + k0 + c8);
    *(bf8*)&As[r4 * 72 + 32 + c8] =
        *(const bf8*)(A + (long)(m0 + r4) * lda + k0 + 32 + c8);
    bf8 bv0 = {}, bv1 = {};
    if (n0 + r4 < N) {
      bv0 = *(const bf8*)(Bm + (long)(n0 + r4) * ldb + k0 + c8);
      bv1 = *(const bf8*)(Bm + (long)(n0 + r4) * ldb + k0 + 32 + c8);
    }
    *(bf8*)&Bs[r4 * 72 + c8] = bv0;
    *(bf8*)&Bs[r4 * 72 + 32 + c8] = bv1;
    __syncthreads();
#pragma unroll
    for (int ks = 0; ks < 2; ++ks) {
      bf8 a0 = *(const bf8*)&As[(wr * 32 + llo) * 72 + ks * 32 + lhi * 8];
      bf8 a1 = *(const bf8*)&As[(wr * 32 + 16 + llo) * 72 + ks * 32 + lhi * 8];
      bf8 b0 = *(const bf8*)&Bs[(wc * 32 + llo) * 72 + ks * 32 + lhi * 8];
      bf8 b1 = *(const bf8*)&Bs[(wc * 32 + 16 + llo) * 72 + ks * 32 + lhi * 8];
      acc[0][0] = MFMA(a0, b0, acc[0][0]);
      acc[0][1] = MFMA(a0, b1, acc[0][1]);
      acc[1][0] = MFMA(a1, b0, acc[1][0]);
      acc[1][1] = MFMA(a1, b1, acc[1][1]);
    }
    __syncthreads();
  }
#pragma unroll
  for (int mi = 0; mi < 2; ++mi) {
    int gmb = m0 + wr * 32 + mi * 16 + lhi * 4;
#pragma unroll
    for (int ni = 0; ni < 2; ++ni) {
      int gn = n0 + wc * 32 + ni * 16 + llo;
      if (gn >= N) continue;
      float bv = bias ? bias[gn] : 0.f;
      float vr[4];
#pragma unroll
      for (int r = 0; r < 4; ++r) {
        float v = acc[mi][ni][r] + bv;
        if (resid) {
          float rv = resid[(long)(gmb + r) * ldr + gn];
          if (act == 2) v = sigmoidf_(rv) * acc[mi][ni][r];
          else v += rv;
        }
        if (act == 1) v = gelu_exact(v);
        vr[r] = v;
      }
      if (outF) {
#pragma unroll
        for (int r = 0; r < 4; ++r) outF[(long)(gmb + r) * ldf + gn] = vr[r];
      }
      if (outB) {
        if (vtrans) {
          bf4 pk;
#pragma unroll
          for (int r = 0; r < 4; ++r) pk[r] = f2bf(vr[r]);
          *(bf4*)(outB + ((long)((gmb >> 9) * 768 + gn) * 512 + (gmb & 511))) = pk;
        } else {
#pragma unroll
          for (int r = 0; r < 4; ++r) outB[(long)(gmb + r) * ldob + gn] = f2bf(vr[r]);
        }
      }
    }
  }
}

// ---------------- QKVG combined projection, BK=64 ----------------
__global__ __launch_bounds__(256) void gemm_qkvg(
    const short* __restrict__ A, const short* __restrict__ W,
    short* __restrict__ q_bf, short* __restrict__ k_bf,
    short* __restrict__ vT_bf, float* __restrict__ gb,
    const float* __restrict__ bg) {
  __shared__ __align__(16) short As[64 * 72];
  __shared__ __align__(16) short Bs[64 * 72];
  int m0 = blockIdx.y * 64, n0 = blockIdx.x * 64;
  int sec = n0 / 768;
  int cbase = n0 - sec * 768;
  int tid = threadIdx.x;
  int wv = tid >> 6, lane = tid & 63;
  int wr = wv >> 1, wc = wv & 1;
  int lhi = lane >> 4, llo = lane & 15;
  int r4 = tid >> 2, c8 = (tid & 3) * 8;
  f32x4 acc[2][2] = {};
  for (int k0 = 0; k0 < 768; k0 += 64) {
    *(bf8*)&As[r4 * 72 + c8] = *(const bf8*)(A + (long)(m0 + r4) * 768 + k0 + c8);
    *(bf8*)&As[r4 * 72 + 32 + c8] =
        *(const bf8*)(A + (long)(m0 + r4) * 768 + k0 + 32 + c8);
    *(bf8*)&Bs[r4 * 72 + c8] = *(const bf8*)(W + (long)(n0 + r4) * 768 + k0 + c8);
    *(bf8*)&Bs[r4 * 72 + 32 + c8] =
        *(const bf8*)(W + (long)(n0 + r4) * 768 + k0 + 32 + c8);
    __syncthreads();
#pragma unroll
    for (int ks = 0; ks < 2; ++ks) {
      bf8 a0 = *(const bf8*)&As[(wr * 32 + llo) * 72 + ks * 32 + lhi * 8];
      bf8 a1 = *(const bf8*)&As[(wr * 32 + 16 + llo) * 72 + ks * 32 + lhi * 8];
      bf8 b0 = *(const bf8*)&Bs[(wc * 32 + llo) * 72 + ks * 32 + lhi * 8];
      bf8 b1 = *(const bf8*)&Bs[(wc * 32 + 16 + llo) * 72 + ks * 32 + lhi * 8];
      acc[0][0] = MFMA(a0, b0, acc[0][0]);
      acc[0][1] = MFMA(a0, b1, acc[0][1]);
      acc[1][0] = MFMA(a1, b0, acc[1][0]);
      acc[1][1] = MFMA(a1, b1, acc[1][1]);
    }
    __syncthreads();
  }
#pragma unroll
  for (int mi = 0; mi < 2; ++mi) {
    int gmb = m0 + wr * 32 + mi * 16 + lhi * 4;
#pragma unroll
    for (int ni = 0; ni < 2; ++ni) {
      int cn = cbase + wc * 32 + ni * 16 + llo;
      if (sec == 0) {
#pragma unroll
        for (int r = 0; r < 4; ++r) q_bf[(long)(gmb + r) * 768 + cn] = f2bf(acc[mi][ni][r]);
      } else if (sec == 1) {
#pragma unroll
        for (int r = 0; r < 4; ++r) k_bf[(long)(gmb + r) * 768 + cn] = f2bf(acc[mi][ni][r]);
      } else if (sec == 2) {
        bf4 pk;
#pragma unroll
        for (int r = 0; r < 4; ++r) pk[r] = f2bf(acc[mi][ni][r]);
        *(bf4*)(vT_bf + ((long)((gmb >> 9) * 768 + cn) * 512 + (gmb & 511))) = pk;
      } else {
        float bv = bg[cn];
#pragma unroll
        for (int r = 0; r < 4; ++r) gb[(long)(gmb + r) * 768 + cn] = acc[mi][ni][r] + bv;
      }
    }
  }
}

// ---------------- fused scores + softmax (flash-row, 16 rows/block) ----------------
__global__ __launch_bounds__(256) void attn_fused(
    const short* __restrict__ q_bf, const short* __restrict__ k_bf,
    const short* __restrict__ bias_bf, const float* __restrict__ mask,
    short* __restrict__ out_bf) {
  int it = blockIdx.x, h = blockIdx.y, b = blockIdx.z;
  int tid = threadIdx.x;
  int wv = tid >> 6, lane = tid & 63;
  int lhi = lane >> 4, llo = lane & 15;
  int i0 = it * 16;
  long qoff = ((long)(b * 512 + i0)) * 768 + h * 96;
  bf8 qf[3];
#pragma unroll
  for (int ks = 0; ks < 3; ++ks)
    qf[ks] = *(const bf8*)(q_bf + qoff + (long)llo * 768 + ks * 32 + lhi * 8);
  long koff = ((long)b * 512) * 768 + h * 96;
  long bioff = (long)(b * 8 + h) * NNe + (long)i0 * 512;
  long moff = (long)b * NNe + (long)i0 * 512;
  float sv[8][4];
  int jb0 = wv * 128;
#pragma unroll
  for (int jf = 0; jf < 8; ++jf) {
    int jb = jb0 + jf * 16;
    f32x4 acc = {0.f, 0.f, 0.f, 0.f};
#pragma unroll
    for (int ks = 0; ks < 3; ++ks) {
      bf8 kf = *(const bf8*)(k_bf + koff + (long)(jb + llo) * 768 + ks * 32 + lhi * 8);
      acc = MFMA(qf[ks], kf, acc);
    }
#pragma unroll
    for (int r = 0; r < 4; ++r) {
      int irow = lhi * 4 + r;
      int j = jb + llo;
      float bia = bf2f(bias_bf[bioff + (long)irow * 512 + j]);
      float mk = mask[moff + (long)irow * 512 + j];
      sv[jf][r] = acc[r] + bia + mk;
    }
  }
  __shared__ float redA[4][20];
  __shared__ float redB[4][20];
  float rmax[4];
#pragma unroll
  for (int r = 0; r < 4; ++r) {
    float m = sv[0][r];
#pragma unroll
    for (int jf = 1; jf < 8; ++jf) m = fmaxf(m, sv[jf][r]);
#pragma unroll
    for (int off = 1; off < 16; off <<= 1) m = fmaxf(m, __shfl_xor(m, off, 16));
    if (llo == 0) redA[wv][lhi * 4 + r] = m;
  }
  __syncthreads();
#pragma unroll
  for (int r = 0; r < 4; ++r) {
    int row = lhi * 4 + r;
    rmax[r] = fmaxf(fmaxf(redA[0][row], redA[1][row]),
                    fmaxf(redA[2][row], redA[3][row]));
  }
  float rsum[4] = {0.f, 0.f, 0.f, 0.f};
#pragma unroll
  for (int jf = 0; jf < 8; ++jf)
#pragma unroll
    for (int r = 0; r < 4; ++r) {
      float e = __expf(sv[jf][r] - rmax[r]);
      sv[jf][r] = e;
      rsum[r] += e;
    }
#pragma unroll
  for (int r = 0; r < 4; ++r) {
#pragma unroll
    for (int off = 1; off < 16; off <<= 1) rsum[r] += __shfl_xor(rsum[r], off, 16);
    if (llo == 0) redB[wv][lhi * 4 + r] = rsum[r];
  }
  __syncthreads();
#pragma unroll
  for (int r = 0; r < 4; ++r) {
    int row = lhi * 4 + r;
    float s = redB[0][row] + redB[1][row] + redB[2][row] + redB[3][row];
    float inv = 1.f / s;
#pragma unroll
    for (int jf = 0; jf < 8; ++jf) {
      int j = jb0 + jf * 16 + llo;
      out_bf[bioff + (long)row * 512 + j] = f2bf(sv[jf][r] * inv);
    }
  }
}

// ---------------- ab *= op_mask ; emit b-half bf16 ----------------
__global__ __launch_bounds__(256) void opmask_kernel(float* __restrict__ ab,
                                                     const float* __restrict__ mask,
                                                     short* __restrict__ bo_bf) {
  int idx = blockIdx.x * 256 + threadIdx.x;
  if (idx < 131072) {
    float v = ab[idx] * mask[idx >> 6];
    ab[idx] = v;
    int ch = idx & 63;
    if (ch >= 32) bo_bf[(idx >> 6) * 32 + ch - 32] = f2bf(v);
  }
}

// ---------------- T[row,p,e] (bf16) = sum_d a_o[row,d] * w[p, d*32+e] ----------------
__global__ __launch_bounds__(256) void opm_T_kernel(const float* __restrict__ ab,
                                                    const float* __restrict__ w,
                                                    short* __restrict__ T) {
  int p = blockIdx.y;
  int row = blockIdx.x * 8 + threadIdx.y;
  int e = threadIdx.x;
  const float* a = ab + (long)row * 64;
  const float* wp = w + p * 1024 + e;
  float acc = 0.f;
#pragma unroll
  for (int d = 0; d < 32; ++d) acc += a[d] * wp[d * 32];
  T[((long)row * 64 + p) * 32 + e] = f2bf(acc);
}

// ---------------- pair bias: register LN ----------------
__global__ __launch_bounds__(256) void pair_bias_mfma(
    const float* __restrict__ pair, const float* __restrict__ gam,
    const float* __restrict__ bet, const short* __restrict__ wb_a,
    const float* __restrict__ bbv, short* __restrict__ bias) {
  __shared__ __align__(16) short Zb[64 * 72];
  __shared__ __align__(16) short Wb[16 * 72];
  __shared__ float sp[4][2][72];
  int tid = threadIdx.x;
  long e0 = (long)blockIdx.x * 64;
  int b = (int)(e0 >> 18);
  long ein = e0 & (NNe - 1);
  const float* base = pair + e0 * 64;
  for (int l = tid; l < 1024; l += 256) {
    int h = l >> 6, c = l & 63;
    Wb[h * 72 + c] = (h < 8) ? wb_a[h * 64 + c] : (short)0;
  }
  int e = tid & 63, q = tid >> 6;
  f32x4 v4[4];
  float s = 0.f, ss = 0.f;
#pragma unroll
  for (int k = 0; k < 4; ++k) {
    v4[k] = *(const f32x4*)(base + (long)e * 64 + q * 16 + k * 4);
#pragma unroll
    for (int u = 0; u < 4; ++u) { float v = v4[k][u]; s += v; ss += v * v; }
  }
  sp[q][0][e] = s; sp[q][1][e] = ss;
  __syncthreads();
  float ts = sp[0][0][e] + sp[1][0][e] + sp[2][0][e] + sp[3][0][e];
  float tss = sp[0][1][e] + sp[1][1][e] + sp[2][1][e] + sp[3][1][e];
  float mu = ts * 0.015625f, var = tss * 0.015625f - mu * mu;
  float rs = rsqrtf(var + LNEPS);
#pragma unroll
  for (int k = 0; k < 4; ++k) {
    bf4 pk;
#pragma unroll
    for (int u = 0; u < 4; ++u) {
      int c = q * 16 + k * 4 + u;
      pk[u] = f2bf((v4[k][u] - mu) * rs * gam[c] + bet[c]);
    }
    *(bf4*)&Zb[e * 72 + q * 16 + k * 4] = pk;
  }
  __syncthreads();
  int wv = tid >> 6, lane = tid & 63;
  int lhi = lane >> 4, llo = lane & 15;
  int n0 = wv * 16;
  f32x4 acc = {0.f, 0.f, 0.f, 0.f};
#pragma unroll
  for (int ks = 0; ks < 2; ++ks) {
    bf8 a = *(const bf8*)&Wb[llo * 72 + ks * 32 + lhi * 8];
    bf8 bz = *(const bf8*)&Zb[(n0 + llo) * 72 + ks * 32 + lhi * 8];
    acc = MFMA(a, bz, acc);
  }
  int elem = n0 + llo;
#pragma unroll
  for (int r = 0; r < 4; ++r) {
    int h = lhi * 4 + r;
    if (h < 8) bias[(long)(b * 8 + h) * NNe + ein + elem] = f2bf(acc[r] + bbv[h]);
  }
}

// ---------------- fused opm update + triangle ab v3 (register X, C-layout) ----------------
__global__ __launch_bounds__(256) void opm_ab_fused(
    const float* __restrict__ pair_in, const short* __restrict__ Tb,
    const short* __restrict__ bo_bf, const float* __restrict__ b_out,
    const float* __restrict__ op_norm, const float* __restrict__ gam,
    const float* __restrict__ bet, const short* __restrict__ wp_a,
    const float* __restrict__ b_abp, const short* __restrict__ wg_a,
    const float* __restrict__ b_abg, float* __restrict__ pair1,
    short* __restrict__ aN, short* __restrict__ bN) {
  int jt = blockIdx.x;   // 0..7
  int i = blockIdx.y;    // 0..511
  int tid = threadIdx.x;
  __shared__ __align__(16) short Tsb[64 * 40];
  __shared__ __align__(16) short Bob[64 * 40];
  __shared__ __align__(16) short Zb[64 * 72];
  __shared__ __align__(16) short Wp[64 * 72];
  __shared__ __align__(16) short Wg[64 * 72];
  __shared__ float spS[64][9];
  __shared__ float spQ[64][9];
  int wv = tid >> 6, lane = tid & 63;
  int wr = wv >> 1, wc = wv & 1;
  int lhi = lane >> 4, llo = lane & 15;
  int chb = wr * 32 + lhi * 4;
  {
    int p = tid >> 2, e8 = (tid & 3) * 8;
    *(bf8*)&Tsb[p * 40 + e8] = *(const bf8*)(Tb + (long)i * 2048 + p * 32 + e8);
    *(bf8*)&Bob[p * 40 + e8] = *(const bf8*)(bo_bf + (long)(jt * 64 + p) * 32 + e8);
  }
  for (int l = tid; l < 512; l += 256) {
    int r = l >> 3, c8 = (l & 7) * 8;
    *(bf8*)&Wp[r * 72 + c8] = *(const bf8*)(wp_a + r * 64 + c8);
    *(bf8*)&Wg[r * 72 + c8] = *(const bf8*)(wg_a + r * 64 + c8);
  }
  long ebase = (long)i * 512 + jt * 64;
  const float* pbase = pair_in + ebase * 64;
  f32x4 x[2][2];
#pragma unroll
  for (int mi = 0; mi < 2; ++mi)
#pragma unroll
    for (int ni = 0; ni < 2; ++ni)
      x[mi][ni] = *(const f32x4*)(pbase + (long)(wc * 32 + ni * 16 + llo) * 64 +
                                  chb + mi * 16);
  __syncthreads();   // (1)
  f32x4 acc[2][2] = {};
  {
    bf8 a0 = *(const bf8*)&Tsb[(wr * 32 + llo) * 40 + lhi * 8];
    bf8 a1 = *(const bf8*)&Tsb[(wr * 32 + 16 + llo) * 40 + lhi * 8];
    bf8 b0 = *(const bf8*)&Bob[(wc * 32 + llo) * 40 + lhi * 8];
    bf8 b1 = *(const bf8*)&Bob[(wc * 32 + 16 + llo) * 40 + lhi * 8];
    acc[0][0] = MFMA(a0, b0, acc[0][0]);
    acc[0][1] = MFMA(a0, b1, acc[0][1]);
    acc[1][0] = MFMA(a1, b0, acc[1][0]);
    acc[1][1] = MFMA(a1, b1, acc[1][1]);
  }
  float nrm = op_norm[0];
#pragma unroll
  for (int mi = 0; mi < 2; ++mi) {
    f32x4 bo4 = *(const f32x4*)(b_out + chb + mi * 16);
#pragma unroll
    for (int ni = 0; ni < 2; ++ni)
#pragma unroll
      for (int r = 0; r < 4; ++r)
        x[mi][ni][r] += (acc[mi][ni][r] + bo4[r]) * nrm;
  }
#pragma unroll
  for (int mi = 0; mi < 2; ++mi)
#pragma unroll
    for (int ni = 0; ni < 2; ++ni)
      *(f32x4*)(pair1 + (ebase + wc * 32 + ni * 16 + llo) * 64 + chb + mi * 16) =
          x[mi][ni];
#pragma unroll
  for (int ni = 0; ni < 2; ++ni) {
    float s = 0.f, ss = 0.f;
#pragma unroll
    for (int mi = 0; mi < 2; ++mi)
#pragma unroll
      for (int r = 0; r < 4; ++r) { float v = x[mi][ni][r]; s += v; ss += v * v; }
    int e = wc * 32 + ni * 16 + llo;
    spS[e][wr * 4 + lhi] = s;
    spQ[e][wr * 4 + lhi] = ss;
  }
  __syncthreads();   // (2)
  float mu1[2], rs1[2];
#pragma unroll
  for (int ni = 0; ni < 2; ++ni) {
    int e = wc * 32 + ni * 16 + llo;
    float s = 0.f, q2 = 0.f;
#pragma unroll
    for (int k = 0; k < 8; ++k) { s += spS[e][k]; q2 += spQ[e][k]; }
    float mu = s * 0.015625f, var = q2 * 0.015625f - mu * mu;
    mu1[ni] = mu; rs1[ni] = rsqrtf(var + LNEPS);
  }
#pragma unroll
  for (int mi = 0; mi < 2; ++mi) {
    f32x4 gv = *(const f32x4*)(gam + chb + mi * 16);
    f32x4 bv = *(const f32x4*)(bet + chb + mi * 16);
#pragma unroll
    for (int ni = 0; ni < 2; ++ni) {
      int e = wc * 32 + ni * 16 + llo;
      bf4 pk;
#pragma unroll
      for (int r = 0; r < 4; ++r)
        pk[r] = f2bf((x[mi][ni][r] - mu1[ni]) * rs1[ni] * gv[r] + bv[r]);
      *(bf4*)&Zb[e * 72 + chb + mi * 16] = pk;
    }
  }
  __syncthreads();   // (3)
  f32x4 ap[2][2] = {};
  f32x4 ag[2][2] = {};
#pragma unroll
  for (int ks = 0; ks < 2; ++ks) {
    bf8 z0 = *(const bf8*)&Zb[(wr * 32 + llo) * 72 + ks * 32 + lhi * 8];
    bf8 z1 = *(const bf8*)&Zb[(wr * 32 + 16 + llo) * 72 + ks * 32 + lhi * 8];
    bf8 p0 = *(const bf8*)&Wp[(wc * 32 + llo) * 72 + ks * 32 + lhi * 8];
    bf8 p1 = *(const bf8*)&Wp[(wc * 32 + 16 + llo) * 72 + ks * 32 + lhi * 8];
    bf8 g0 = *(const bf8*)&Wg[(wc * 32 + llo) * 72 + ks * 32 + lhi * 8];
    bf8 g1 = *(const bf8*)&Wg[(wc * 32 + 16 + llo) * 72 + ks * 32 + lhi * 8];
    ap[0][0] = MFMA(z0, p0, ap[0][0]);
    ap[0][1] = MFMA(z0, p1, ap[0][1]);
    ap[1][0] = MFMA(z1, p0, ap[1][0]);
    ap[1][1] = MFMA(z1, p1, ap[1][1]);
    ag[0][0] = MFMA(z0, g0, ag[0][0]);
    ag[0][1] = MFMA(z0, g1, ag[0][1]);
    ag[1][0] = MFMA(z1, g0, ag[1][0]);
    ag[1][1] = MFMA(z1, g1, ag[1][1]);
  }
#pragma unroll
  for (int mi = 0; mi < 2; ++mi) {
    int elemb = wr * 32 + mi * 16 + lhi * 4;
#pragma unroll
    for (int ni = 0; ni < 2; ++ni) {
      int ch = wc * 32 + ni * 16 + llo;
      float bp = b_abp[ch], bg = b_abg[ch];
      bf4 pack;
#pragma unroll
      for (int r = 0; r < 4; ++r)
        pack[r] = f2bf((ap[mi][ni][r] + bp) * sigmoidf_(ag[mi][ni][r] + bg));
      short* dst = (ch < 32) ? (aN + (long)ch * NNe) : (bN + (long)(ch - 32) * NNe);
      *(bf4*)(dst + ebase + elemb) = pack;
    }
  }
}

// ---------------- triangle einsum -> t bf16 (128x128 tile, 8 waves) ----------------
__global__ __launch_bounds__(512) void tm_tri_mfma(const short* __restrict__ aN,
                                                   const short* __restrict__ bN,
                                                   short* __restrict__ t_out) {
  int h = blockIdx.z;
  int i0 = blockIdx.y * 128, k0 = blockIdx.x * 128;
  const short* A = aN + (long)h * NNe;
  const short* B = bN + (long)h * NNe;
  __shared__ __align__(16) short A1[128 * 40];
  __shared__ __align__(16) short B1[128 * 40];
  __shared__ __align__(16) short A2[128 * 40];
  __shared__ __align__(16) short B2[128 * 40];
  int tid = threadIdx.x;
  int wv = tid >> 6, lane = tid & 63;
  int wr = wv >> 2, wc = wv & 3;       // 2x4 wave grid: 64 rows x 32 cols per wave
  int lhi = lane >> 4, llo = lane & 15;
  int r1 = tid >> 2, cp = (tid & 3) * 8;   // A1/B1 staging: 128 rows x 32 cols
  int s2 = tid >> 5, cg = (tid & 31) * 4;  // A2/B2: row pair (j), 4 cols (i/k)
  f32x4 acc[4][2] = {};
  for (int j0 = 0; j0 < 512; j0 += 32) {
    *(bf8*)&A1[r1 * 40 + cp] = *(const bf8*)(A + (long)(i0 + r1) * 512 + j0 + cp);
    *(bf8*)&B1[r1 * 40 + cp] = *(const bf8*)(B + (long)(k0 + r1) * 512 + j0 + cp);
    bf4 va0 = *(const bf4*)(A + (long)(j0 + 2 * s2) * 512 + i0 + cg);
    bf4 va1 = *(const bf4*)(A + (long)(j0 + 2 * s2 + 1) * 512 + i0 + cg);
    bf4 vb0 = *(const bf4*)(B + (long)(j0 + 2 * s2) * 512 + k0 + cg);
    bf4 vb1 = *(const bf4*)(B + (long)(j0 + 2 * s2 + 1) * 512 + k0 + cg);
#pragma unroll
    for (int q = 0; q < 4; ++q) {
      unsigned pa = (unsigned)(unsigned short)va0[q] |
                    ((unsigned)(unsigned short)va1[q] << 16);
      unsigned pb = (unsigned)(unsigned short)vb0[q] |
                    ((unsigned)(unsigned short)vb1[q] << 16);
      *(unsigned*)&A2[(cg + q) * 40 + 2 * s2] = pa;
      *(unsigned*)&B2[(cg + q) * 40 + 2 * s2] = pb;
    }
    __syncthreads();
    bf8 bfr[2], dfr[2];
#pragma unroll
    for (int ni = 0; ni < 2; ++ni) {
      bfr[ni] = *(const bf8*)&B1[(wc * 32 + ni * 16 + llo) * 40 + lhi * 8];
      dfr[ni] = *(const bf8*)&B2[(wc * 32 + ni * 16 + llo) * 40 + lhi * 8];
    }
#pragma unroll
    for (int mi = 0; mi < 4; ++mi) {
      bf8 a = *(const bf8*)&A1[(wr * 64 + mi * 16 + llo) * 40 + lhi * 8];
      acc[mi][0] = MFMA(a, bfr[0], acc[mi][0]);
      acc[mi][1] = MFMA(a, bfr[1], acc[mi][1]);
    }
#pragma unroll
    for (int mi = 0; mi < 4; ++mi) {
      bf8 c = *(const bf8*)&A2[(wr * 64 + mi * 16 + llo) * 40 + lhi * 8];
      acc[mi][0] = MFMA(c, dfr[0], acc[mi][0]);
      acc[mi][1] = MFMA(c, dfr[1], acc[mi][1]);
    }
    __syncthreads();
  }
  short* tp = t_out + (long)h * NNe;
#pragma unroll
  for (int mi = 0; mi < 4; ++mi)
#pragma unroll
    for (int ni = 0; ni < 2; ++ni) {
      int row = i0 + wr * 64 + mi * 16 + lhi * 4;
      int col = k0 + wc * 32 + ni * 16 + llo;
#pragma unroll
      for (int r = 0; r < 4; ++r) tp[(long)(row + r) * 512 + col] = f2bf(acc[mi][ni][r]);
    }
}

// ---------------- fused triangle update + pair FFN v3 (register X, shared Wbuf) ----------------
__global__ __launch_bounds__(256) void upd_pffn_fused(
    float* __restrict__ pb, const short* __restrict__ t_in,
    const float* __restrict__ g_tm, const float* __restrict__ b_tm,
    const short* __restrict__ wg_a, const float* __restrict__ b_g,
    const short* __restrict__ wz_a, const float* __restrict__ b_z,
    const float* __restrict__ g_tmo, const float* __restrict__ b_tmo,
    const float* __restrict__ g_pf, const float* __restrict__ b_pf,
    const short* __restrict__ w1_a, const float* __restrict__ b1,
    const short* __restrict__ w2_a, const float* __restrict__ b2) {
  __shared__ __align__(16) short Zb[64 * 72];
  __shared__ __align__(16) short Tlb[64 * 40];
  __shared__ __align__(16) short Wbuf[64 * 72];
  __shared__ __align__(16) short Wzb[64 * 40];
  __shared__ float spS[64][9];
  __shared__ float spQ[64][9];
  __shared__ float spB[4][2][72];
  int tid = threadIdx.x;
  long e0 = (long)blockIdx.x * 64;
  float* base = pb + e0 * 64;
  int wv = tid >> 6, lane = tid & 63;
  int wr = wv >> 1, wc = wv & 1;
  int lhi = lane >> 4, llo = lane & 15;
  int chb = wr * 32 + lhi * 4;
  int r0 = tid >> 3, c0 = (tid & 7) * 8;
  int r1 = (tid + 256) >> 3, c1 = ((tid + 256) & 7) * 8;
  bf8 w1r0, w1r1, w2r0, w2r1;
  {
    *(bf8*)&Wbuf[r0 * 72 + c0] = *(const bf8*)(wg_a + r0 * 64 + c0);
    *(bf8*)&Wbuf[r1 * 72 + c1] = *(const bf8*)(wg_a + r1 * 64 + c1);
    w1r0 = *(const bf8*)(w1_a + r0 * 64 + c0);
    w1r1 = *(const bf8*)(w1_a + r1 * 64 + c1);
    w2r0 = *(const bf8*)(w2_a + r0 * 64 + c0);
    w2r1 = *(const bf8*)(w2_a + r1 * 64 + c1);
    int rz = tid >> 2, cz = (tid & 3) * 8;
    *(bf8*)&Wzb[rz * 40 + cz] = *(const bf8*)(wz_a + rz * 32 + cz);
  }
  f32x4 x[2][2];
#pragma unroll
  for (int mi = 0; mi < 2; ++mi)
#pragma unroll
    for (int ni = 0; ni < 2; ++ni)
      x[mi][ni] = *(const f32x4*)(base + (long)(wc * 32 + ni * 16 + llo) * 64 +
                                  chb + mi * 16);
#pragma unroll
  for (int ni = 0; ni < 2; ++ni) {
    float s = 0.f, ss = 0.f;
#pragma unroll
    for (int mi = 0; mi < 2; ++mi)
#pragma unroll
      for (int r = 0; r < 4; ++r) { float v = x[mi][ni][r]; s += v; ss += v * v; }
    int e = wc * 32 + ni * 16 + llo;
    spS[e][wr * 4 + lhi] = s;
    spQ[e][wr * 4 + lhi] = ss;
  }
  int te = tid & 63, tq = tid >> 6;
  float tt[8];
  {
    float sB = 0.f, ssB = 0.f;
#pragma unroll
    for (int k = 0; k < 8; ++k) {
      float v = bf2f(t_in[(long)(tq * 8 + k) * NNe + e0 + te]);
      tt[k] = v; sB += v; ssB += v * v;
    }
    spB[tq][0][te] = sB; spB[tq][1][te] = ssB;
  }
  __syncthreads();   // (1)
  {
    float ts = spB[0][0][te] + spB[1][0][te] + spB[2][0][te] + spB[3][0][te];
    float tss = spB[0][1][te] + spB[1][1][te] + spB[2][1][te] + spB[3][1][te];
    float mu = ts * 0.03125f, var = tss * 0.03125f - mu * mu;
    float rs = rsqrtf(var + LNEPS);
    bf8 pk;
#pragma unroll
    for (int k = 0; k < 8; ++k) {
      int c = tq * 8 + k;
      pk[k] = f2bf((tt[k] - mu) * rs * g_tmo[c] + b_tmo[c]);
    }
    *(bf8*)&Tlb[te * 40 + tq * 8] = pk;
  }
  float mu1[2], rs1[2];
#pragma unroll
  for (int ni = 0; ni < 2; ++ni) {
    int e = wc * 32 + ni * 16 + llo;
    float s = 0.f, q2 = 0.f;
#pragma unroll
    for (int k = 0; k < 8; ++k) { s += spS[e][k]; q2 += spQ[e][k]; }
    float mu = s * 0.015625f, var = q2 * 0.015625f - mu * mu;
    mu1[ni] = mu; rs1[ni] = rsqrtf(var + LNEPS);
  }
#pragma unroll
  for (int mi = 0; mi < 2; ++mi) {
    f32x4 gv = *(const f32x4*)(g_tm + chb + mi * 16);
    f32x4 bv = *(const f32x4*)(b_tm + chb + mi * 16);
#pragma unroll
    for (int ni = 0; ni < 2; ++ni) {
      int e = wc * 32 + ni * 16 + llo;
      bf4 pk;
#pragma unroll
      for (int r = 0; r < 4; ++r)
        pk[r] = f2bf((x[mi][ni][r] - mu1[ni]) * rs1[ni] * gv[r] + bv[r]);
      *(bf4*)&Zb[e * 72 + chb + mi * 16] = pk;
    }
  }
  __syncthreads();   // (2)
  f32x4 accg[2][2] = {};
  f32x4 accz[2][2] = {};
#pragma unroll
  for (int ks = 0; ks < 2; ++ks) {
    bf8 a0 = *(const bf8*)&Wbuf[(wr * 32 + llo) * 72 + ks * 32 + lhi * 8];
    bf8 a1 = *(const bf8*)&Wbuf[(wr * 32 + 16 + llo) * 72 + ks * 32 + lhi * 8];
    bf8 z0 = *(const bf8*)&Zb[(wc * 32 + llo) * 72 + ks * 32 + lhi * 8];
    bf8 z1 = *(const bf8*)&Zb[(wc * 32 + 16 + llo) * 72 + ks * 32 + lhi * 8];
    accg[0][0] = MFMA(a0, z0, accg[0][0]);
    accg[0][1] = MFMA(a0, z1, accg[0][1]);
    accg[1][0] = MFMA(a1, z0, accg[1][0]);
    accg[1][1] = MFMA(a1, z1, accg[1][1]);
  }
  {
    bf8 a0 = *(const bf8*)&Wzb[(wr * 32 + llo) * 40 + lhi * 8];
    bf8 a1 = *(const bf8*)&Wzb[(wr * 32 + 16 + llo) * 40 + lhi * 8];
    bf8 t0 = *(const bf8*)&Tlb[(wc * 32 + llo) * 40 + lhi * 8];
    bf8 t1 = *(const bf8*)&Tlb[(wc * 32 + 16 + llo) * 40 + lhi * 8];
    accz[0][0] = MFMA(a0, t0, accz[0][0]);
    accz[0][1] = MFMA(a0, t1, accz[0][1]);
    accz[1][0] = MFMA(a1, t0, accz[1][0]);
    accz[1][1] = MFMA(a1, t1, accz[1][1]);
  }
#pragma unroll
  for (int mi = 0; mi < 2; ++mi) {
    f32x4 bgv = *(const f32x4*)(b_g + chb + mi * 16);
    f32x4 bzv = *(const f32x4*)(b_z + chb + mi * 16);
#pragma unroll
    for (int ni = 0; ni < 2; ++ni)
#pragma unroll
      for (int r = 0; r < 4; ++r)
        x[mi][ni][r] += (accg[mi][ni][r] + bgv[r]) * (accz[mi][ni][r] + bzv[r]);
  }
#pragma unroll
  for (int ni = 0; ni < 2; ++ni) {
    float s = 0.f, ss = 0.f;
#pragma unroll
    for (int mi = 0; mi < 2; ++mi)
#pragma unroll
      for (int r = 0; r < 4; ++r) { float v = x[mi][ni][r]; s += v; ss += v * v; }
    int e = wc * 32 + ni * 16 + llo;
    spS[e][wr * 4 + lhi] = s;
    spQ[e][wr * 4 + lhi] = ss;
  }
  __syncthreads();   // (3)
  *(bf8*)&Wbuf[r0 * 72 + c0] = w1r0;
  *(bf8*)&Wbuf[r1 * 72 + c1] = w1r1;
#pragma unroll
  for (int ni = 0; ni < 2; ++ni) {
    int e = wc * 32 + ni * 16 + llo;
    float s = 0.f, q2 = 0.f;
#pragma unroll
    for (int k = 0; k < 8; ++k) { s += spS[e][k]; q2 += spQ[e][k]; }
    float mu = s * 0.015625f, var = q2 * 0.015625f - mu * mu;
    mu1[ni] = mu; rs1[ni] = rsqrtf(var + LNEPS);
  }
#pragma unroll
  for (int mi = 0; mi < 2; ++mi) {
    f32x4 gv = *(const f32x4*)(g_pf + chb + mi * 16);
    f32x4 bv = *(const f32x4*)(b_pf + chb + mi * 16);
#pragma unroll
    for (int ni = 0; ni < 2; ++ni) {
      int e = wc * 32 + ni * 16 + llo;
      bf4 pk;
#pragma unroll
      for (int r = 0; r < 4; ++r)
        pk[r] = f2bf((x[mi][ni][r] - mu1[ni]) * rs1[ni] * gv[r] + bv[r]);
      *(bf4*)&Zb[e * 72 + chb + mi * 16] = pk;
    }
  }
  __syncthreads();   // (4)
  f32x4 acc1[2][2] = {};
#pragma unroll
  for (int ks = 0; ks < 2; ++ks) {
    bf8 a0 = *(const bf8*)&Wbuf[(wr * 32 + llo) * 72 + ks * 32 + lhi * 8];
    bf8 a1 = *(const bf8*)&Wbuf[(wr * 32 + 16 + llo) * 72 + ks * 32 + lhi * 8];
    bf8 z0 = *(const bf8*)&Zb[(wc * 32 + llo) * 72 + ks * 32 + lhi * 8];
    bf8 z1 = *(const bf8*)&Zb[(wc * 32 + 16 + llo) * 72 + ks * 32 + lhi * 8];
    acc1[0][0] = MFMA(a0, z0, acc1[0][0]);
    acc1[0][1] = MFMA(a0, z1, acc1[0][1]);
    acc1[1][0] = MFMA(a1, z0, acc1[1][0]);
    acc1[1][1] = MFMA(a1, z1, acc1[1][1]);
  }
  __syncthreads();   // (5)
  *(bf8*)&Wbuf[r0 * 72 + c0] = w2r0;
  *(bf8*)&Wbuf[r1 * 72 + c1] = w2r1;
#pragma unroll
  for (int mi = 0; mi < 2; ++mi) {
    f32x4 bv = *(const f32x4*)(b1 + chb + mi * 16);
#pragma unroll
    for (int ni = 0; ni < 2; ++ni) {
      int e = wc * 32 + ni * 16 + llo;
      bf4 pk;
#pragma unroll
      for (int r = 0; r < 4; ++r) pk[r] = f2bf(gelu_exact(acc1[mi][ni][r] + bv[r]));
      *(bf4*)&Zb[e * 72 + chb + mi * 16] = pk;
    }
  }
  __syncthreads();   // (6)
  f32x4 acc2[2][2] = {};
#pragma unroll
  for (int ks = 0; ks < 2; ++ks) {
    bf8 a0 = *(const bf8*)&Wbuf[(wr * 32 + llo) * 72 + ks * 32 + lhi * 8];
    bf8 a1 = *(const bf8*)&Wbuf[(wr * 32 + 16 + llo) * 72 + ks * 32 + lhi * 8];
    bf8 z0 = *(const bf8*)&Zb[(wc * 32 + llo) * 72 + ks * 32 + lhi * 8];
    bf8 z1 = *(const bf8*)&Zb[(wc * 32 + 16 + llo) * 72 + ks * 32 + lhi * 8];
    acc2[0][0] = MFMA(a0, z0, acc2[0][0]);
    acc2[0][1] = MFMA(a0, z1, acc2[0][1]);
    acc2[1][0] = MFMA(a1, z0, acc2[1][0]);
    acc2[1][1] = MFMA(a1, z1, acc2[1][1]);
  }
#pragma unroll
  for (int mi = 0; mi < 2; ++mi) {
    f32x4 bv = *(const f32x4*)(b2 + chb + mi * 16);
#pragma unroll
    for (int ni = 0; ni < 2; ++ni) {
#pragma unroll
      for (int r = 0; r < 4; ++r) x[mi][ni][r] += acc2[mi][ni][r] + bv[r];
      *(f32x4*)(base + (long)(wc * 32 + ni * 16 + llo) * 64 + chb + mi * 16) =
          x[mi][ni];
    }
  }
}

extern "C" void kernel_launch(void* const* d_in, const int* in_sizes, int n_in,
                              void* d_out, int out_size, void* d_ws, size_t ws_size,
                              hipStream_t stream) {
  const float* x = (const float*)d_in[0];
  const float* pair = (const float*)d_in[1];
  const float* attn_mask = (const float*)d_in[2];
  const float* op_mask = (const float*)d_in[3];
  const float* op_norm = (const float*)d_in[4];
  const float* wq = (const float*)d_in[6];
  const float* wk = (const float*)d_in[7];
  const float* wv_ = (const float*)d_in[8];
  const float* wg = (const float*)d_in[9];
  const float* bg = (const float*)d_in[10];
  const float* wo = (const float*)d_in[11];
  const float* bo = (const float*)d_in[12];
  const float* ln_pair_g = (const float*)d_in[13];
  const float* ln_pair_b = (const float*)d_in[14];
  const float* wb = (const float*)d_in[15];
  const float* bb = (const float*)d_in[16];
  const float* ln_attn_g = (const float*)d_in[17];
  const float* ln_attn_b = (const float*)d_in[18];
  const float* ln_ffn_g = (const float*)d_in[19];
  const float* ln_ffn_b = (const float*)d_in[20];
  const float* w_ffn1 = (const float*)d_in[21];
  const float* b_ffn1 = (const float*)d_in[22];
  const float* w_ffn2 = (const float*)d_in[23];
  const float* b_ffn2 = (const float*)d_in[24];
  const float* ln_opm_g = (const float*)d_in[25];
  const float* ln_opm_b = (const float*)d_in[26];
  const float* w_opm_in = (const float*)d_in[27];
  const float* b_opm_in = (const float*)d_in[28];
  const float* w_opm_out = (const float*)d_in[29];
  const float* b_opm_out = (const float*)d_in[30];
  const float* ln_tm_g = (const float*)d_in[31];
  const float* ln_tm_b = (const float*)d_in[32];
  const float* w_tm_abp = (const float*)d_in[33];
  const float* b_tm_abp = (const float*)d_in[34];
  const float* w_tm_abg = (const float*)d_in[35];
  const float* b_tm_abg = (const float*)d_in[36];
  const float* w_tm_g = (const float*)d_in[37];
  const float* b_tm_g = (const float*)d_in[38];
  const float* w_tm_z = (const float*)d_in[39];
  const float* b_tm_z = (const float*)d_in[40];
  const float* ln_tmo_g = (const float*)d_in[41];
  const float* ln_tmo_b = (const float*)d_in[42];
  const float* ln_pffn_g = (const float*)d_in[43];
  const float* ln_pffn_b = (const float*)d_in[44];
  const float* w_pffn1 = (const float*)d_in[45];
  const float* b_pffn1 = (const float*)d_in[46];
  const float* w_pffn2 = (const float*)d_in[47];
  const float* b_pffn2 = (const float*)d_in[48];

  float* ws = (float*)d_ws;
  short* wbf = (short*)ws;
  short* wq_bf = wbf + 0;            // base of contiguous [3072][768] qkvg block
  short* wo_bf = wbf + 2359296;
  short* wf1_bf = wbf + 2949120;
  short* wf2_bf = wbf + 5308416;
  short* wop_bf = wbf + 7667712;
  short* wb_a = wbf + 7716864;
  short* wabp_a = wbf + 7717376;
  short* wabg_a = wbf + 7721472;
  short* wtg_a = wbf + 7725568;
  short* wtz_a = wbf + 7729664;
  short* wp1_a = wbf + 7731712;
  short* wp2_a = wbf + 7735808;

  short* h_bf = (short*)(ws + 3869952);
  short* q_bf = (short*)(ws + 4656384);
  short* k_bf = (short*)(ws + 5442816);
  short* vT_bf = (short*)(ws + 6229248);
  float* gb = ws + 7015680;
  short* gb_bf = (short*)(ws + 10161408);
  float* x1b = ws + 10947840;
  short* biasb_bf = (short*)(ws + 12520704);   // 8388608 bf16
  short* attn_bf = (short*)(ws + 16715008);    // 8388608 bf16
  short* mffn_bf = (short*)(ws + 20909312);    // 6291456 bf16
  float* abb = ws + 24055040;                  // 131072 f32
  short* abb_bf = (short*)(ws + 24186112);     // 65536 bf16
  short* Tb_bf = (short*)(ws + 24218880);      // 4194304 bf16
  // triangle-stage overlays (attention/ffn buffers dead by then)
  short* aNb = (short*)(ws + 4656384);         // 8388608 bf16
  short* bNb = (short*)(ws + 8850688);         // 8388608 bf16
  short* t_bf = (short*)(ws + 13044992);       // 8388608 bf16

  float* xo = (float*)d_out;
  float* pair1 = xo + 1572864;

  const float qscale = 0.1020620726159658f;  // 96^-0.5

  // --- weight casts ---
  castw_kernel<<<30144, 256, 0, stream>>>(wq, wk, wv_, wg, wo, w_ffn1, w_ffn2, w_opm_in,
                                          wbf, qscale);
  castw2_kernel<<<90, 256, 0, stream>>>(wb, w_tm_abp, w_tm_abg, w_tm_g, w_tm_z,
                                        w_pffn1, w_pffn2, wb_a);
  // --- attention ---
  ln_bf_kernel<<<2048, 256, 0, stream>>>(x, h_bf, ln_attn_g, ln_attn_b, 768);
  gemm_qkvg<<<dim3(48, 32, 1), 256, 0, stream>>>(h_bf, wq_bf, q_bf, k_bf, vT_bf, gb, bg);
  pair_bias_mfma<<<16384, 256, 0, stream>>>(pair, ln_pair_g, ln_pair_b, wb_a, bb, biasb_bf);
  attn_fused<<<dim3(32, 8, 4), 256, 0, stream>>>(q_bf, k_bf, biasb_bf, attn_mask, attn_bf);
  // AV with fused output gate: gb_bf = sigmoid(gb) * (attn @ V)
  gemm_bf<<<dim3(2, 8, 32), 256, 0, stream>>>(attn_bf, 512, 2097152, 262144,
                                              vT_bf, 512, 393216, 49152,
                                              nullptr, 0, 393216, 96, gb_bf, 768,
                                              gb, 768, 393216, 96, nullptr,
                                              512, 96, 512, 2, 0, 8);
  gemm_bf<<<dim3(12, 32, 1), 256, 0, stream>>>(gb_bf, 768, 0, 0, wo_bf, 768, 0, 0,
                                               x1b, 768, 0, 0, nullptr, 0,
                                               x, 768, 0, 0, bo,
                                               2048, 768, 768, 0, 0, 1);
  // --- FFN ---
  ln_bf_kernel<<<2048, 256, 0, stream>>>(x1b, h_bf, ln_ffn_g, ln_ffn_b, 768);
  gemm_bf<<<dim3(48, 32, 1), 256, 0, stream>>>(h_bf, 768, 0, 0, wf1_bf, 768, 0, 0,
                                               nullptr, 0, 0, 0, mffn_bf, 3072,
                                               nullptr, 0, 0, 0, b_ffn1,
                                               2048, 3072, 768, 1, 0, 1);
  gemm_bf<<<dim3(12, 32, 1), 256, 0, stream>>>(mffn_bf, 3072, 0, 0, wf2_bf, 3072, 0, 0,
                                               xo, 768, 0, 0, nullptr, 0,
                                               x1b, 768, 0, 0, b_ffn2,
                                               2048, 768, 3072, 0, 0, 1);
  // --- outer product mean prep ---
  ln_bf_kernel<<<2048, 256, 0, stream>>>(xo, h_bf, ln_opm_g, ln_opm_b, 768);
  gemm_bf<<<dim3(1, 32, 1), 256, 0, stream>>>(h_bf, 768, 0, 0, wop_bf, 768, 0, 0,
                                              abb, 64, 0, 0, nullptr, 0,
                                              nullptr, 0, 0, 0, b_opm_in,
                                              2048, 64, 768, 0, 0, 1);
  opmask_kernel<<<512, 256, 0, stream>>>(abb, op_mask, abb_bf);
  opm_T_kernel<<<dim3(256, 64, 1), dim3(32, 8, 1), 0, stream>>>(abb, w_opm_out, Tb_bf);
  // --- pair stack per batch ---
  for (int b = 0; b < 4; ++b) {
    const float* pin = pair + (long)b * NNe * 64;
    float* pbb = pair1 + (long)b * NNe * 64;
    opm_ab_fused<<<dim3(8, 512, 1), 256, 0, stream>>>(
        pin, Tb_bf + (long)b * 1048576, abb_bf + (long)b * 16384, b_opm_out, op_norm,
        ln_tm_g, ln_tm_b, wabp_a, b_tm_abp, wabg_a, b_tm_abg, pbb, aNb, bNb);
    tm_tri_mfma<<<dim3(4, 4, 32), 512, 0, stream>>>(aNb, bNb, t_bf);
    upd_pffn_fused<<<4096, 256, 0, stream>>>(
        pbb, t_bf, ln_tm_g, ln_tm_b, wtg_a, b_tm_g, wtz_a, b_tm_z,
        ln_tmo_g, ln_tmo_b, ln_pffn_g, ln_pffn_b, wp1_a, b_pffn1, wp2_a, b_pffn2);
  }
}

// Round 8
// 907.011 us; speedup vs baseline: 7.5611x; 1.0471x over previous
//
#include <hip/hip_runtime.h>
#include <hip/hip_bf16.h>
#include <math.h>

#define Nn 512
#define Ee 768
#define Pp 64
#define PHh 32
#define Hh 8
#define Dd 96
#define NNe 262144      // N*N
#define LNEPS 1e-5f

typedef __attribute__((ext_vector_type(8))) short bf8;
typedef __attribute__((ext_vector_type(4))) short bf4;
typedef __attribute__((ext_vector_type(4))) float f32x4;
#define MFMA(a,b,c) __builtin_amdgcn_mfma_f32_16x16x32_bf16(a,b,c,0,0,0)

__device__ __forceinline__ short f2bf(float f) {
  unsigned u = __builtin_bit_cast(unsigned, f);
  unsigned r = (u + 0x7fffu + ((u >> 16) & 1u)) >> 16;
  return (short)r;
}
__device__ __forceinline__ float bf2f(short s) {
  unsigned u = ((unsigned)(unsigned short)s) << 16;
  return __builtin_bit_cast(float, u);
}

__device__ __forceinline__ float wave_red_sum(float v) {
#pragma unroll
  for (int off = 32; off > 0; off >>= 1) v += __shfl_xor(v, off);
  return v;
}
__device__ __forceinline__ float gelu_exact(float v) {
  return 0.5f * v * (1.f + erff(v * 0.70710678118654752f));
}
__device__ __forceinline__ float sigmoidf_(float v) {
  return 1.f / (1.f + expf(-v));
}

// ---------------- weight casts to bf16 arena ----------------
__global__ __launch_bounds__(256) void castw_kernel(
    const float* __restrict__ wq, const float* __restrict__ wk,
    const float* __restrict__ wv, const float* __restrict__ wg,
    const float* __restrict__ wo, const float* __restrict__ f1,
    const float* __restrict__ f2, const float* __restrict__ wop,
    short* __restrict__ dst, float qs) {
  long i = (long)blockIdx.x * 256 + threadIdx.x;
  float v;
  if (i < 589824) v = wq[i] * qs;
  else if (i < 1179648) v = wk[i - 589824];
  else if (i < 1769472) v = wv[i - 1179648];
  else if (i < 2359296) v = wg[i - 1769472];
  else if (i < 2949120) v = wo[i - 2359296];
  else if (i < 5308416) v = f1[i - 2949120];
  else if (i < 7667712) v = f2[i - 5308416];
  else if (i < 7716864) v = wop[i - 7667712];
  else return;
  dst[i] = f2bf(v);
}

__global__ __launch_bounds__(256) void castw2_kernel(
    const float* __restrict__ wb, const float* __restrict__ abp,
    const float* __restrict__ abg, const float* __restrict__ wtg,
    const float* __restrict__ wtz, const float* __restrict__ p1,
    const float* __restrict__ p2, short* __restrict__ dst) {
  int i = blockIdx.x * 256 + threadIdx.x;
  float v;
  if (i < 512) v = wb[i];
  else if (i < 4608) v = abp[i - 512];
  else if (i < 8704) v = abg[i - 4608];
  else if (i < 12800) v = wtg[i - 8704];
  else if (i < 14848) v = wtz[i - 12800];
  else if (i < 18944) v = p1[i - 14848];
  else if (i < 23040) v = p2[i - 18944];
  else return;
  dst[i] = f2bf(v);
}

// ---------------- LayerNorm over last dim C -> bf16 out ----------------
__global__ __launch_bounds__(256) void ln_bf_kernel(const float* __restrict__ in,
                                                    short* __restrict__ out,
                                                    const float* __restrict__ gam,
                                                    const float* __restrict__ bet, int C) {
  int row = blockIdx.x;
  const float* xr = in + (long)row * C;
  short* yr = out + (long)row * C;
  float s = 0.f, ss = 0.f;
  for (int c = threadIdx.x; c < C; c += 256) { float v = xr[c]; s += v; ss += v * v; }
  s = wave_red_sum(s); ss = wave_red_sum(ss);
  __shared__ float sm[4][2];
  int wv = threadIdx.x >> 6, lane = threadIdx.x & 63;
  if (lane == 0) { sm[wv][0] = s; sm[wv][1] = ss; }
  __syncthreads();
  float ts = sm[0][0] + sm[1][0] + sm[2][0] + sm[3][0];
  float tss = sm[0][1] + sm[1][1] + sm[2][1] + sm[3][1];
  float mu = ts / C;
  float var = tss / C - mu * mu;
  float rs = rsqrtf(var + LNEPS);
  for (int c = threadIdx.x; c < C; c += 256) {
    float v = xr[c];
    yr[c] = f2bf((v - mu) * rs * gam[c] + bet[c]);
  }
}

// ---------------- bf16 MFMA NT GEMM, 64x64, BK=64 (small/medium shapes) ----------------
__global__ __launch_bounds__(256) void gemm_bf(
    const short* __restrict__ A, int lda, long asB, long asH,
    const short* __restrict__ Bm, int ldb, long bsB, long bsH,
    float* __restrict__ outF, int ldf, long fsB, long fsH,
    short* __restrict__ outB, int ldob,
    const float* __restrict__ resid, int ldr, long rsB, long rsH,
    const float* __restrict__ bias,
    int M, int N, int K, int act, int vtrans, int Hdim) {
  int bz = blockIdx.z, bb = bz / Hdim, hh = bz % Hdim;
  A += bb * asB + hh * asH;
  Bm += bb * bsB + hh * bsH;
  if (outF) outF += bb * fsB + hh * fsH;
  if (outB) outB += bb * fsB + hh * fsH;
  if (resid) resid += bb * rsB + hh * rsH;
  __shared__ __align__(16) short As[64 * 72];
  __shared__ __align__(16) short Bs[64 * 72];
  int m0 = blockIdx.y * 64, n0 = blockIdx.x * 64;
  int tid = threadIdx.x;
  int wv = tid >> 6, lane = tid & 63;
  int wr = wv >> 1, wc = wv & 1;
  int lhi = lane >> 4, llo = lane & 15;
  int r4 = tid >> 2, c8 = (tid & 3) * 8;
  f32x4 acc[2][2] = {};
  for (int k0 = 0; k0 < K; k0 += 64) {
    *(bf8*)&As[r4 * 72 + c8] = *(const bf8*)(A + (long)(m0 + r4) * lda + k0 + c8);
    *(bf8*)&As[r4 * 72 + 32 + c8] =
        *(const bf8*)(A + (long)(m0 + r4) * lda + k0 + 32 + c8);
    bf8 bv0 = {}, bv1 = {};
    if (n0 + r4 < N) {
      bv0 = *(const bf8*)(Bm + (long)(n0 + r4) * ldb + k0 + c8);
      bv1 = *(const bf8*)(Bm + (long)(n0 + r4) * ldb + k0 + 32 + c8);
    }
    *(bf8*)&Bs[r4 * 72 + c8] = bv0;
    *(bf8*)&Bs[r4 * 72 + 32 + c8] = bv1;
    __syncthreads();
#pragma unroll
    for (int ks = 0; ks < 2; ++ks) {
      bf8 a0 = *(const bf8*)&As[(wr * 32 + llo) * 72 + ks * 32 + lhi * 8];
      bf8 a1 = *(const bf8*)&As[(wr * 32 + 16 + llo) * 72 + ks * 32 + lhi * 8];
      bf8 b0 = *(const bf8*)&Bs[(wc * 32 + llo) * 72 + ks * 32 + lhi * 8];
      bf8 b1 = *(const bf8*)&Bs[(wc * 32 + 16 + llo) * 72 + ks * 32 + lhi * 8];
      acc[0][0] = MFMA(a0, b0, acc[0][0]);
      acc[0][1] = MFMA(a0, b1, acc[0][1]);
      acc[1][0] = MFMA(a1, b0, acc[1][0]);
      acc[1][1] = MFMA(a1, b1, acc[1][1]);
    }
    __syncthreads();
  }
#pragma unroll
  for (int mi = 0; mi < 2; ++mi) {
    int gmb = m0 + wr * 32 + mi * 16 + lhi * 4;
#pragma unroll
    for (int ni = 0; ni < 2; ++ni) {
      int gn = n0 + wc * 32 + ni * 16 + llo;
      if (gn >= N) continue;
      float bv = bias ? bias[gn] : 0.f;
      float vr[4];
#pragma unroll
      for (int r = 0; r < 4; ++r) {
        float v = acc[mi][ni][r] + bv;
        if (resid) {
          float rv = resid[(long)(gmb + r) * ldr + gn];
          if (act == 2) v = sigmoidf_(rv) * acc[mi][ni][r];
          else v += rv;
        }
        if (act == 1) v = gelu_exact(v);
        vr[r] = v;
      }
      if (outF) {
#pragma unroll
        for (int r = 0; r < 4; ++r) outF[(long)(gmb + r) * ldf + gn] = vr[r];
      }
      if (outB) {
        if (vtrans) {
          bf4 pk;
#pragma unroll
          for (int r = 0; r < 4; ++r) pk[r] = f2bf(vr[r]);
          *(bf4*)(outB + ((long)((gmb >> 9) * 768 + gn) * 512 + (gmb & 511))) = pk;
        } else {
#pragma unroll
          for (int r = 0; r < 4; ++r) outB[(long)(gmb + r) * ldob + gn] = f2bf(vr[r]);
        }
      }
    }
  }
}

// ---------------- 128x128 tile (m97 structure): QKVG projection ----------------
__global__ __launch_bounds__(256) void gemm_qkvg(
    const short* __restrict__ A, const short* __restrict__ W,
    short* __restrict__ q_bf, short* __restrict__ k_bf,
    short* __restrict__ vT_bf, float* __restrict__ gb,
    const float* __restrict__ bg) {
  __shared__ __align__(16) short As[128 * 40];
  __shared__ __align__(16) short Bs[128 * 40];
  int m0 = blockIdx.y * 128, n0 = blockIdx.x * 128;
  int sec = n0 / 768;
  int cbase = n0 - sec * 768;
  int tid = threadIdx.x;
  int wv = tid >> 6, lane = tid & 63;
  int wr = wv >> 1, wc = wv & 1;
  int lhi = lane >> 4, llo = lane & 15;
  int r4 = tid >> 2, c8 = (tid & 3) * 8;
  f32x4 acc[4][4] = {};
  for (int k0 = 0; k0 < 768; k0 += 32) {
    *(bf8*)&As[r4 * 40 + c8] = *(const bf8*)(A + (long)(m0 + r4) * 768 + k0 + c8);
    *(bf8*)&As[(r4 + 64) * 40 + c8] =
        *(const bf8*)(A + (long)(m0 + r4 + 64) * 768 + k0 + c8);
    *(bf8*)&Bs[r4 * 40 + c8] = *(const bf8*)(W + (long)(n0 + r4) * 768 + k0 + c8);
    *(bf8*)&Bs[(r4 + 64) * 40 + c8] =
        *(const bf8*)(W + (long)(n0 + r4 + 64) * 768 + k0 + c8);
    __syncthreads();
    bf8 af[4], bfm[4];
#pragma unroll
    for (int mi = 0; mi < 4; ++mi)
      af[mi] = *(const bf8*)&As[(wr * 64 + mi * 16 + llo) * 40 + lhi * 8];
#pragma unroll
    for (int ni = 0; ni < 4; ++ni)
      bfm[ni] = *(const bf8*)&Bs[(wc * 64 + ni * 16 + llo) * 40 + lhi * 8];
#pragma unroll
    for (int mi = 0; mi < 4; ++mi)
#pragma unroll
      for (int ni = 0; ni < 4; ++ni)
        acc[mi][ni] = MFMA(af[mi], bfm[ni], acc[mi][ni]);
    __syncthreads();
  }
#pragma unroll
  for (int mi = 0; mi < 4; ++mi) {
    int gmb = m0 + wr * 64 + mi * 16 + lhi * 4;
#pragma unroll
    for (int ni = 0; ni < 4; ++ni) {
      int cn = cbase + wc * 64 + ni * 16 + llo;
      if (sec == 0) {
#pragma unroll
        for (int r = 0; r < 4; ++r) q_bf[(long)(gmb + r) * 768 + cn] = f2bf(acc[mi][ni][r]);
      } else if (sec == 1) {
#pragma unroll
        for (int r = 0; r < 4; ++r) k_bf[(long)(gmb + r) * 768 + cn] = f2bf(acc[mi][ni][r]);
      } else if (sec == 2) {
        bf4 pk;
#pragma unroll
        for (int r = 0; r < 4; ++r) pk[r] = f2bf(acc[mi][ni][r]);
        *(bf4*)(vT_bf + ((long)((gmb >> 9) * 768 + cn) * 512 + (gmb & 511))) = pk;
      } else {
        float bv = bg[cn];
#pragma unroll
        for (int r = 0; r < 4; ++r) gb[(long)(gmb + r) * 768 + cn] = acc[mi][ni][r] + bv;
      }
    }
  }
}

// ---------------- 128x128 tile: FFN1 (gelu, bf16 out) ----------------
__global__ __launch_bounds__(256) void gemm_ffn1(
    const short* __restrict__ A, const short* __restrict__ W,
    short* __restrict__ outB, const float* __restrict__ bias) {
  __shared__ __align__(16) short As[128 * 40];
  __shared__ __align__(16) short Bs[128 * 40];
  int m0 = blockIdx.y * 128, n0 = blockIdx.x * 128;
  int tid = threadIdx.x;
  int wv = tid >> 6, lane = tid & 63;
  int wr = wv >> 1, wc = wv & 1;
  int lhi = lane >> 4, llo = lane & 15;
  int r4 = tid >> 2, c8 = (tid & 3) * 8;
  f32x4 acc[4][4] = {};
  for (int k0 = 0; k0 < 768; k0 += 32) {
    *(bf8*)&As[r4 * 40 + c8] = *(const bf8*)(A + (long)(m0 + r4) * 768 + k0 + c8);
    *(bf8*)&As[(r4 + 64) * 40 + c8] =
        *(const bf8*)(A + (long)(m0 + r4 + 64) * 768 + k0 + c8);
    *(bf8*)&Bs[r4 * 40 + c8] = *(const bf8*)(W + (long)(n0 + r4) * 768 + k0 + c8);
    *(bf8*)&Bs[(r4 + 64) * 40 + c8] =
        *(const bf8*)(W + (long)(n0 + r4 + 64) * 768 + k0 + c8);
    __syncthreads();
    bf8 af[4], bfm[4];
#pragma unroll
    for (int mi = 0; mi < 4; ++mi)
      af[mi] = *(const bf8*)&As[(wr * 64 + mi * 16 + llo) * 40 + lhi * 8];
#pragma unroll
    for (int ni = 0; ni < 4; ++ni)
      bfm[ni] = *(const bf8*)&Bs[(wc * 64 + ni * 16 + llo) * 40 + lhi * 8];
#pragma unroll
    for (int mi = 0; mi < 4; ++mi)
#pragma unroll
      for (int ni = 0; ni < 4; ++ni)
        acc[mi][ni] = MFMA(af[mi], bfm[ni], acc[mi][ni]);
    __syncthreads();
  }
#pragma unroll
  for (int mi = 0; mi < 4; ++mi) {
    int gmb = m0 + wr * 64 + mi * 16 + lhi * 4;
#pragma unroll
    for (int ni = 0; ni < 4; ++ni) {
      int gn = n0 + wc * 64 + ni * 16 + llo;
      float bv = bias[gn];
#pragma unroll
      for (int r = 0; r < 4; ++r)
        outB[(long)(gmb + r) * 3072 + gn] = f2bf(gelu_exact(acc[mi][ni][r] + bv));
    }
  }
}

// ---------------- fused scores + softmax (flash-row, 16 rows/block) ----------------
__global__ __launch_bounds__(256) void attn_fused(
    const short* __restrict__ q_bf, const short* __restrict__ k_bf,
    const short* __restrict__ bias_bf, const float* __restrict__ mask,
    short* __restrict__ out_bf) {
  int it = blockIdx.x, h = blockIdx.y, b = blockIdx.z;
  int tid = threadIdx.x;
  int wv = tid >> 6, lane = tid & 63;
  int lhi = lane >> 4, llo = lane & 15;
  int i0 = it * 16;
  long qoff = ((long)(b * 512 + i0)) * 768 + h * 96;
  bf8 qf[3];
#pragma unroll
  for (int ks = 0; ks < 3; ++ks)
    qf[ks] = *(const bf8*)(q_bf + qoff + (long)llo * 768 + ks * 32 + lhi * 8);
  long koff = ((long)b * 512) * 768 + h * 96;
  long bioff = (long)(b * 8 + h) * NNe + (long)i0 * 512;
  long moff = (long)b * NNe + (long)i0 * 512;
  float sv[8][4];
  int jb0 = wv * 128;
#pragma unroll
  for (int jf = 0; jf < 8; ++jf) {
    int jb = jb0 + jf * 16;
    f32x4 acc = {0.f, 0.f, 0.f, 0.f};
#pragma unroll
    for (int ks = 0; ks < 3; ++ks) {
      bf8 kf = *(const bf8*)(k_bf + koff + (long)(jb + llo) * 768 + ks * 32 + lhi * 8);
      acc = MFMA(qf[ks], kf, acc);
    }
#pragma unroll
    for (int r = 0; r < 4; ++r) {
      int irow = lhi * 4 + r;
      int j = jb + llo;
      float bia = bf2f(bias_bf[bioff + (long)irow * 512 + j]);
      float mk = mask[moff + (long)irow * 512 + j];
      sv[jf][r] = acc[r] + bia + mk;
    }
  }
  __shared__ float redA[4][20];
  __shared__ float redB[4][20];
  float rmax[4];
#pragma unroll
  for (int r = 0; r < 4; ++r) {
    float m = sv[0][r];
#pragma unroll
    for (int jf = 1; jf < 8; ++jf) m = fmaxf(m, sv[jf][r]);
#pragma unroll
    for (int off = 1; off < 16; off <<= 1) m = fmaxf(m, __shfl_xor(m, off, 16));
    if (llo == 0) redA[wv][lhi * 4 + r] = m;
  }
  __syncthreads();
#pragma unroll
  for (int r = 0; r < 4; ++r) {
    int row = lhi * 4 + r;
    rmax[r] = fmaxf(fmaxf(redA[0][row], redA[1][row]),
                    fmaxf(redA[2][row], redA[3][row]));
  }
  float rsum[4] = {0.f, 0.f, 0.f, 0.f};
#pragma unroll
  for (int jf = 0; jf < 8; ++jf)
#pragma unroll
    for (int r = 0; r < 4; ++r) {
      float e = __expf(sv[jf][r] - rmax[r]);
      sv[jf][r] = e;
      rsum[r] += e;
    }
#pragma unroll
  for (int r = 0; r < 4; ++r) {
#pragma unroll
    for (int off = 1; off < 16; off <<= 1) rsum[r] += __shfl_xor(rsum[r], off, 16);
    if (llo == 0) redB[wv][lhi * 4 + r] = rsum[r];
  }
  __syncthreads();
#pragma unroll
  for (int r = 0; r < 4; ++r) {
    int row = lhi * 4 + r;
    float s = redB[0][row] + redB[1][row] + redB[2][row] + redB[3][row];
    float inv = 1.f / s;
#pragma unroll
    for (int jf = 0; jf < 8; ++jf) {
      int j = jb0 + jf * 16 + llo;
      out_bf[bioff + (long)row * 512 + j] = f2bf(sv[jf][r] * inv);
    }
  }
}

// ---------------- ab *= op_mask ; emit b-half bf16 ----------------
__global__ __launch_bounds__(256) void opmask_kernel(float* __restrict__ ab,
                                                     const float* __restrict__ mask,
                                                     short* __restrict__ bo_bf) {
  int idx = blockIdx.x * 256 + threadIdx.x;
  if (idx < 131072) {
    float v = ab[idx] * mask[idx >> 6];
    ab[idx] = v;
    int ch = idx & 63;
    if (ch >= 32) bo_bf[(idx >> 6) * 32 + ch - 32] = f2bf(v);
  }
}

// ---------------- T[row,p,e] (bf16) = sum_d a_o[row,d] * w[p, d*32+e] ----------------
__global__ __launch_bounds__(256) void opm_T_kernel(const float* __restrict__ ab,
                                                    const float* __restrict__ w,
                                                    short* __restrict__ T) {
  int p = blockIdx.y;
  int row = blockIdx.x * 8 + threadIdx.y;
  int e = threadIdx.x;
  const float* a = ab + (long)row * 64;
  const float* wp = w + p * 1024 + e;
  float acc = 0.f;
#pragma unroll
  for (int d = 0; d < 32; ++d) acc += a[d] * wp[d * 32];
  T[((long)row * 64 + p) * 32 + e] = f2bf(acc);
}

// ---------------- pair bias: register LN ----------------
__global__ __launch_bounds__(256) void pair_bias_mfma(
    const float* __restrict__ pair, const float* __restrict__ gam,
    const float* __restrict__ bet, const short* __restrict__ wb_a,
    const float* __restrict__ bbv, short* __restrict__ bias) {
  __shared__ __align__(16) short Zb[64 * 72];
  __shared__ __align__(16) short Wb[16 * 72];
  __shared__ float sp[4][2][72];
  int tid = threadIdx.x;
  long e0 = (long)blockIdx.x * 64;
  int b = (int)(e0 >> 18);
  long ein = e0 & (NNe - 1);
  const float* base = pair + e0 * 64;
  for (int l = tid; l < 1024; l += 256) {
    int h = l >> 6, c = l & 63;
    Wb[h * 72 + c] = (h < 8) ? wb_a[h * 64 + c] : (short)0;
  }
  int e = tid & 63, q = tid >> 6;
  f32x4 v4[4];
  float s = 0.f, ss = 0.f;
#pragma unroll
  for (int k = 0; k < 4; ++k) {
    v4[k] = *(const f32x4*)(base + (long)e * 64 + q * 16 + k * 4);
#pragma unroll
    for (int u = 0; u < 4; ++u) { float v = v4[k][u]; s += v; ss += v * v; }
  }
  sp[q][0][e] = s; sp[q][1][e] = ss;
  __syncthreads();
  float ts = sp[0][0][e] + sp[1][0][e] + sp[2][0][e] + sp[3][0][e];
  float tss = sp[0][1][e] + sp[1][1][e] + sp[2][1][e] + sp[3][1][e];
  float mu = ts * 0.015625f, var = tss * 0.015625f - mu * mu;
  float rs = rsqrtf(var + LNEPS);
#pragma unroll
  for (int k = 0; k < 4; ++k) {
    bf4 pk;
#pragma unroll
    for (int u = 0; u < 4; ++u) {
      int c = q * 16 + k * 4 + u;
      pk[u] = f2bf((v4[k][u] - mu) * rs * gam[c] + bet[c]);
    }
    *(bf4*)&Zb[e * 72 + q * 16 + k * 4] = pk;
  }
  __syncthreads();
  int wv = tid >> 6, lane = tid & 63;
  int lhi = lane >> 4, llo = lane & 15;
  int n0 = wv * 16;
  f32x4 acc = {0.f, 0.f, 0.f, 0.f};
#pragma unroll
  for (int ks = 0; ks < 2; ++ks) {
    bf8 a = *(const bf8*)&Wb[llo * 72 + ks * 32 + lhi * 8];
    bf8 bz = *(const bf8*)&Zb[(n0 + llo) * 72 + ks * 32 + lhi * 8];
    acc = MFMA(a, bz, acc);
  }
  int elem = n0 + llo;
#pragma unroll
  for (int r = 0; r < 4; ++r) {
    int h = lhi * 4 + r;
    if (h < 8) bias[(long)(b * 8 + h) * NNe + ein + elem] = f2bf(acc[r] + bbv[h]);
  }
}

// ---------------- opm + triangle ab (no pair1 write; aN/bN only) ----------------
__global__ __launch_bounds__(256) void opm_ab_fused(
    const float* __restrict__ pair_in, const short* __restrict__ Tb,
    const short* __restrict__ bo_bf, const float* __restrict__ b_out,
    const float* __restrict__ op_norm, const float* __restrict__ gam,
    const float* __restrict__ bet, const short* __restrict__ wp_a,
    const float* __restrict__ b_abp, const short* __restrict__ wg_a,
    const float* __restrict__ b_abg,
    short* __restrict__ aN, short* __restrict__ bN) {
  int jt = blockIdx.x;   // 0..7
  int i = blockIdx.y;    // 0..511
  int tid = threadIdx.x;
  __shared__ __align__(16) short Tsb[64 * 40];
  __shared__ __align__(16) short Bob[64 * 40];
  __shared__ __align__(16) short Zb[64 * 72];
  __shared__ __align__(16) short Wp[64 * 72];
  __shared__ __align__(16) short Wg[64 * 72];
  __shared__ float spS[64][9];
  __shared__ float spQ[64][9];
  int wv = tid >> 6, lane = tid & 63;
  int wr = wv >> 1, wc = wv & 1;
  int lhi = lane >> 4, llo = lane & 15;
  int chb = wr * 32 + lhi * 4;
  {
    int p = tid >> 2, e8 = (tid & 3) * 8;
    *(bf8*)&Tsb[p * 40 + e8] = *(const bf8*)(Tb + (long)i * 2048 + p * 32 + e8);
    *(bf8*)&Bob[p * 40 + e8] = *(const bf8*)(bo_bf + (long)(jt * 64 + p) * 32 + e8);
  }
  for (int l = tid; l < 512; l += 256) {
    int r = l >> 3, c8 = (l & 7) * 8;
    *(bf8*)&Wp[r * 72 + c8] = *(const bf8*)(wp_a + r * 64 + c8);
    *(bf8*)&Wg[r * 72 + c8] = *(const bf8*)(wg_a + r * 64 + c8);
  }
  long ebase = (long)i * 512 + jt * 64;
  const float* pbase = pair_in + ebase * 64;
  f32x4 x[2][2];
#pragma unroll
  for (int mi = 0; mi < 2; ++mi)
#pragma unroll
    for (int ni = 0; ni < 2; ++ni)
      x[mi][ni] = *(const f32x4*)(pbase + (long)(wc * 32 + ni * 16 + llo) * 64 +
                                  chb + mi * 16);
  __syncthreads();   // (1)
  f32x4 acc[2][2] = {};
  {
    bf8 a0 = *(const bf8*)&Tsb[(wr * 32 + llo) * 40 + lhi * 8];
    bf8 a1 = *(const bf8*)&Tsb[(wr * 32 + 16 + llo) * 40 + lhi * 8];
    bf8 b0 = *(const bf8*)&Bob[(wc * 32 + llo) * 40 + lhi * 8];
    bf8 b1 = *(const bf8*)&Bob[(wc * 32 + 16 + llo) * 40 + lhi * 8];
    acc[0][0] = MFMA(a0, b0, acc[0][0]);
    acc[0][1] = MFMA(a0, b1, acc[0][1]);
    acc[1][0] = MFMA(a1, b0, acc[1][0]);
    acc[1][1] = MFMA(a1, b1, acc[1][1]);
  }
  float nrm = op_norm[0];
#pragma unroll
  for (int mi = 0; mi < 2; ++mi) {
    f32x4 bo4 = *(const f32x4*)(b_out + chb + mi * 16);
#pragma unroll
    for (int ni = 0; ni < 2; ++ni)
#pragma unroll
      for (int r = 0; r < 4; ++r)
        x[mi][ni][r] += (acc[mi][ni][r] + bo4[r]) * nrm;
  }
#pragma unroll
  for (int ni = 0; ni < 2; ++ni) {
    float s = 0.f, ss = 0.f;
#pragma unroll
    for (int mi = 0; mi < 2; ++mi)
#pragma unroll
      for (int r = 0; r < 4; ++r) { float v = x[mi][ni][r]; s += v; ss += v * v; }
    int e = wc * 32 + ni * 16 + llo;
    spS[e][wr * 4 + lhi] = s;
    spQ[e][wr * 4 + lhi] = ss;
  }
  __syncthreads();   // (2)
  float mu1[2], rs1[2];
#pragma unroll
  for (int ni = 0; ni < 2; ++ni) {
    int e = wc * 32 + ni * 16 + llo;
    float s = 0.f, q2 = 0.f;
#pragma unroll
    for (int k = 0; k < 8; ++k) { s += spS[e][k]; q2 += spQ[e][k]; }
    float mu = s * 0.015625f, var = q2 * 0.015625f - mu * mu;
    mu1[ni] = mu; rs1[ni] = rsqrtf(var + LNEPS);
  }
#pragma unroll
  for (int mi = 0; mi < 2; ++mi) {
    f32x4 gv = *(const f32x4*)(gam + chb + mi * 16);
    f32x4 bv = *(const f32x4*)(bet + chb + mi * 16);
#pragma unroll
    for (int ni = 0; ni < 2; ++ni) {
      int e = wc * 32 + ni * 16 + llo;
      bf4 pk;
#pragma unroll
      for (int r = 0; r < 4; ++r)
        pk[r] = f2bf((x[mi][ni][r] - mu1[ni]) * rs1[ni] * gv[r] + bv[r]);
      *(bf4*)&Zb[e * 72 + chb + mi * 16] = pk;
    }
  }
  __syncthreads();   // (3)
  f32x4 ap[2][2] = {};
  f32x4 ag[2][2] = {};
#pragma unroll
  for (int ks = 0; ks < 2; ++ks) {
    bf8 z0 = *(const bf8*)&Zb[(wr * 32 + llo) * 72 + ks * 32 + lhi * 8];
    bf8 z1 = *(const bf8*)&Zb[(wr * 32 + 16 + llo) * 72 + ks * 32 + lhi * 8];
    bf8 p0 = *(const bf8*)&Wp[(wc * 32 + llo) * 72 + ks * 32 + lhi * 8];
    bf8 p1 = *(const bf8*)&Wp[(wc * 32 + 16 + llo) * 72 + ks * 32 + lhi * 8];
    bf8 g0 = *(const bf8*)&Wg[(wc * 32 + llo) * 72 + ks * 32 + lhi * 8];
    bf8 g1 = *(const bf8*)&Wg[(wc * 32 + 16 + llo) * 72 + ks * 32 + lhi * 8];
    ap[0][0] = MFMA(z0, p0, ap[0][0]);
    ap[0][1] = MFMA(z0, p1, ap[0][1]);
    ap[1][0] = MFMA(z1, p0, ap[1][0]);
    ap[1][1] = MFMA(z1, p1, ap[1][1]);
    ag[0][0] = MFMA(z0, g0, ag[0][0]);
    ag[0][1] = MFMA(z0, g1, ag[0][1]);
    ag[1][0] = MFMA(z1, g0, ag[1][0]);
    ag[1][1] = MFMA(z1, g1, ag[1][1]);
  }
#pragma unroll
  for (int mi = 0; mi < 2; ++mi) {
    int elemb = wr * 32 + mi * 16 + lhi * 4;
#pragma unroll
    for (int ni = 0; ni < 2; ++ni) {
      int ch = wc * 32 + ni * 16 + llo;
      float bp = b_abp[ch], bg = b_abg[ch];
      bf4 pack;
#pragma unroll
      for (int r = 0; r < 4; ++r)
        pack[r] = f2bf((ap[mi][ni][r] + bp) * sigmoidf_(ag[mi][ni][r] + bg));
      short* dst = (ch < 32) ? (aN + (long)ch * NNe) : (bN + (long)(ch - 32) * NNe);
      *(bf4*)(dst + ebase + elemb) = pack;
    }
  }
}

// ---------------- triangle einsum -> t bf16 (128x128 tile, XCD swizzle) ----------------
__global__ __launch_bounds__(512) void tm_tri_mfma(const short* __restrict__ aN,
                                                   const short* __restrict__ bN,
                                                   short* __restrict__ t_out) {
  // XCD-aware remap: 512 blocks, give each XCD 64 consecutive virtual tiles (4 heads)
  int lin = blockIdx.z * 16 + blockIdx.y * 4 + blockIdx.x;
  int vid = (lin & 7) * 64 + (lin >> 3);
  int h = vid >> 4;
  int rem = vid & 15;
  int i0 = (rem >> 2) * 128, k0 = (rem & 3) * 128;
  const short* A = aN + (long)h * NNe;
  const short* B = bN + (long)h * NNe;
  __shared__ __align__(16) short A1[128 * 40];
  __shared__ __align__(16) short B1[128 * 40];
  __shared__ __align__(16) short A2[128 * 40];
  __shared__ __align__(16) short B2[128 * 40];
  int tid = threadIdx.x;
  int wv = tid >> 6, lane = tid & 63;
  int wr = wv >> 2, wc = wv & 3;
  int lhi = lane >> 4, llo = lane & 15;
  int r1 = tid >> 2, cp = (tid & 3) * 8;
  int s2 = tid >> 5, cg = (tid & 31) * 4;
  f32x4 acc[4][2] = {};
  for (int j0 = 0; j0 < 512; j0 += 32) {
    *(bf8*)&A1[r1 * 40 + cp] = *(const bf8*)(A + (long)(i0 + r1) * 512 + j0 + cp);
    *(bf8*)&B1[r1 * 40 + cp] = *(const bf8*)(B + (long)(k0 + r1) * 512 + j0 + cp);
    bf4 va0 = *(const bf4*)(A + (long)(j0 + 2 * s2) * 512 + i0 + cg);
    bf4 va1 = *(const bf4*)(A + (long)(j0 + 2 * s2 + 1) * 512 + i0 + cg);
    bf4 vb0 = *(const bf4*)(B + (long)(j0 + 2 * s2) * 512 + k0 + cg);
    bf4 vb1 = *(const bf4*)(B + (long)(j0 + 2 * s2 + 1) * 512 + k0 + cg);
#pragma unroll
    for (int q = 0; q < 4; ++q) {
      unsigned pa = (unsigned)(unsigned short)va0[q] |
                    ((unsigned)(unsigned short)va1[q] << 16);
      unsigned pb = (unsigned)(unsigned short)vb0[q] |
                    ((unsigned)(unsigned short)vb1[q] << 16);
      *(unsigned*)&A2[(cg + q) * 40 + 2 * s2] = pa;
      *(unsigned*)&B2[(cg + q) * 40 + 2 * s2] = pb;
    }
    __syncthreads();
    bf8 bfr[2], dfr[2];
#pragma unroll
    for (int ni = 0; ni < 2; ++ni) {
      bfr[ni] = *(const bf8*)&B1[(wc * 32 + ni * 16 + llo) * 40 + lhi * 8];
      dfr[ni] = *(const bf8*)&B2[(wc * 32 + ni * 16 + llo) * 40 + lhi * 8];
    }
#pragma unroll
    for (int mi = 0; mi < 4; ++mi) {
      bf8 a = *(const bf8*)&A1[(wr * 64 + mi * 16 + llo) * 40 + lhi * 8];
      acc[mi][0] = MFMA(a, bfr[0], acc[mi][0]);
      acc[mi][1] = MFMA(a, bfr[1], acc[mi][1]);
    }
#pragma unroll
    for (int mi = 0; mi < 4; ++mi) {
      bf8 c = *(const bf8*)&A2[(wr * 64 + mi * 16 + llo) * 40 + lhi * 8];
      acc[mi][0] = MFMA(c, dfr[0], acc[mi][0]);
      acc[mi][1] = MFMA(c, dfr[1], acc[mi][1]);
    }
    __syncthreads();
  }
  short* tp = t_out + (long)h * NNe;
#pragma unroll
  for (int mi = 0; mi < 4; ++mi)
#pragma unroll
    for (int ni = 0; ni < 2; ++ni) {
      int row = i0 + wr * 64 + mi * 16 + lhi * 4;
      int col = k0 + wc * 32 + ni * 16 + llo;
#pragma unroll
      for (int r = 0; r < 4; ++r) tp[(long)(row + r) * 512 + col] = f2bf(acc[mi][ni][r]);
    }
}

// ---------------- fused OPM-recompute + triangle update + pair FFN (pin -> pout) ----------------
__global__ __launch_bounds__(256) void upd_pffn_fused(
    const float* __restrict__ pin, float* __restrict__ pout,
    const short* __restrict__ t_in,
    const short* __restrict__ Tb, const short* __restrict__ bo_bf,
    const float* __restrict__ b_out, const float* __restrict__ op_norm,
    const float* __restrict__ g_tm, const float* __restrict__ b_tm,
    const short* __restrict__ wg_a, const float* __restrict__ b_g,
    const short* __restrict__ wz_a, const float* __restrict__ b_z,
    const float* __restrict__ g_tmo, const float* __restrict__ b_tmo,
    const float* __restrict__ g_pf, const float* __restrict__ b_pf,
    const short* __restrict__ w1_a, const float* __restrict__ b1,
    const short* __restrict__ w2_a, const float* __restrict__ b2) {
  __shared__ __align__(16) short Zb[64 * 72];
  __shared__ __align__(16) short Tlb[64 * 40];
  __shared__ __align__(16) short Wbuf[64 * 72];
  __shared__ __align__(16) short Wzb[64 * 40];
  __shared__ __align__(16) short Tsb[64 * 40];
  __shared__ __align__(16) short Bob[64 * 40];
  __shared__ float spS[64][9];
  __shared__ float spQ[64][9];
  __shared__ float spB[4][2][72];
  int tid = threadIdx.x;
  long e0 = (long)blockIdx.x * 64;
  int i = (int)(e0 >> 9);
  int jt = (int)((e0 >> 6) & 7);
  int wv = tid >> 6, lane = tid & 63;
  int wr = wv >> 1, wc = wv & 1;
  int lhi = lane >> 4, llo = lane & 15;
  int chb = wr * 32 + lhi * 4;
  int r0 = tid >> 3, c0 = (tid & 7) * 8;
  int r1 = (tid + 256) >> 3, c1 = ((tid + 256) & 7) * 8;
  bf8 w1r0, w1r1, w2r0, w2r1;
  {
    *(bf8*)&Wbuf[r0 * 72 + c0] = *(const bf8*)(wg_a + r0 * 64 + c0);
    *(bf8*)&Wbuf[r1 * 72 + c1] = *(const bf8*)(wg_a + r1 * 64 + c1);
    w1r0 = *(const bf8*)(w1_a + r0 * 64 + c0);
    w1r1 = *(const bf8*)(w1_a + r1 * 64 + c1);
    w2r0 = *(const bf8*)(w2_a + r0 * 64 + c0);
    w2r1 = *(const bf8*)(w2_a + r1 * 64 + c1);
    int rz = tid >> 2, cz = (tid & 3) * 8;
    *(bf8*)&Wzb[rz * 40 + cz] = *(const bf8*)(wz_a + rz * 32 + cz);
    int p = tid >> 2, e8 = (tid & 3) * 8;
    *(bf8*)&Tsb[p * 40 + e8] = *(const bf8*)(Tb + (long)i * 2048 + p * 32 + e8);
    *(bf8*)&Bob[p * 40 + e8] = *(const bf8*)(bo_bf + (long)(jt * 64 + p) * 32 + e8);
  }
  // X registers (C-layout) from ORIGINAL pair input
  f32x4 x[2][2];
#pragma unroll
  for (int mi = 0; mi < 2; ++mi)
#pragma unroll
    for (int ni = 0; ni < 2; ++ni)
      x[mi][ni] = *(const f32x4*)(pin + (e0 + wc * 32 + ni * 16 + llo) * 64 +
                                  chb + mi * 16);
  // t loads + LN32 partials
  int te = tid & 63, tq = tid >> 6;
  float tt[8];
  {
    float sB = 0.f, ssB = 0.f;
#pragma unroll
    for (int k = 0; k < 8; ++k) {
      float v = bf2f(t_in[(long)(tq * 8 + k) * NNe + e0 + te]);
      tt[k] = v; sB += v; ssB += v * v;
    }
    spB[tq][0][te] = sB; spB[tq][1][te] = ssB;
  }
  __syncthreads();   // (1)
  // Tlb
  {
    float ts = spB[0][0][te] + spB[1][0][te] + spB[2][0][te] + spB[3][0][te];
    float tss = spB[0][1][te] + spB[1][1][te] + spB[2][1][te] + spB[3][1][te];
    float mu = ts * 0.03125f, var = tss * 0.03125f - mu * mu;
    float rs = rsqrtf(var + LNEPS);
    bf8 pk;
#pragma unroll
    for (int k = 0; k < 8; ++k) {
      int c = tq * 8 + k;
      pk[k] = f2bf((tt[k] - mu) * rs * g_tmo[c] + b_tmo[c]);
    }
    *(bf8*)&Tlb[te * 40 + tq * 8] = pk;
  }
  // recompute OPM delta: D[p][j] = sum_e T[p][e]*Bo[j][e]
  {
    f32x4 acc[2][2] = {};
    bf8 a0 = *(const bf8*)&Tsb[(wr * 32 + llo) * 40 + lhi * 8];
    bf8 a1 = *(const bf8*)&Tsb[(wr * 32 + 16 + llo) * 40 + lhi * 8];
    bf8 b0 = *(const bf8*)&Bob[(wc * 32 + llo) * 40 + lhi * 8];
    bf8 b1 = *(const bf8*)&Bob[(wc * 32 + 16 + llo) * 40 + lhi * 8];
    acc[0][0] = MFMA(a0, b0, acc[0][0]);
    acc[0][1] = MFMA(a0, b1, acc[0][1]);
    acc[1][0] = MFMA(a1, b0, acc[1][0]);
    acc[1][1] = MFMA(a1, b1, acc[1][1]);
    float nrm = op_norm[0];
#pragma unroll
    for (int mi = 0; mi < 2; ++mi) {
      f32x4 bo4 = *(const f32x4*)(b_out + chb + mi * 16);
#pragma unroll
      for (int ni = 0; ni < 2; ++ni)
#pragma unroll
        for (int r = 0; r < 4; ++r)
          x[mi][ni][r] += (acc[mi][ni][r] + bo4[r]) * nrm;
    }
  }
  // LN1 partials
#pragma unroll
  for (int ni = 0; ni < 2; ++ni) {
    float s = 0.f, ss = 0.f;
#pragma unroll
    for (int mi = 0; mi < 2; ++mi)
#pragma unroll
      for (int r = 0; r < 4; ++r) { float v = x[mi][ni][r]; s += v; ss += v * v; }
    int e = wc * 32 + ni * 16 + llo;
    spS[e][wr * 4 + lhi] = s;
    spQ[e][wr * 4 + lhi] = ss;
  }
  __syncthreads();   // (1b)
  float mu1[2], rs1[2];
#pragma unroll
  for (int ni = 0; ni < 2; ++ni) {
    int e = wc * 32 + ni * 16 + llo;
    float s = 0.f, q2 = 0.f;
#pragma unroll
    for (int k = 0; k < 8; ++k) { s += spS[e][k]; q2 += spQ[e][k]; }
    float mu = s * 0.015625f, var = q2 * 0.015625f - mu * mu;
    mu1[ni] = mu; rs1[ni] = rsqrtf(var + LNEPS);
  }
#pragma unroll
  for (int mi = 0; mi < 2; ++mi) {
    f32x4 gv = *(const f32x4*)(g_tm + chb + mi * 16);
    f32x4 bv = *(const f32x4*)(b_tm + chb + mi * 16);
#pragma unroll
    for (int ni = 0; ni < 2; ++ni) {
      int e = wc * 32 + ni * 16 + llo;
      bf4 pk;
#pragma unroll
      for (int r = 0; r < 4; ++r)
        pk[r] = f2bf((x[mi][ni][r] - mu1[ni]) * rs1[ni] * gv[r] + bv[r]);
      *(bf4*)&Zb[e * 72 + chb + mi * 16] = pk;
    }
  }
  __syncthreads();   // (2)
  // MFMA gate + z
  f32x4 accg[2][2] = {};
  f32x4 accz[2][2] = {};
#pragma unroll
  for (int ks = 0; ks < 2; ++ks) {
    bf8 a0 = *(const bf8*)&Wbuf[(wr * 32 + llo) * 72 + ks * 32 + lhi * 8];
    bf8 a1 = *(const bf8*)&Wbuf[(wr * 32 + 16 + llo) * 72 + ks * 32 + lhi * 8];
    bf8 z0 = *(const bf8*)&Zb[(wc * 32 + llo) * 72 + ks * 32 + lhi * 8];
    bf8 z1 = *(const bf8*)&Zb[(wc * 32 + 16 + llo) * 72 + ks * 32 + lhi * 8];
    accg[0][0] = MFMA(a0, z0, accg[0][0]);
    accg[0][1] = MFMA(a0, z1, accg[0][1]);
    accg[1][0] = MFMA(a1, z0, accg[1][0]);
    accg[1][1] = MFMA(a1, z1, accg[1][1]);
  }
  {
    bf8 a0 = *(const bf8*)&Wzb[(wr * 32 + llo) * 40 + lhi * 8];
    bf8 a1 = *(const bf8*)&Wzb[(wr * 32 + 16 + llo) * 40 + lhi * 8];
    bf8 t0 = *(const bf8*)&Tlb[(wc * 32 + llo) * 40 + lhi * 8];
    bf8 t1 = *(const bf8*)&Tlb[(wc * 32 + 16 + llo) * 40 + lhi * 8];
    accz[0][0] = MFMA(a0, t0, accz[0][0]);
    accz[0][1] = MFMA(a0, t1, accz[0][1]);
    accz[1][0] = MFMA(a1, t0, accz[1][0]);
    accz[1][1] = MFMA(a1, t1, accz[1][1]);
  }
#pragma unroll
  for (int mi = 0; mi < 2; ++mi) {
    f32x4 bgv = *(const f32x4*)(b_g + chb + mi * 16);
    f32x4 bzv = *(const f32x4*)(b_z + chb + mi * 16);
#pragma unroll
    for (int ni = 0; ni < 2; ++ni)
#pragma unroll
      for (int r = 0; r < 4; ++r)
        x[mi][ni][r] += (accg[mi][ni][r] + bgv[r]) * (accz[mi][ni][r] + bzv[r]);
  }
  // LN2 partials
#pragma unroll
  for (int ni = 0; ni < 2; ++ni) {
    float s = 0.f, ss = 0.f;
#pragma unroll
    for (int mi = 0; mi < 2; ++mi)
#pragma unroll
      for (int r = 0; r < 4; ++r) { float v = x[mi][ni][r]; s += v; ss += v * v; }
    int e = wc * 32 + ni * 16 + llo;
    spS[e][wr * 4 + lhi] = s;
    spQ[e][wr * 4 + lhi] = ss;
  }
  __syncthreads();   // (3)
  *(bf8*)&Wbuf[r0 * 72 + c0] = w1r0;
  *(bf8*)&Wbuf[r1 * 72 + c1] = w1r1;
#pragma unroll
  for (int ni = 0; ni < 2; ++ni) {
    int e = wc * 32 + ni * 16 + llo;
    float s = 0.f, q2 = 0.f;
#pragma unroll
    for (int k = 0; k < 8; ++k) { s += spS[e][k]; q2 += spQ[e][k]; }
    float mu = s * 0.015625f, var = q2 * 0.015625f - mu * mu;
    mu1[ni] = mu; rs1[ni] = rsqrtf(var + LNEPS);
  }
#pragma unroll
  for (int mi = 0; mi < 2; ++mi) {
    f32x4 gv = *(const f32x4*)(g_pf + chb + mi * 16);
    f32x4 bv = *(const f32x4*)(b_pf + chb + mi * 16);
#pragma unroll
    for (int ni = 0; ni < 2; ++ni) {
      int e = wc * 32 + ni * 16 + llo;
      bf4 pk;
#pragma unroll
      for (int r = 0; r < 4; ++r)
        pk[r] = f2bf((x[mi][ni][r] - mu1[ni]) * rs1[ni] * gv[r] + bv[r]);
      *(bf4*)&Zb[e * 72 + chb + mi * 16] = pk;
    }
  }
  __syncthreads();   // (4)
  f32x4 acc1[2][2] = {};
#pragma unroll
  for (int ks = 0; ks < 2; ++ks) {
    bf8 a0 = *(const bf8*)&Wbuf[(wr * 32 + llo) * 72 + ks * 32 + lhi * 8];
    bf8 a1 = *(const bf8*)&Wbuf[(wr * 32 + 16 + llo) * 72 + ks * 32 + lhi * 8];
    bf8 z0 = *(const bf8*)&Zb[(wc * 32 + llo) * 72 + ks * 32 + lhi * 8];
    bf8 z1 = *(const bf8*)&Zb[(wc * 32 + 16 + llo) * 72 + ks * 32 + lhi * 8];
    acc1[0][0] = MFMA(a0, z0, acc1[0][0]);
    acc1[0][1] = MFMA(a0, z1, acc1[0][1]);
    acc1[1][0] = MFMA(a1, z0, acc1[1][0]);
    acc1[1][1] = MFMA(a1, z1, acc1[1][1]);
  }
  __syncthreads();   // (5)
  *(bf8*)&Wbuf[r0 * 72 + c0] = w2r0;
  *(bf8*)&Wbuf[r1 * 72 + c1] = w2r1;
#pragma unroll
  for (int mi = 0; mi < 2; ++mi) {
    f32x4 bv = *(const f32x4*)(b1 + chb + mi * 16);
#pragma unroll
    for (int ni = 0; ni < 2; ++ni) {
      int e = wc * 32 + ni * 16 + llo;
      bf4 pk;
#pragma unroll
      for (int r = 0; r < 4; ++r) pk[r] = f2bf(gelu_exact(acc1[mi][ni][r] + bv[r]));
      *(bf4*)&Zb[e * 72 + chb + mi * 16] = pk;
    }
  }
  __syncthreads();   // (6)
  f32x4 acc2[2][2] = {};
#pragma unroll
  for (int ks = 0; ks < 2; ++ks) {
    bf8 a0 = *(const bf8*)&Wbuf[(wr * 32 + llo) * 72 + ks * 32 + lhi * 8];
    bf8 a1 = *(const bf8*)&Wbuf[(wr * 32 + 16 + llo) * 72 + ks * 32 + lhi * 8];
    bf8 z0 = *(const bf8*)&Zb[(wc * 32 + llo) * 72 + ks * 32 + lhi * 8];
    bf8 z1 = *(const bf8*)&Zb[(wc * 32 + 16 + llo) * 72 + ks * 32 + lhi * 8];
    acc2[0][0] = MFMA(a0, z0, acc2[0][0]);
    acc2[0][1] = MFMA(a0, z1, acc2[0][1]);
    acc2[1][0] = MFMA(a1, z0, acc2[1][0]);
    acc2[1][1] = MFMA(a1, z1, acc2[1][1]);
  }
#pragma unroll
  for (int mi = 0; mi < 2; ++mi) {
    f32x4 bv = *(const f32x4*)(b2 + chb + mi * 16);
#pragma unroll
    for (int ni = 0; ni < 2; ++ni) {
#pragma unroll
      for (int r = 0; r < 4; ++r) x[mi][ni][r] += acc2[mi][ni][r] + bv[r];
      *(f32x4*)(pout + (e0 + wc * 32 + ni * 16 + llo) * 64 + chb + mi * 16) =
          x[mi][ni];
    }
  }
}

extern "C" void kernel_launch(void* const* d_in, const int* in_sizes, int n_in,
                              void* d_out, int out_size, void* d_ws, size_t ws_size,
                              hipStream_t stream) {
  const float* x = (const float*)d_in[0];
  const float* pair = (const float*)d_in[1];
  const float* attn_mask = (const float*)d_in[2];
  const float* op_mask = (const float*)d_in[3];
  const float* op_norm = (const float*)d_in[4];
  const float* wq = (const float*)d_in[6];
  const float* wk = (const float*)d_in[7];
  const float* wv_ = (const float*)d_in[8];
  const float* wg = (const float*)d_in[9];
  const float* bg = (const float*)d_in[10];
  const float* wo = (const float*)d_in[11];
  const float* bo = (const float*)d_in[12];
  const float* ln_pair_g = (const float*)d_in[13];
  const float* ln_pair_b = (const float*)d_in[14];
  const float* wb = (const float*)d_in[15];
  const float* bb = (const float*)d_in[16];
  const float* ln_attn_g = (const float*)d_in[17];
  const float* ln_attn_b = (const float*)d_in[18];
  const float* ln_ffn_g = (const float*)d_in[19];
  const float* ln_ffn_b = (const float*)d_in[20];
  const float* w_ffn1 = (const float*)d_in[21];
  const float* b_ffn1 = (const float*)d_in[22];
  const float* w_ffn2 = (const float*)d_in[23];
  const float* b_ffn2 = (const float*)d_in[24];
  const float* ln_opm_g = (const float*)d_in[25];
  const float* ln_opm_b = (const float*)d_in[26];
  const float* w_opm_in = (const float*)d_in[27];
  const float* b_opm_in = (const float*)d_in[28];
  const float* w_opm_out = (const float*)d_in[29];
  const float* b_opm_out = (const float*)d_in[30];
  const float* ln_tm_g = (const float*)d_in[31];
  const float* ln_tm_b = (const float*)d_in[32];
  const float* w_tm_abp = (const float*)d_in[33];
  const float* b_tm_abp = (const float*)d_in[34];
  const float* w_tm_abg = (const float*)d_in[35];
  const float* b_tm_abg = (const float*)d_in[36];
  const float* w_tm_g = (const float*)d_in[37];
  const float* b_tm_g = (const float*)d_in[38];
  const float* w_tm_z = (const float*)d_in[39];
  const float* b_tm_z = (const float*)d_in[40];
  const float* ln_tmo_g = (const float*)d_in[41];
  const float* ln_tmo_b = (const float*)d_in[42];
  const float* ln_pffn_g = (const float*)d_in[43];
  const float* ln_pffn_b = (const float*)d_in[44];
  const float* w_pffn1 = (const float*)d_in[45];
  const float* b_pffn1 = (const float*)d_in[46];
  const float* w_pffn2 = (const float*)d_in[47];
  const float* b_pffn2 = (const float*)d_in[48];

  float* ws = (float*)d_ws;
  short* wbf = (short*)ws;
  short* wq_bf = wbf + 0;            // base of contiguous [3072][768] qkvg block
  short* wo_bf = wbf + 2359296;
  short* wf1_bf = wbf + 2949120;
  short* wf2_bf = wbf + 5308416;
  short* wop_bf = wbf + 7667712;
  short* wb_a = wbf + 7716864;
  short* wabp_a = wbf + 7717376;
  short* wabg_a = wbf + 7721472;
  short* wtg_a = wbf + 7725568;
  short* wtz_a = wbf + 7729664;
  short* wp1_a = wbf + 7731712;
  short* wp2_a = wbf + 7735808;

  short* h_bf = (short*)(ws + 3869952);
  short* q_bf = (short*)(ws + 4656384);
  short* k_bf = (short*)(ws + 5442816);
  short* vT_bf = (short*)(ws + 6229248);
  float* gb = ws + 7015680;
  short* gb_bf = (short*)(ws + 10161408);
  float* x1b = ws + 10947840;
  short* biasb_bf = (short*)(ws + 12520704);   // 8388608 bf16
  short* attn_bf = (short*)(ws + 16715008);    // 8388608 bf16
  short* mffn_bf = (short*)(ws + 20909312);    // 6291456 bf16
  float* abb = ws + 24055040;                  // 131072 f32
  short* abb_bf = (short*)(ws + 24186112);     // 65536 bf16
  short* Tb_bf = (short*)(ws + 24218880);      // 4194304 bf16
  // triangle-stage overlays (attention/ffn buffers dead by then)
  short* aNb = (short*)(ws + 4656384);         // 8388608 bf16
  short* bNb = (short*)(ws + 8850688);         // 8388608 bf16
  short* t_bf = (short*)(ws + 13044992);       // 8388608 bf16

  float* xo = (float*)d_out;
  float* pair1 = xo + 1572864;

  const float qscale = 0.1020620726159658f;  // 96^-0.5

  // --- weight casts ---
  castw_kernel<<<30144, 256, 0, stream>>>(wq, wk, wv_, wg, wo, w_ffn1, w_ffn2, w_opm_in,
                                          wbf, qscale);
  castw2_kernel<<<90, 256, 0, stream>>>(wb, w_tm_abp, w_tm_abg, w_tm_g, w_tm_z,
                                        w_pffn1, w_pffn2, wb_a);
  // --- attention ---
  ln_bf_kernel<<<2048, 256, 0, stream>>>(x, h_bf, ln_attn_g, ln_attn_b, 768);
  gemm_qkvg<<<dim3(24, 16, 1), 256, 0, stream>>>(h_bf, wq_bf, q_bf, k_bf, vT_bf, gb, bg);
  pair_bias_mfma<<<16384, 256, 0, stream>>>(pair, ln_pair_g, ln_pair_b, wb_a, bb, biasb_bf);
  attn_fused<<<dim3(32, 8, 4), 256, 0, stream>>>(q_bf, k_bf, biasb_bf, attn_mask, attn_bf);
  // AV with fused output gate: gb_bf = sigmoid(gb) * (attn @ V)
  gemm_bf<<<dim3(2, 8, 32), 256, 0, stream>>>(attn_bf, 512, 2097152, 262144,
                                              vT_bf, 512, 393216, 49152,
                                              nullptr, 0, 393216, 96, gb_bf, 768,
                                              gb, 768, 393216, 96, nullptr,
                                              512, 96, 512, 2, 0, 8);
  gemm_bf<<<dim3(12, 32, 1), 256, 0, stream>>>(gb_bf, 768, 0, 0, wo_bf, 768, 0, 0,
                                               x1b, 768, 0, 0, nullptr, 0,
                                               x, 768, 0, 0, bo,
                                               2048, 768, 768, 0, 0, 1);
  // --- FFN ---
  ln_bf_kernel<<<2048, 256, 0, stream>>>(x1b, h_bf, ln_ffn_g, ln_ffn_b, 768);
  gemm_ffn1<<<dim3(24, 16, 1), 256, 0, stream>>>(h_bf, wf1_bf, mffn_bf, b_ffn1);
  gemm_bf<<<dim3(12, 32, 1), 256, 0, stream>>>(mffn_bf, 3072, 0, 0, wf2_bf, 3072, 0, 0,
                                               xo, 768, 0, 0, nullptr, 0,
                                               x1b, 768, 0, 0, b_ffn2,
                                               2048, 768, 3072, 0, 0, 1);
  // --- outer product mean prep ---
  ln_bf_kernel<<<2048, 256, 0, stream>>>(xo, h_bf, ln_opm_g, ln_opm_b, 768);
  gemm_bf<<<dim3(1, 32, 1), 256, 0, stream>>>(h_bf, 768, 0, 0, wop_bf, 768, 0, 0,
                                              abb, 64, 0, 0, nullptr, 0,
                                              nullptr, 0, 0, 0, b_opm_in,
                                              2048, 64, 768, 0, 0, 1);
  opmask_kernel<<<512, 256, 0, stream>>>(abb, op_mask, abb_bf);
  opm_T_kernel<<<dim3(256, 64, 1), dim3(32, 8, 1), 0, stream>>>(abb, w_opm_out, Tb_bf);
  // --- pair stack per batch ---
  for (int b = 0; b < 4; ++b) {
    const float* pin = pair + (long)b * NNe * 64;
    float* pbb = pair1 + (long)b * NNe * 64;
    opm_ab_fused<<<dim3(8, 512, 1), 256, 0, stream>>>(
        pin, Tb_bf + (long)b * 1048576, abb_bf + (long)b * 16384, b_opm_out, op_norm,
        ln_tm_g, ln_tm_b, wabp_a, b_tm_abp, wabg_a, b_tm_abg, aNb, bNb);
    tm_tri_mfma<<<dim3(4, 4, 32), 512, 0, stream>>>(aNb, bNb, t_bf);
    upd_pffn_fused<<<4096, 256, 0, stream>>>(
        pin, pbb, t_bf, Tb_bf + (long)b * 1048576, abb_bf + (long)b * 16384,
        b_opm_out, op_norm,
        ln_tm_g, ln_tm_b, wtg_a, b_tm_g, wtz_a, b_tm_z,
        ln_tmo_g, ln_tmo_b, ln_pffn_g, ln_pffn_b, wp1_a, b_pffn1, wp2_a, b_pffn2);
  }
}